// Round 1
// baseline (2163.951 us; speedup 1.0000x reference)
//
#include <hip/hip_runtime.h>
#include <math.h>
#include <stdint.h>

#define B 64
#define T 2048
#define D 256
#define HID 32
#define NSEL 6
#define NBIN 8192      // 13-bit bins: sign + 8 exp + 4 mantissa
#define CAP 8192
#define EPS 1e-8

// accum slots per batch (stride 16 doubles)
#define A_S1 0
#define A_S2 1
#define A_S3 2
#define A_S4 3
#define A_AC 4
#define A_Y2 5
#define A_DIAG 6
#define A_TRACE 7
#define A_N 16

#define NAPPLY 320

// ---------------- sortable float keys ----------------
__device__ __forceinline__ unsigned int f2key(float f) {
    unsigned int u = __float_as_uint(f);
    return (u & 0x80000000u) ? ~u : (u | 0x80000000u);
}
__device__ __forceinline__ float key2f(unsigned int k) {
    unsigned int u = (k & 0x80000000u) ? (k ^ 0x80000000u) : ~k;
    return __uint_as_float(u);
}

// ---------------- pass1: fused moments / autocorr / row means / mask / channel sums ----------------
__global__ __launch_bounds__(256) void k_pass1(const float* __restrict__ x, const int* __restrict__ mask,
        double* __restrict__ xm, float* __restrict__ rowm,
        double* __restrict__ cs1, double* __restrict__ cs2, double* __restrict__ accum) {
    int b = blockIdx.x >> 4;
    int blk = blockIdx.x & 15;
    int wave = threadIdx.x >> 6;
    int lane = threadIdx.x & 63;
    int ts = blk * 128 + wave * 32;
    const float* xb = x + (size_t)b * T * D;
    const int* mb = mask + (size_t)b * T * D;
    double c1l[4] = {0, 0, 0, 0}, c2l[4] = {0, 0, 0, 0};
    double s1 = 0, s2 = 0, s3 = 0, s4 = 0, ac = 0;
    float pa[4] = {0, 0, 0, 0};
    for (int r = 0; r < 32; ++r) {
        int t = ts + r;
        float4 xv = *(const float4*)(xb + (size_t)t * D + lane * 4);
        int4 mv = *(const int4*)(mb + (size_t)t * D + lane * 4);
        double rs = (double)xv.x + (double)xv.y + (double)xv.z + (double)xv.w;
        int rm = mv.x + mv.y + mv.z + mv.w;
        for (int o = 32; o > 0; o >>= 1) { rs += __shfl_down(rs, o); rm += __shfl_down(rm, o); }
        if (lane == 0) {
            xm[(size_t)b * T + t] = rs * (1.0 / 256.0);
            rowm[(size_t)b * T + t] = (float)rm;
        }
        float xa[4] = {xv.x, xv.y, xv.z, xv.w};
        #pragma unroll
        for (int j = 0; j < 4; ++j) {
            double xd = (double)xa[j];
            double x2 = xd * xd;
            s1 += xd; s2 += x2; s3 += x2 * xd; s4 += x2 * x2;
            c1l[j] += xd; c2l[j] += x2;
        }
        if (r > 0) {
            #pragma unroll
            for (int j = 0; j < 4; ++j) ac += (double)pa[j] * (double)xa[j];
        }
        pa[0] = xa[0]; pa[1] = xa[1]; pa[2] = xa[2]; pa[3] = xa[3];
    }
    if (ts + 32 <= T - 1) {
        float4 xn = *(const float4*)(xb + (size_t)(ts + 32) * D + lane * 4);
        float na[4] = {xn.x, xn.y, xn.z, xn.w};
        #pragma unroll
        for (int j = 0; j < 4; ++j) ac += (double)pa[j] * (double)na[j];
    }
    for (int o = 32; o > 0; o >>= 1) {
        s1 += __shfl_down(s1, o); s2 += __shfl_down(s2, o);
        s3 += __shfl_down(s3, o); s4 += __shfl_down(s4, o);
        ac += __shfl_down(ac, o);
    }
    if (lane == 0) {
        atomicAdd(&accum[b * A_N + A_S1], s1);
        atomicAdd(&accum[b * A_N + A_S2], s2);
        atomicAdd(&accum[b * A_N + A_S3], s3);
        atomicAdd(&accum[b * A_N + A_S4], s4);
        atomicAdd(&accum[b * A_N + A_AC], ac);
    }
    #pragma unroll
    for (int j = 0; j < 4; ++j) {
        atomicAdd(&cs1[b * D + lane * 4 + j], c1l[j]);
        atomicAdd(&cs2[b * D + lane * 4 + j], c2l[j]);
    }
}

// ---------------- per-channel finalize: mu, 1/std, diag-corr sum, trace ----------------
__global__ __launch_bounds__(256) void k_chan(const double* __restrict__ cs1, const double* __restrict__ cs2,
        float* __restrict__ mu, float* __restrict__ winv, double* __restrict__ accum) {
    int b = blockIdx.x, d = threadIdx.x;
    double c1 = cs1[b * D + d], c2 = cs2[b * D + d];
    double m = c1 / (double)T;
    double c2c = c2 - c1 * c1 / (double)T;
    double var = c2c / (double)(T - 1);
    mu[b * D + d] = (float)m;
    winv[b * D + d] = (float)(1.0 / sqrt(var));
    double diag = (c2c / ((double)(T - 1) + EPS)) / (var + EPS);
    __shared__ double sd[256], st[256];
    sd[d] = diag; st[d] = c2c; __syncthreads();
    for (int o = 128; o > 0; o >>= 1) {
        if (d < o) { sd[d] += sd[d + o]; st[d] += st[d + o]; }
        __syncthreads();
    }
    if (d == 0) { accum[b * A_N + A_DIAG] = sd[0]; accum[b * A_N + A_TRACE] = st[0]; }
}

// ---------------- attention logits: tanh(x@Wa1+ba1)@Wa2+ba2 ----------------
__global__ __launch_bounds__(256) void k_attn(const float* __restrict__ x,
        const float* __restrict__ Wa1, const float* __restrict__ ba1,
        const float* __restrict__ Wa2, const float* __restrict__ ba2,
        float* __restrict__ logit) {
    __shared__ float tile[256][33];   // +1 pad: conflict-free column reads
    int bid = blockIdx.x;
    int b = bid >> 3, t0 = (bid & 7) * 256;
    int tid = threadIdx.x;
    const float* xb = x + (size_t)b * T * D + (size_t)t0 * D;
    float acc[HID];
    #pragma unroll
    for (int h = 0; h < HID; ++h) acc[h] = 0.f;
    for (int dc = 0; dc < 8; ++dc) {
        __syncthreads();
        #pragma unroll
        for (int i = 0; i < 32; ++i) {
            int idx = i * 256 + tid;
            int tl = idx >> 5, dd = idx & 31;
            tile[tl][dd] = xb[(size_t)tl * D + dc * 32 + dd];
        }
        __syncthreads();
        #pragma unroll
        for (int dd = 0; dd < 32; ++dd) {
            float xval = tile[tid][dd];
            const float* wrow = Wa1 + (dc * 32 + dd) * HID;   // wave-uniform -> s_load
            #pragma unroll
            for (int h = 0; h < HID; ++h) acc[h] += xval * wrow[h];
        }
    }
    float lg = ba2[0];
    #pragma unroll
    for (int h = 0; h < HID; ++h) lg += tanhf(acc[h] + ba1[h]) * Wa2[h];
    logit[(size_t)b * T + t0 + tid] = lg;
}

// ---------------- softmax max & denominator over T ----------------
__global__ __launch_bounds__(256) void k_smax(const float* __restrict__ logit, float* __restrict__ smz) {
    int b = blockIdx.x, tid = threadIdx.x;
    __shared__ float sm[256];
    __shared__ double sz[256];
    float mx = -1e30f;
    for (int i = tid; i < T; i += 256) mx = fmaxf(mx, logit[(size_t)b * T + i]);
    sm[tid] = mx; __syncthreads();
    for (int o = 128; o > 0; o >>= 1) { if (tid < o) sm[tid] = fmaxf(sm[tid], sm[tid + o]); __syncthreads(); }
    float m = sm[0];
    double z = 0;
    for (int i = tid; i < T; i += 256) z += (double)expf(logit[(size_t)b * T + i] - m);
    sz[tid] = z; __syncthreads();
    for (int o = 128; o > 0; o >>= 1) { if (tid < o) sz[tid] += sz[tid + o]; __syncthreads(); }
    if (tid == 0) { smz[b * 2] = m; smz[b * 2 + 1] = (float)sz[0]; }
}

// ---------------- fused: attention pooling + mean_corr y-pass ----------------
__global__ __launch_bounds__(256) void k_pool(const float* __restrict__ x,
        const float* __restrict__ logit, const float* __restrict__ smz,
        const float* __restrict__ mu, const float* __restrict__ winv,
        float* __restrict__ hpool, double* __restrict__ accum) {
    int bid = blockIdx.x;
    int b = bid >> 3, t0 = (bid & 7) * 256;
    int wave = threadIdx.x >> 6, lane = threadIdx.x & 63;
    const float* xb = x + (size_t)b * T * D;
    float m = smz[b * 2], Z = smz[b * 2 + 1];
    float4 mu4 = *(const float4*)(mu + b * D + lane * 4);
    float4 w4 = *(const float4*)(winv + b * D + lane * 4);
    double p0 = 0, p1 = 0, p2 = 0, p3 = 0, yacc = 0;
    for (int r = 0; r < 64; ++r) {
        int t = t0 + wave * 64 + r;
        float4 xv = *(const float4*)(xb + (size_t)t * D + lane * 4);
        float wt = expf(logit[(size_t)b * T + t] - m) / Z;
        p0 += (double)(wt * xv.x); p1 += (double)(wt * xv.y);
        p2 += (double)(wt * xv.z); p3 += (double)(wt * xv.w);
        double y = (double)((xv.x - mu4.x) * w4.x) + (double)((xv.y - mu4.y) * w4.y)
                 + (double)((xv.z - mu4.z) * w4.z) + (double)((xv.w - mu4.w) * w4.w);
        for (int o = 32; o > 0; o >>= 1) y += __shfl_down(y, o);
        if (lane == 0) yacc += y * y;
    }
    if (lane == 0) atomicAdd(&accum[b * A_N + A_Y2], yacc);
    atomicAdd(&hpool[b * D + lane * 4 + 0], (float)p0);
    atomicAdd(&hpool[b * D + lane * 4 + 1], (float)p1);
    atomicAdd(&hpool[b * D + lane * 4 + 2], (float)p2);
    atomicAdd(&hpool[b * D + lane * 4 + 3], (float)p3);
}

// ---------------- routing head MLP + softmax(logits/temp) ----------------
__global__ void k_route(const float* __restrict__ hpool,
        const float* __restrict__ Wr1, const float* __restrict__ br1,
        const float* __restrict__ Wr2, const float* __restrict__ br2,
        const float* __restrict__ Wr3, const float* __restrict__ br3,
        const float* __restrict__ temperature, float* __restrict__ alpha) {
    int b = blockIdx.x, tid = threadIdx.x;   // 64 threads
    __shared__ float z1[HID], z2[HID], hp[D];
    for (int i = tid; i < D; i += 64) hp[i] = hpool[b * D + i];
    __syncthreads();
    if (tid < HID) {
        float a = br1[tid];
        for (int d = 0; d < D; ++d) a += hp[d] * Wr1[d * HID + tid];
        z1[tid] = fmaxf(a, 0.f);
    }
    __syncthreads();
    if (tid < HID) {
        float a = br2[tid];
        for (int j = 0; j < HID; ++j) a += z1[j] * Wr2[j * HID + tid];
        z2[tid] = fmaxf(a, 0.f);
    }
    __syncthreads();
    if (tid == 0) {
        float tmp = temperature[0];
        tmp = fminf(fmaxf(tmp, 0.5f), 2.0f);
        float lg[3];
        for (int k = 0; k < 3; ++k) {
            float a = br3[k];
            for (int j = 0; j < HID; ++j) a += z2[j] * Wr3[j * 3 + k];
            lg[k] = a / tmp;
        }
        float mx = fmaxf(lg[0], fmaxf(lg[1], lg[2]));
        float e0 = expf(lg[0] - mx), e1 = expf(lg[1] - mx), e2 = expf(lg[2] - mx);
        float s = e0 + e1 + e2;
        alpha[b * 3 + 0] = e0 / s; alpha[b * 3 + 1] = e1 / s; alpha[b * 3 + 2] = e2 / s;
    }
}

// ---------------- xm-based stats + scalar finalize ----------------
__global__ __launch_bounds__(256) void k_xmstats(const double* __restrict__ xm,
        const float* __restrict__ rowm, const double* __restrict__ accum,
        float* __restrict__ stats) {
    int b = blockIdx.x, tid = threadIdx.x;
    __shared__ double xs[T];
    __shared__ double r0[256], r1[256], r2[256];
    __shared__ int i0[256], i1[256];
    const double* xmb = xm + (size_t)b * T;
    for (int i = tid; i < T; i += 256) xs[i] = xmb[i];
    __syncthreads();
    double ls = 0;
    for (int i = tid; i < T; i += 256) ls += xs[i];
    r0[tid] = ls; __syncthreads();
    for (int o = 128; o > 0; o >>= 1) { if (tid < o) r0[tid] += r0[tid + o]; __syncthreads(); }
    double xmean = r0[0] / (double)T;
    __syncthreads();
    double tn = 0, roc = 0; int pk = 0, zc = 0;
    for (int i = tid; i < T; i += 256) {
        tn += ((double)i - 1023.5) * (xs[i] - xmean);
        if (i <= T - 2) {
            double d1 = xs[i + 1] - xs[i];
            roc += fabs(d1);
            if (i >= 1) { double d0 = xs[i] - xs[i - 1]; if (d0 * d1 < 0.0) pk++; }
            if ((xs[i] - xmean) * (xs[i + 1] - xmean) < 0.0) zc++;
        }
    }
    r0[tid] = tn; r1[tid] = roc; i0[tid] = pk; i1[tid] = zc; __syncthreads();
    for (int o = 128; o > 0; o >>= 1) {
        if (tid < o) { r0[tid] += r0[tid + o]; r1[tid] += r1[tid + o]; i0[tid] += i0[tid + o]; i1[tid] += i1[tid + o]; }
        __syncthreads();
    }
    double trendnum = r0[0], rocsum = r1[0];
    int pks = i0[0], zcs = i1[0];
    __syncthreads();
    double ds = 0, ds2 = 0, obs = 0; int ft = T;
    for (int i = tid; i < T; i += 256) {
        double rm = (double)rowm[(size_t)b * T + i];
        obs += rm;
        double dn = rm / (256.0 + EPS);
        ds += dn; ds2 += dn * dn;
        if (rm > 0.0 && i < ft) ft = i;
    }
    r0[tid] = ds; r1[tid] = ds2; r2[tid] = obs; i0[tid] = ft; __syncthreads();
    for (int o = 128; o > 0; o >>= 1) {
        if (tid < o) { r0[tid] += r0[tid + o]; r1[tid] += r1[tid + o]; r2[tid] += r2[tid + o]; i0[tid] = min(i0[tid], i0[tid + o]); }
        __syncthreads();
    }
    if (tid == 0) {
        double dsum = r0[0], dsq = r1[0], obst = r2[0]; int ftt = i0[0];
        const double n = (double)T * (double)D;
        const double* ab = accum + b * A_N;
        double s1 = ab[A_S1], s2 = ab[A_S2], s3 = ab[A_S3], s4 = ab[A_S4];
        double acv = ab[A_AC], y2 = ab[A_Y2], dg = ab[A_DIAG];
        double mu_ = s1 / n;
        double m2 = s2 / n - mu_ * mu_;
        double m3 = s3 / n - 3.0 * mu_ * (s2 / n) + 2.0 * mu_ * mu_ * mu_;
        double m4 = s4 / n - 4.0 * mu_ * (s3 / n) + 6.0 * mu_ * mu_ * (s2 / n) - 3.0 * mu_ * mu_ * mu_ * mu_;
        float* st = stats + b * 17;
        st[0] = (float)(acv / ((double)(T - 1) * (double)D));
        st[1] = (float)(trendnum / (715827712.0 + EPS));
        st[4] = (float)(m3 / (sqrt(m2) * m2 + EPS));
        st[5] = (float)(m4 / (m2 * m2 + EPS));
        st[9] = (float)((double)pks / (double)(T - 2));
        st[10] = (float)((double)zcs / (double)(T - 1));
        st[11] = (float)(rocsum / (double)(T - 1));
        st[12] = (float)(1.0 - obst / ((double)T * (double)D + EPS));
        double dmean = dsum / (double)T;
        st[13] = (float)((dsq - dsum * dmean) / (double)(T - 1));
        st[14] = (ftt < T) ? (float)((double)ftt / (double)T) : 0.0f;
        st[15] = (float)((y2 / ((double)(T - 1) + EPS) - dg) / ((double)D * (D - 1) + EPS));
    }
}

// ---------------- DFT of xm (exact angles, f64 accumulation) ----------------
__global__ __launch_bounds__(256) void k_dft(const double* __restrict__ xm, double* __restrict__ power) {
    __shared__ double xs[T];
    __shared__ double ctab[T];
    __shared__ double stab[T];
    int b = blockIdx.x / 5, kc = blockIdx.x % 5;
    int tid = threadIdx.x;
    for (int i = tid; i < T; i += 256) {
        xs[i] = xm[(size_t)b * T + i];
        double ang = -6.283185307179586476925286766559 * (double)i / (double)T;
        ctab[i] = cos(ang); stab[i] = sin(ang);
    }
    __syncthreads();
    int k = kc * 256 + tid;
    if (k <= T / 2) {
        double ar = 0, ai = 0;
        int idx = 0;
        for (int t = 0; t < T; ++t) {
            double xv = xs[t];
            ar += xv * ctab[idx];
            ai += xv * stab[idx];
            idx = (idx + k) & (T - 1);
        }
        power[(size_t)b * 1025 + k] = ar * ar + ai * ai;
    }
}

// ---------------- spectral: argmax + entropy ----------------
__global__ __launch_bounds__(256) void k_spec(const double* __restrict__ power, float* __restrict__ stats) {
    int b = blockIdx.x, tid = threadIdx.x;
    __shared__ double rv[256];
    __shared__ int ri[256];
    const double* pb = power + (size_t)b * 1025;
    double bm = -1.0; int bi = 0; double lsum = 0;
    for (int i = tid; i < 1025; i += 256) {
        double p = pb[i];
        lsum += p;
        if (p > bm) { bm = p; bi = i; }
    }
    rv[tid] = bm; ri[tid] = bi; __syncthreads();
    for (int o = 128; o > 0; o >>= 1) {
        if (tid < o) {
            if (rv[tid + o] > rv[tid] || (rv[tid + o] == rv[tid] && ri[tid + o] < ri[tid])) {
                rv[tid] = rv[tid + o]; ri[tid] = ri[tid + o];
            }
        }
        __syncthreads();
    }
    int amax = ri[0];
    __syncthreads();
    rv[tid] = lsum; __syncthreads();
    for (int o = 128; o > 0; o >>= 1) { if (tid < o) rv[tid] += rv[tid + o]; __syncthreads(); }
    double S = rv[0] + EPS;
    __syncthreads();
    double le = 0;
    for (int i = tid; i < 1025; i += 256) {
        double pn = pb[i] / S;
        le -= pn * log(pn + EPS);
    }
    rv[tid] = le; __syncthreads();
    for (int o = 128; o > 0; o >>= 1) { if (tid < o) rv[tid] += rv[tid + o]; __syncthreads(); }
    if (tid == 0) {
        stats[b * 17 + 2] = (float)((double)amax / (double)(T / 2));
        stats[b * 17 + 3] = (float)rv[0];
    }
}

// ---------------- quantiles: 13-bit histogram ----------------
__global__ __launch_bounds__(256) void k_histA(const float* __restrict__ x, unsigned int* __restrict__ hist) {
    __shared__ unsigned int lh[NBIN];   // 32 KB
    int b = blockIdx.x >> 2, chunk = blockIdx.x & 3;
    int tid = threadIdx.x;
    for (int i = tid; i < NBIN; i += 256) lh[i] = 0;
    __syncthreads();
    const float4* xb = (const float4*)(x + (size_t)b * T * D + (size_t)chunk * (T * D / 4));
    for (int i = tid; i < T * D / 16; i += 256) {
        float4 v = xb[i];
        atomicAdd(&lh[f2key(v.x) >> 19], 1u);
        atomicAdd(&lh[f2key(v.y) >> 19], 1u);
        atomicAdd(&lh[f2key(v.z) >> 19], 1u);
        atomicAdd(&lh[f2key(v.w) >> 19], 1u);
    }
    __syncthreads();
    for (int i = tid; i < NBIN; i += 256)
        if (lh[i]) atomicAdd(&hist[(size_t)b * NBIN + i], lh[i]);
}

// ---------------- quantiles: locate bin + within-bin rank for each target ----------------
__global__ __launch_bounds__(256) void k_histB(const unsigned int* __restrict__ hist,
        unsigned int* __restrict__ binsel, unsigned int* __restrict__ krem) {
    int b = blockIdx.x, tid = threadIdx.x;
    __shared__ unsigned int seg[256], base[256];
    const unsigned int* hb = hist + (size_t)b * NBIN;
    unsigned int s = 0;
    for (int i = 0; i < 32; ++i) s += hb[tid * 32 + i];
    seg[tid] = s; __syncthreads();
    if (tid == 0) {
        unsigned int run = 0;
        for (int i = 0; i < 256; ++i) { base[i] = run; run += seg[i]; }
    }
    __syncthreads();
    const unsigned int targets[NSEL] = {131071u, 131072u, 262143u, 262144u, 393215u, 393216u};
    for (int q = 0; q < NSEL; ++q) {
        unsigned int k = targets[q];
        if (k >= base[tid] && k < base[tid] + seg[tid]) {
            unsigned int run = base[tid];
            for (int i = 0; i < 32; ++i) {
                unsigned int c = hb[tid * 32 + i];
                if (k < run + c) { binsel[b * NSEL + q] = tid * 32 + i; krem[b * NSEL + q] = k - run; break; }
                run += c;
            }
        }
    }
}

// ---------------- quantiles: compact candidates for the 6 selected bins ----------------
__global__ __launch_bounds__(256) void k_compact(const float* __restrict__ x,
        const unsigned int* __restrict__ binsel, unsigned int* __restrict__ ccnt,
        unsigned int* __restrict__ cand) {
    int b = blockIdx.x >> 4, chunk = blockIdx.x & 15;
    unsigned int bs[NSEL];
    #pragma unroll
    for (int q = 0; q < NSEL; ++q) bs[q] = binsel[b * NSEL + q];
    const float4* xb = (const float4*)(x + (size_t)b * T * D + (size_t)chunk * (T * D / 16));
    for (int i = threadIdx.x; i < T * D / 64; i += 256) {
        float4 v = xb[i];
        float va[4] = {v.x, v.y, v.z, v.w};
        #pragma unroll
        for (int j = 0; j < 4; ++j) {
            unsigned int u = f2key(va[j]);
            unsigned int bin = u >> 19;
            #pragma unroll
            for (int q = 0; q < NSEL; ++q) {
                if (bin == bs[q]) {
                    unsigned int p = atomicAdd(&ccnt[b * NSEL + q], 1u);
                    if (p < CAP) cand[((size_t)b * NSEL + q) * CAP + p] = u;
                }
            }
        }
    }
}

// ---------------- quantiles: bitwise exact select of k-th smallest within bin ----------------
__global__ __launch_bounds__(256) void k_select(const unsigned int* __restrict__ cand,
        const unsigned int* __restrict__ ccnt, const unsigned int* __restrict__ binsel,
        const unsigned int* __restrict__ krem, float* __restrict__ qv) {
    int b = blockIdx.x / NSEL, q = blockIdx.x % NSEL;
    int tid = threadIdx.x;
    __shared__ unsigned int lc[CAP];   // 32 KB
    __shared__ unsigned int rc[256];
    unsigned int n = ccnt[b * NSEL + q];
    if (n > CAP) n = CAP;
    for (unsigned int i = tid; i < n; i += 256) lc[i] = cand[((size_t)b * NSEL + q) * CAP + i];
    __syncthreads();
    unsigned int prefix = binsel[b * NSEL + q] << 19;
    unsigned int k = krem[b * NSEL + q];
    for (int bit = 18; bit >= 0; --bit) {
        unsigned int hi = prefix >> (bit + 1);
        unsigned int c = 0;
        for (unsigned int i = tid; i < n; i += 256) {
            unsigned int u = lc[i];
            if ((u >> (bit + 1)) == hi && !((u >> bit) & 1u)) c++;
        }
        rc[tid] = c; __syncthreads();
        for (int o = 128; o > 0; o >>= 1) { if (tid < o) rc[tid] += rc[tid + o]; __syncthreads(); }
        unsigned int c0 = rc[0];
        __syncthreads();
        if (k >= c0) { k -= c0; prefix |= (1u << bit); }
    }
    if (tid == 0) qv[b * NSEL + q] = key2f(prefix);
}

// ---------------- quantile interpolation -> stats ----------------
__global__ void k_qwrite(const float* __restrict__ qv, float* __restrict__ stats) {
    int b = threadIdx.x;
    if (b >= B) return;
    const float* qq = qv + b * NSEL;
    double q25 = 0.25 * (double)qq[0] + 0.75 * (double)qq[1];
    double q50 = 0.5 * ((double)qq[2] + (double)qq[3]);
    double q75 = 0.75 * (double)qq[4] + 0.25 * (double)qq[5];
    stats[b * 17 + 6] = (float)q25;
    stats[b * 17 + 7] = (float)q50;
    stats[b * 17 + 8] = (float)q75;
}

// ---------------- gram = Xc^T Xc (fp32 tiled GEMM, 64x64 tiles) ----------------
__global__ __launch_bounds__(256) void k_gram(const float* __restrict__ x, const float* __restrict__ mu,
        float* __restrict__ gram) {
    __shared__ __align__(16) float As[32][64];
    __shared__ __align__(16) float Bs[32][64];
    int bid = blockIdx.x;
    int b = bid >> 4, tile = bid & 15;
    int R0 = (tile >> 2) * 64, C0 = (tile & 3) * 64;
    int tid = threadIdx.x;
    const float* xb = x + (size_t)b * T * D;
    int cg = tid & 15;
    float4 muAv = *(const float4*)(mu + b * D + R0 + cg * 4);
    float4 muBv = *(const float4*)(mu + b * D + C0 + cg * 4);
    float accv[4][4];
    #pragma unroll
    for (int i = 0; i < 4; ++i)
        #pragma unroll
        for (int j = 0; j < 4; ++j) accv[i][j] = 0.f;
    int tr = (tid & 15) * 4;
    int tc = (tid >> 4) * 4;
    for (int t0 = 0; t0 < T; t0 += 32) {
        __syncthreads();
        #pragma unroll
        for (int i = 0; i < 2; ++i) {
            int kk = i * 16 + (tid >> 4);
            float4 a = *(const float4*)(xb + (size_t)(t0 + kk) * D + R0 + cg * 4);
            a.x -= muAv.x; a.y -= muAv.y; a.z -= muAv.z; a.w -= muAv.w;
            *(float4*)&As[kk][cg * 4] = a;
            float4 c = *(const float4*)(xb + (size_t)(t0 + kk) * D + C0 + cg * 4);
            c.x -= muBv.x; c.y -= muBv.y; c.z -= muBv.z; c.w -= muBv.w;
            *(float4*)&Bs[kk][cg * 4] = c;
        }
        __syncthreads();
        #pragma unroll
        for (int kk = 0; kk < 32; ++kk) {
            float4 av = *(const float4*)&As[kk][tr];
            float4 bv = *(const float4*)&Bs[kk][tc];
            float aa[4] = {av.x, av.y, av.z, av.w};
            float bb[4] = {bv.x, bv.y, bv.z, bv.w};
            #pragma unroll
            for (int i = 0; i < 4; ++i)
                #pragma unroll
                for (int j = 0; j < 4; ++j) accv[i][j] += aa[i] * bb[j];
        }
    }
    float* gb = gram + (size_t)b * D * D;
    #pragma unroll
    for (int i = 0; i < 4; ++i) {
        float4 o4 = {accv[i][0], accv[i][1], accv[i][2], accv[i][3]};
        *(float4*)(gb + (size_t)(R0 + tr + i) * D + C0 + tc) = o4;
    }
}

// ---------------- power iteration for lambda_max -> var_exp ----------------
__global__ __launch_bounds__(1024) void k_power(const float* __restrict__ gram,
        const double* __restrict__ accum, float* __restrict__ stats) {
    int b = blockIdx.x;
    int tid = threadIdx.x;
    int row = tid & 255, sl = tid >> 8;   // 4 column-slices of 64
    __shared__ __align__(16) float v[2][D];
    __shared__ float part[1024];
    __shared__ double dpart[1024];
    const float* g = gram + (size_t)b * D * D + (size_t)row * D + sl * 64;
    float gr[64];
    #pragma unroll
    for (int j = 0; j < 64; j += 4) {
        float4 t4 = *(const float4*)(g + j);
        gr[j] = t4.x; gr[j + 1] = t4.y; gr[j + 2] = t4.z; gr[j + 3] = t4.w;
    }
    if (tid < D) {
        float h = sinf((float)tid * 12.9898f) * 43758.547f;
        v[0][tid] = h - floorf(h) - 0.4375f;
    }
    __syncthreads();
    int cur = 0;
    for (int it = 0; it < NAPPLY; ++it) {
        const float* vv = &v[cur][sl * 64];
        float acc = 0.f;
        #pragma unroll
        for (int j = 0; j < 64; j += 4) {
            float4 vb = *(const float4*)(vv + j);
            acc += gr[j] * vb.x + gr[j + 1] * vb.y + gr[j + 2] * vb.z + gr[j + 3] * vb.w;
        }
        part[tid] = acc; __syncthreads();
        if (tid < D) v[cur ^ 1][tid] = part[tid] + part[tid + 256] + part[tid + 512] + part[tid + 768];
        cur ^= 1;
        if ((it & 7) == 7 || it == NAPPLY - 1) {
            __syncthreads();
            double nl = 0;
            if (tid < D) { double yv = (double)v[cur][tid]; nl = yv * yv; }
            dpart[tid] = nl; __syncthreads();
            for (int o = 512; o > 0; o >>= 1) { if (tid < o) dpart[tid] += dpart[tid + o]; __syncthreads(); }
            float inv = (float)(1.0 / sqrt(dpart[0]));
            __syncthreads();
            if (tid < D) v[cur][tid] *= inv;
        }
        __syncthreads();
    }
    // Rayleigh quotient
    const float* vv = &v[cur][sl * 64];
    float acc = 0.f;
    #pragma unroll
    for (int j = 0; j < 64; j += 4) {
        float4 vb = *(const float4*)(vv + j);
        acc += gr[j] * vb.x + gr[j + 1] * vb.y + gr[j + 2] * vb.z + gr[j + 3] * vb.w;
    }
    part[tid] = acc; __syncthreads();
    double num = 0, den = 0;
    if (tid < D) {
        double w = (double)part[tid] + (double)part[tid + 256] + (double)part[tid + 512] + (double)part[tid + 768];
        double vd = (double)v[cur][tid];
        num = vd * w; den = vd * vd;
    }
    dpart[tid] = num; __syncthreads();
    for (int o = 512; o > 0; o >>= 1) { if (tid < o) dpart[tid] += dpart[tid + o]; __syncthreads(); }
    double lam = dpart[0];
    __syncthreads();
    dpart[tid] = den; __syncthreads();
    for (int o = 512; o > 0; o >>= 1) { if (tid < o) dpart[tid] += dpart[tid + o]; __syncthreads(); }
    if (tid == 0) {
        double trace = accum[b * A_N + A_TRACE];
        stats[b * 17 + 16] = (float)(lam / dpart[0] / trace);
    }
}

// ---------------- host launcher ----------------
extern "C" void kernel_launch(void* const* d_in, const int* in_sizes, int n_in,
                              void* d_out, int out_size, void* d_ws, size_t ws_size,
                              hipStream_t stream) {
    (void)in_sizes; (void)n_in; (void)ws_size;
    const float* x    = (const float*)d_in[0];
    const int*   mask = (const int*)d_in[1];
    const float* Wa1  = (const float*)d_in[2];
    const float* ba1  = (const float*)d_in[3];
    const float* Wa2  = (const float*)d_in[4];
    const float* ba2  = (const float*)d_in[5];
    const float* Wr1  = (const float*)d_in[6];
    const float* br1  = (const float*)d_in[7];
    const float* Wr2  = (const float*)d_in[8];
    const float* br2  = (const float*)d_in[9];
    const float* Wr3  = (const float*)d_in[10];
    const float* br3  = (const float*)d_in[11];
    const float* temp = (const float*)d_in[12];

    float* out = (float*)d_out;
    float* alpha = out;                 // 64*3
    float* hpool = out + 192;           // 64*256
    float* stats = out + 192 + 16384;   // 64*17

    char* w = (char*)d_ws;
    size_t off = 0;
    auto alloc = [&](size_t bytes) -> char* {
        char* p = w + off;
        off = (off + bytes + 255) & ~(size_t)255;
        return p;
    };
    // zeroed region first
    double* cs1 = (double*)alloc((size_t)B * D * 8);
    double* cs2 = (double*)alloc((size_t)B * D * 8);
    double* accum = (double*)alloc((size_t)B * A_N * 8);
    unsigned int* ccnt = (unsigned int*)alloc((size_t)B * NSEL * 4);
    unsigned int* hist = (unsigned int*)alloc((size_t)B * NBIN * 4);
    size_t zero_bytes = off;
    // non-zeroed
    double* xm = (double*)alloc((size_t)B * T * 8);
    float* rowm = (float*)alloc((size_t)B * T * 4);
    float* logit = (float*)alloc((size_t)B * T * 4);
    float* smz = (float*)alloc((size_t)B * 2 * 4);
    float* mu = (float*)alloc((size_t)B * D * 4);
    float* winv = (float*)alloc((size_t)B * D * 4);
    double* power = (double*)alloc((size_t)B * 1025 * 8);
    unsigned int* binsel = (unsigned int*)alloc((size_t)B * NSEL * 4);
    unsigned int* krem = (unsigned int*)alloc((size_t)B * NSEL * 4);
    float* qv = (float*)alloc((size_t)B * NSEL * 4);
    // cand (12.6MB) and gram (16.8MB) are temporally disjoint: cand dead after
    // k_select, gram written after -> alias them in one union region.
    size_t union_bytes = (size_t)B * D * D * 4;   // 16.8MB >= cand's 12.6MB
    char* ureg = alloc(union_bytes);
    unsigned int* cand = (unsigned int*)ureg;
    float* gram = (float*)ureg;

    hipMemsetAsync(d_ws, 0, zero_bytes, stream);
    hipMemsetAsync(d_out, 0, (size_t)out_size * 4, stream);

    k_pass1<<<B * 16, 256, 0, stream>>>(x, mask, xm, rowm, cs1, cs2, accum);
    k_chan<<<B, 256, 0, stream>>>(cs1, cs2, mu, winv, accum);
    k_attn<<<B * 8, 256, 0, stream>>>(x, Wa1, ba1, Wa2, ba2, logit);
    k_smax<<<B, 256, 0, stream>>>(logit, smz);
    k_pool<<<B * 8, 256, 0, stream>>>(x, logit, smz, mu, winv, hpool, accum);
    k_route<<<B, 64, 0, stream>>>(hpool, Wr1, br1, Wr2, br2, Wr3, br3, temp, alpha);
    k_xmstats<<<B, 256, 0, stream>>>(xm, rowm, accum, stats);
    k_dft<<<B * 5, 256, 0, stream>>>(xm, power);
    k_spec<<<B, 256, 0, stream>>>(power, stats);
    k_histA<<<B * 4, 256, 0, stream>>>(x, hist);
    k_histB<<<B, 256, 0, stream>>>(hist, binsel, krem);
    k_compact<<<B * 16, 256, 0, stream>>>(x, binsel, ccnt, cand);
    k_select<<<B * NSEL, 256, 0, stream>>>(cand, ccnt, binsel, krem, qv);
    k_qwrite<<<1, 64, 0, stream>>>(qv, stats);
    k_gram<<<B * 16, 256, 0, stream>>>(x, mu, gram);
    k_power<<<B, 1024, 0, stream>>>(gram, accum, stats);
}

// Round 2
// 1456.186 us; speedup vs baseline: 1.4860x; 1.4860x over previous
//
#include <hip/hip_runtime.h>
#include <math.h>
#include <stdint.h>

#define B 64
#define T 2048
#define D 256
#define HID 32
#define NSEL 6
#define NBIN 8192      // 13-bit bins: sign + 8 exp + 4 mantissa
#define CAP 8192
#define LCAP 2048      // per-block per-bin LDS candidate capacity
#define EPS 1e-8

// accum slots per batch (stride 16 doubles)
#define A_S1 0
#define A_S2 1
#define A_S3 2
#define A_S4 3
#define A_AC 4
#define A_Y2 5
#define A_DIAG 6
#define A_TRACE 7
#define A_N 16

#define NAPPLY 320

// ---------------- sortable float keys ----------------
__device__ __forceinline__ unsigned int f2key(float f) {
    unsigned int u = __float_as_uint(f);
    return (u & 0x80000000u) ? ~u : (u | 0x80000000u);
}
__device__ __forceinline__ float key2f(unsigned int k) {
    unsigned int u = (k & 0x80000000u) ? (k ^ 0x80000000u) : ~k;
    return __uint_as_float(u);
}

// ---------------- pass1: fused moments / autocorr / row means / mask / channel sums ----------------
__global__ __launch_bounds__(256) void k_pass1(const float* __restrict__ x, const int* __restrict__ mask,
        double* __restrict__ xm, float* __restrict__ rowm,
        double* __restrict__ cs1, double* __restrict__ cs2, double* __restrict__ accum) {
    int b = blockIdx.x >> 4;
    int blk = blockIdx.x & 15;
    int wave = threadIdx.x >> 6;
    int lane = threadIdx.x & 63;
    int ts = blk * 128 + wave * 32;
    const float* xb = x + (size_t)b * T * D;
    const int* mb = mask + (size_t)b * T * D;
    double c1l[4] = {0, 0, 0, 0}, c2l[4] = {0, 0, 0, 0};
    double s1 = 0, s2 = 0, s3 = 0, s4 = 0, ac = 0;
    float pa[4] = {0, 0, 0, 0};
    for (int r = 0; r < 32; ++r) {
        int t = ts + r;
        float4 xv = *(const float4*)(xb + (size_t)t * D + lane * 4);
        int4 mv = *(const int4*)(mb + (size_t)t * D + lane * 4);
        double rs = (double)xv.x + (double)xv.y + (double)xv.z + (double)xv.w;
        int rm = mv.x + mv.y + mv.z + mv.w;
        for (int o = 32; o > 0; o >>= 1) { rs += __shfl_down(rs, o); rm += __shfl_down(rm, o); }
        if (lane == 0) {
            xm[(size_t)b * T + t] = rs * (1.0 / 256.0);
            rowm[(size_t)b * T + t] = (float)rm;
        }
        float xa[4] = {xv.x, xv.y, xv.z, xv.w};
        #pragma unroll
        for (int j = 0; j < 4; ++j) {
            double xd = (double)xa[j];
            double x2 = xd * xd;
            s1 += xd; s2 += x2; s3 += x2 * xd; s4 += x2 * x2;
            c1l[j] += xd; c2l[j] += x2;
        }
        if (r > 0) {
            #pragma unroll
            for (int j = 0; j < 4; ++j) ac += (double)pa[j] * (double)xa[j];
        }
        pa[0] = xa[0]; pa[1] = xa[1]; pa[2] = xa[2]; pa[3] = xa[3];
    }
    if (ts + 32 <= T - 1) {
        float4 xn = *(const float4*)(xb + (size_t)(ts + 32) * D + lane * 4);
        float na[4] = {xn.x, xn.y, xn.z, xn.w};
        #pragma unroll
        for (int j = 0; j < 4; ++j) ac += (double)pa[j] * (double)na[j];
    }
    for (int o = 32; o > 0; o >>= 1) {
        s1 += __shfl_down(s1, o); s2 += __shfl_down(s2, o);
        s3 += __shfl_down(s3, o); s4 += __shfl_down(s4, o);
        ac += __shfl_down(ac, o);
    }
    if (lane == 0) {
        atomicAdd(&accum[b * A_N + A_S1], s1);
        atomicAdd(&accum[b * A_N + A_S2], s2);
        atomicAdd(&accum[b * A_N + A_S3], s3);
        atomicAdd(&accum[b * A_N + A_S4], s4);
        atomicAdd(&accum[b * A_N + A_AC], ac);
    }
    #pragma unroll
    for (int j = 0; j < 4; ++j) {
        atomicAdd(&cs1[b * D + lane * 4 + j], c1l[j]);
        atomicAdd(&cs2[b * D + lane * 4 + j], c2l[j]);
    }
}

// ---------------- per-channel finalize: mu, 1/std, diag-corr sum, trace ----------------
__global__ __launch_bounds__(256) void k_chan(const double* __restrict__ cs1, const double* __restrict__ cs2,
        float* __restrict__ mu, float* __restrict__ winv, double* __restrict__ accum) {
    int b = blockIdx.x, d = threadIdx.x;
    double c1 = cs1[b * D + d], c2 = cs2[b * D + d];
    double m = c1 / (double)T;
    double c2c = c2 - c1 * c1 / (double)T;
    double var = c2c / (double)(T - 1);
    mu[b * D + d] = (float)m;
    winv[b * D + d] = (float)(1.0 / sqrt(var));
    double diag = (c2c / ((double)(T - 1) + EPS)) / (var + EPS);
    __shared__ double sd[256], st[256];
    sd[d] = diag; st[d] = c2c; __syncthreads();
    for (int o = 128; o > 0; o >>= 1) {
        if (d < o) { sd[d] += sd[d + o]; st[d] += st[d + o]; }
        __syncthreads();
    }
    if (d == 0) { accum[b * A_N + A_DIAG] = sd[0]; accum[b * A_N + A_TRACE] = st[0]; }
}

// ---------------- attention logits: tanh(x@Wa1+ba1)@Wa2+ba2 ----------------
__global__ __launch_bounds__(256) void k_attn(const float* __restrict__ x,
        const float* __restrict__ Wa1, const float* __restrict__ ba1,
        const float* __restrict__ Wa2, const float* __restrict__ ba2,
        float* __restrict__ logit) {
    __shared__ float tile[256][33];   // +1 pad: conflict-free column reads
    int bid = blockIdx.x;
    int b = bid >> 3, t0 = (bid & 7) * 256;
    int tid = threadIdx.x;
    const float* xb = x + (size_t)b * T * D + (size_t)t0 * D;
    float acc[HID];
    #pragma unroll
    for (int h = 0; h < HID; ++h) acc[h] = 0.f;
    for (int dc = 0; dc < 8; ++dc) {
        __syncthreads();
        #pragma unroll
        for (int i = 0; i < 32; ++i) {
            int idx = i * 256 + tid;
            int tl = idx >> 5, dd = idx & 31;
            tile[tl][dd] = xb[(size_t)tl * D + dc * 32 + dd];
        }
        __syncthreads();
        #pragma unroll
        for (int dd = 0; dd < 32; ++dd) {
            float xval = tile[tid][dd];
            const float* wrow = Wa1 + (dc * 32 + dd) * HID;   // wave-uniform -> s_load
            #pragma unroll
            for (int h = 0; h < HID; ++h) acc[h] += xval * wrow[h];
        }
    }
    float lg = ba2[0];
    #pragma unroll
    for (int h = 0; h < HID; ++h) lg += tanhf(acc[h] + ba1[h]) * Wa2[h];
    logit[(size_t)b * T + t0 + tid] = lg;
}

// ---------------- softmax max & denominator over T ----------------
__global__ __launch_bounds__(256) void k_smax(const float* __restrict__ logit, float* __restrict__ smz) {
    int b = blockIdx.x, tid = threadIdx.x;
    __shared__ float sm[256];
    __shared__ double sz[256];
    float mx = -1e30f;
    for (int i = tid; i < T; i += 256) mx = fmaxf(mx, logit[(size_t)b * T + i]);
    sm[tid] = mx; __syncthreads();
    for (int o = 128; o > 0; o >>= 1) { if (tid < o) sm[tid] = fmaxf(sm[tid], sm[tid + o]); __syncthreads(); }
    float m = sm[0];
    double z = 0;
    for (int i = tid; i < T; i += 256) z += (double)expf(logit[(size_t)b * T + i] - m);
    sz[tid] = z; __syncthreads();
    for (int o = 128; o > 0; o >>= 1) { if (tid < o) sz[tid] += sz[tid + o]; __syncthreads(); }
    if (tid == 0) { smz[b * 2] = m; smz[b * 2 + 1] = (float)sz[0]; }
}

// ---------------- fused: attention pooling + mean_corr y-pass ----------------
__global__ __launch_bounds__(256) void k_pool(const float* __restrict__ x,
        const float* __restrict__ logit, const float* __restrict__ smz,
        const float* __restrict__ mu, const float* __restrict__ winv,
        float* __restrict__ hpool, double* __restrict__ accum) {
    int bid = blockIdx.x;
    int b = bid >> 3, t0 = (bid & 7) * 256;
    int wave = threadIdx.x >> 6, lane = threadIdx.x & 63;
    const float* xb = x + (size_t)b * T * D;
    float m = smz[b * 2], Z = smz[b * 2 + 1];
    float4 mu4 = *(const float4*)(mu + b * D + lane * 4);
    float4 w4 = *(const float4*)(winv + b * D + lane * 4);
    double p0 = 0, p1 = 0, p2 = 0, p3 = 0, yacc = 0;
    for (int r = 0; r < 64; ++r) {
        int t = t0 + wave * 64 + r;
        float4 xv = *(const float4*)(xb + (size_t)t * D + lane * 4);
        float wt = expf(logit[(size_t)b * T + t] - m) / Z;
        p0 += (double)(wt * xv.x); p1 += (double)(wt * xv.y);
        p2 += (double)(wt * xv.z); p3 += (double)(wt * xv.w);
        double y = (double)((xv.x - mu4.x) * w4.x) + (double)((xv.y - mu4.y) * w4.y)
                 + (double)((xv.z - mu4.z) * w4.z) + (double)((xv.w - mu4.w) * w4.w);
        for (int o = 32; o > 0; o >>= 1) y += __shfl_down(y, o);
        if (lane == 0) yacc += y * y;
    }
    if (lane == 0) atomicAdd(&accum[b * A_N + A_Y2], yacc);
    atomicAdd(&hpool[b * D + lane * 4 + 0], (float)p0);
    atomicAdd(&hpool[b * D + lane * 4 + 1], (float)p1);
    atomicAdd(&hpool[b * D + lane * 4 + 2], (float)p2);
    atomicAdd(&hpool[b * D + lane * 4 + 3], (float)p3);
}

// ---------------- routing head MLP + softmax(logits/temp) ----------------
__global__ void k_route(const float* __restrict__ hpool,
        const float* __restrict__ Wr1, const float* __restrict__ br1,
        const float* __restrict__ Wr2, const float* __restrict__ br2,
        const float* __restrict__ Wr3, const float* __restrict__ br3,
        const float* __restrict__ temperature, float* __restrict__ alpha) {
    int b = blockIdx.x, tid = threadIdx.x;   // 64 threads
    __shared__ float z1[HID], z2[HID], hp[D];
    for (int i = tid; i < D; i += 64) hp[i] = hpool[b * D + i];
    __syncthreads();
    if (tid < HID) {
        float a = br1[tid];
        for (int d = 0; d < D; ++d) a += hp[d] * Wr1[d * HID + tid];
        z1[tid] = fmaxf(a, 0.f);
    }
    __syncthreads();
    if (tid < HID) {
        float a = br2[tid];
        for (int j = 0; j < HID; ++j) a += z1[j] * Wr2[j * HID + tid];
        z2[tid] = fmaxf(a, 0.f);
    }
    __syncthreads();
    if (tid == 0) {
        float tmp = temperature[0];
        tmp = fminf(fmaxf(tmp, 0.5f), 2.0f);
        float lg[3];
        for (int k = 0; k < 3; ++k) {
            float a = br3[k];
            for (int j = 0; j < HID; ++j) a += z2[j] * Wr3[j * 3 + k];
            lg[k] = a / tmp;
        }
        float mx = fmaxf(lg[0], fmaxf(lg[1], lg[2]));
        float e0 = expf(lg[0] - mx), e1 = expf(lg[1] - mx), e2 = expf(lg[2] - mx);
        float s = e0 + e1 + e2;
        alpha[b * 3 + 0] = e0 / s; alpha[b * 3 + 1] = e1 / s; alpha[b * 3 + 2] = e2 / s;
    }
}

// ---------------- xm-based stats + scalar finalize ----------------
__global__ __launch_bounds__(256) void k_xmstats(const double* __restrict__ xm,
        const float* __restrict__ rowm, const double* __restrict__ accum,
        float* __restrict__ stats) {
    int b = blockIdx.x, tid = threadIdx.x;
    __shared__ double xs[T];
    __shared__ double r0[256], r1[256], r2[256];
    __shared__ int i0[256], i1[256];
    const double* xmb = xm + (size_t)b * T;
    for (int i = tid; i < T; i += 256) xs[i] = xmb[i];
    __syncthreads();
    double ls = 0;
    for (int i = tid; i < T; i += 256) ls += xs[i];
    r0[tid] = ls; __syncthreads();
    for (int o = 128; o > 0; o >>= 1) { if (tid < o) r0[tid] += r0[tid + o]; __syncthreads(); }
    double xmean = r0[0] / (double)T;
    __syncthreads();
    double tn = 0, roc = 0; int pk = 0, zc = 0;
    for (int i = tid; i < T; i += 256) {
        tn += ((double)i - 1023.5) * (xs[i] - xmean);
        if (i <= T - 2) {
            double d1 = xs[i + 1] - xs[i];
            roc += fabs(d1);
            if (i >= 1) { double d0 = xs[i] - xs[i - 1]; if (d0 * d1 < 0.0) pk++; }
            if ((xs[i] - xmean) * (xs[i + 1] - xmean) < 0.0) zc++;
        }
    }
    r0[tid] = tn; r1[tid] = roc; i0[tid] = pk; i1[tid] = zc; __syncthreads();
    for (int o = 128; o > 0; o >>= 1) {
        if (tid < o) { r0[tid] += r0[tid + o]; r1[tid] += r1[tid + o]; i0[tid] += i0[tid + o]; i1[tid] += i1[tid + o]; }
        __syncthreads();
    }
    double trendnum = r0[0], rocsum = r1[0];
    int pks = i0[0], zcs = i1[0];
    __syncthreads();
    double ds = 0, ds2 = 0, obs = 0; int ft = T;
    for (int i = tid; i < T; i += 256) {
        double rm = (double)rowm[(size_t)b * T + i];
        obs += rm;
        double dn = rm / (256.0 + EPS);
        ds += dn; ds2 += dn * dn;
        if (rm > 0.0 && i < ft) ft = i;
    }
    r0[tid] = ds; r1[tid] = ds2; r2[tid] = obs; i0[tid] = ft; __syncthreads();
    for (int o = 128; o > 0; o >>= 1) {
        if (tid < o) { r0[tid] += r0[tid + o]; r1[tid] += r1[tid + o]; r2[tid] += r2[tid + o]; i0[tid] = min(i0[tid], i0[tid + o]); }
        __syncthreads();
    }
    if (tid == 0) {
        double dsum = r0[0], dsq = r1[0], obst = r2[0]; int ftt = i0[0];
        const double n = (double)T * (double)D;
        const double* ab = accum + b * A_N;
        double s1 = ab[A_S1], s2 = ab[A_S2], s3 = ab[A_S3], s4 = ab[A_S4];
        double acv = ab[A_AC], y2 = ab[A_Y2], dg = ab[A_DIAG];
        double mu_ = s1 / n;
        double m2 = s2 / n - mu_ * mu_;
        double m3 = s3 / n - 3.0 * mu_ * (s2 / n) + 2.0 * mu_ * mu_ * mu_;
        double m4 = s4 / n - 4.0 * mu_ * (s3 / n) + 6.0 * mu_ * mu_ * (s2 / n) - 3.0 * mu_ * mu_ * mu_ * mu_;
        float* st = stats + b * 17;
        st[0] = (float)(acv / ((double)(T - 1) * (double)D));
        st[1] = (float)(trendnum / (715827712.0 + EPS));
        st[4] = (float)(m3 / (sqrt(m2) * m2 + EPS));
        st[5] = (float)(m4 / (m2 * m2 + EPS));
        st[9] = (float)((double)pks / (double)(T - 2));
        st[10] = (float)((double)zcs / (double)(T - 1));
        st[11] = (float)(rocsum / (double)(T - 1));
        st[12] = (float)(1.0 - obst / ((double)T * (double)D + EPS));
        double dmean = dsum / (double)T;
        st[13] = (float)((dsq - dsum * dmean) / (double)(T - 1));
        st[14] = (ftt < T) ? (float)((double)ftt / (double)T) : 0.0f;
        st[15] = (float)((y2 / ((double)(T - 1) + EPS) - dg) / ((double)D * (D - 1) + EPS));
    }
}

// ---------------- DFT of xm (exact angles, f64 accumulation) ----------------
__global__ __launch_bounds__(256) void k_dft(const double* __restrict__ xm, double* __restrict__ power) {
    __shared__ double xs[T];
    __shared__ double ctab[T];
    __shared__ double stab[T];
    int b = blockIdx.x / 5, kc = blockIdx.x % 5;
    int tid = threadIdx.x;
    for (int i = tid; i < T; i += 256) {
        xs[i] = xm[(size_t)b * T + i];
        double ang = -6.283185307179586476925286766559 * (double)i / (double)T;
        ctab[i] = cos(ang); stab[i] = sin(ang);
    }
    __syncthreads();
    int k = kc * 256 + tid;
    if (k <= T / 2) {
        double ar = 0, ai = 0;
        int idx = 0;
        for (int t = 0; t < T; ++t) {
            double xv = xs[t];
            ar += xv * ctab[idx];
            ai += xv * stab[idx];
            idx = (idx + k) & (T - 1);
        }
        power[(size_t)b * 1025 + k] = ar * ar + ai * ai;
    }
}

// ---------------- spectral: argmax + entropy ----------------
__global__ __launch_bounds__(256) void k_spec(const double* __restrict__ power, float* __restrict__ stats) {
    int b = blockIdx.x, tid = threadIdx.x;
    __shared__ double rv[256];
    __shared__ int ri[256];
    const double* pb = power + (size_t)b * 1025;
    double bm = -1.0; int bi = 0; double lsum = 0;
    for (int i = tid; i < 1025; i += 256) {
        double p = pb[i];
        lsum += p;
        if (p > bm) { bm = p; bi = i; }
    }
    rv[tid] = bm; ri[tid] = bi; __syncthreads();
    for (int o = 128; o > 0; o >>= 1) {
        if (tid < o) {
            if (rv[tid + o] > rv[tid] || (rv[tid + o] == rv[tid] && ri[tid + o] < ri[tid])) {
                rv[tid] = rv[tid + o]; ri[tid] = ri[tid + o];
            }
        }
        __syncthreads();
    }
    int amax = ri[0];
    __syncthreads();
    rv[tid] = lsum; __syncthreads();
    for (int o = 128; o > 0; o >>= 1) { if (tid < o) rv[tid] += rv[tid + o]; __syncthreads(); }
    double S = rv[0] + EPS;
    __syncthreads();
    double le = 0;
    for (int i = tid; i < 1025; i += 256) {
        double pn = pb[i] / S;
        le -= pn * log(pn + EPS);
    }
    rv[tid] = le; __syncthreads();
    for (int o = 128; o > 0; o >>= 1) { if (tid < o) rv[tid] += rv[tid + o]; __syncthreads(); }
    if (tid == 0) {
        stats[b * 17 + 2] = (float)((double)amax / (double)(T / 2));
        stats[b * 17 + 3] = (float)rv[0];
    }
}

// ---------------- quantiles: 13-bit histogram ----------------
__global__ __launch_bounds__(256) void k_histA(const float* __restrict__ x, unsigned int* __restrict__ hist) {
    __shared__ unsigned int lh[NBIN];   // 32 KB
    int b = blockIdx.x >> 2, chunk = blockIdx.x & 3;
    int tid = threadIdx.x;
    for (int i = tid; i < NBIN; i += 256) lh[i] = 0;
    __syncthreads();
    const float4* xb = (const float4*)(x + (size_t)b * T * D + (size_t)chunk * (T * D / 4));
    for (int i = tid; i < T * D / 16; i += 256) {
        float4 v = xb[i];
        atomicAdd(&lh[f2key(v.x) >> 19], 1u);
        atomicAdd(&lh[f2key(v.y) >> 19], 1u);
        atomicAdd(&lh[f2key(v.z) >> 19], 1u);
        atomicAdd(&lh[f2key(v.w) >> 19], 1u);
    }
    __syncthreads();
    for (int i = tid; i < NBIN; i += 256)
        if (lh[i]) atomicAdd(&hist[(size_t)b * NBIN + i], lh[i]);
}

// ---------------- quantiles: locate bin + within-bin rank for each target ----------------
__global__ __launch_bounds__(256) void k_histB(const unsigned int* __restrict__ hist,
        unsigned int* __restrict__ binsel, unsigned int* __restrict__ krem) {
    int b = blockIdx.x, tid = threadIdx.x;
    __shared__ unsigned int seg[256], base[256];
    const unsigned int* hb = hist + (size_t)b * NBIN;
    unsigned int s = 0;
    for (int i = 0; i < 32; ++i) s += hb[tid * 32 + i];
    seg[tid] = s; __syncthreads();
    if (tid == 0) {
        unsigned int run = 0;
        for (int i = 0; i < 256; ++i) { base[i] = run; run += seg[i]; }
    }
    __syncthreads();
    const unsigned int targets[NSEL] = {131071u, 131072u, 262143u, 262144u, 393215u, 393216u};
    for (int q = 0; q < NSEL; ++q) {
        unsigned int k = targets[q];
        if (k >= base[tid] && k < base[tid] + seg[tid]) {
            unsigned int run = base[tid];
            for (int i = 0; i < 32; ++i) {
                unsigned int c = hb[tid * 32 + i];
                if (k < run + c) { binsel[b * NSEL + q] = tid * 32 + i; krem[b * NSEL + q] = k - run; break; }
                run += c;
            }
        }
    }
}

// ---------------- quantiles: compact candidates (LDS-aggregated, 1 global atomic per block per bin) ----------------
__global__ __launch_bounds__(256) void k_compact(const float* __restrict__ x,
        const unsigned int* __restrict__ binsel, unsigned int* __restrict__ ccnt,
        unsigned int* __restrict__ cand) {
    __shared__ unsigned int lbuf[NSEL][LCAP];   // 48 KB
    __shared__ unsigned int lcnt[NSEL];
    __shared__ unsigned int gbase[NSEL];
    int b = blockIdx.x >> 4, chunk = blockIdx.x & 15;
    int tid = threadIdx.x;
    if (tid < NSEL) lcnt[tid] = 0;
    unsigned int bs[NSEL];
    #pragma unroll
    for (int q = 0; q < NSEL; ++q) bs[q] = binsel[b * NSEL + q];
    __syncthreads();
    const float4* xb = (const float4*)(x + (size_t)b * T * D + (size_t)chunk * (T * D / 16));
    // 32 uniform iterations: T*D/64 = 8192 float4 per chunk = 32 * 256
    for (int it = 0; it < 32; ++it) {
        float4 v = xb[it * 256 + tid];
        float va[4] = {v.x, v.y, v.z, v.w};
        #pragma unroll
        for (int j = 0; j < 4; ++j) {
            unsigned int u = f2key(va[j]);
            unsigned int bin = u >> 19;
            #pragma unroll
            for (int q = 0; q < NSEL; ++q) {
                if (bin == bs[q]) {
                    unsigned int p = atomicAdd(&lcnt[q], 1u);
                    if (p < LCAP) lbuf[q][p] = u;
                }
            }
        }
        // uniform overflow check: max growth per iteration is 256*4 = 1024 per bin
        __syncthreads();
        bool need = false;
        #pragma unroll
        for (int q = 0; q < NSEL; ++q) need = need || (lcnt[q] > (unsigned)(LCAP - 1024));
        if (need) {
            if (tid < NSEL) {
                unsigned int n = min(lcnt[tid], (unsigned)LCAP);
                gbase[tid] = atomicAdd(&ccnt[b * NSEL + tid], n);
            }
            __syncthreads();
            #pragma unroll
            for (int q = 0; q < NSEL; ++q) {
                unsigned int n = min(lcnt[q], (unsigned)LCAP);
                unsigned int g0 = gbase[q];
                for (unsigned int i = tid; i < n; i += 256) {
                    unsigned int p = g0 + i;
                    if (p < CAP) cand[((size_t)b * NSEL + q) * CAP + p] = lbuf[q][i];
                }
            }
            __syncthreads();
            if (tid < NSEL) lcnt[tid] = 0;
            __syncthreads();
        }
    }
    // final flush
    __syncthreads();
    if (tid < NSEL) {
        unsigned int n = min(lcnt[tid], (unsigned)LCAP);
        gbase[tid] = atomicAdd(&ccnt[b * NSEL + tid], n);
    }
    __syncthreads();
    #pragma unroll
    for (int q = 0; q < NSEL; ++q) {
        unsigned int n = min(lcnt[q], (unsigned)LCAP);
        unsigned int g0 = gbase[q];
        for (unsigned int i = tid; i < n; i += 256) {
            unsigned int p = g0 + i;
            if (p < CAP) cand[((size_t)b * NSEL + q) * CAP + p] = lbuf[q][i];
        }
    }
}

// ---------------- quantiles: bitwise exact select of k-th smallest within bin ----------------
__global__ __launch_bounds__(256) void k_select(const unsigned int* __restrict__ cand,
        const unsigned int* __restrict__ ccnt, const unsigned int* __restrict__ binsel,
        const unsigned int* __restrict__ krem, float* __restrict__ qv) {
    int b = blockIdx.x / NSEL, q = blockIdx.x % NSEL;
    int tid = threadIdx.x;
    __shared__ unsigned int lc[CAP];   // 32 KB
    __shared__ unsigned int rc[256];
    unsigned int n = ccnt[b * NSEL + q];
    if (n > CAP) n = CAP;
    for (unsigned int i = tid; i < n; i += 256) lc[i] = cand[((size_t)b * NSEL + q) * CAP + i];
    __syncthreads();
    unsigned int prefix = binsel[b * NSEL + q] << 19;
    unsigned int k = krem[b * NSEL + q];
    for (int bit = 18; bit >= 0; --bit) {
        unsigned int hi = prefix >> (bit + 1);
        unsigned int c = 0;
        for (unsigned int i = tid; i < n; i += 256) {
            unsigned int u = lc[i];
            if ((u >> (bit + 1)) == hi && !((u >> bit) & 1u)) c++;
        }
        rc[tid] = c; __syncthreads();
        for (int o = 128; o > 0; o >>= 1) { if (tid < o) rc[tid] += rc[tid + o]; __syncthreads(); }
        unsigned int c0 = rc[0];
        __syncthreads();
        if (k >= c0) { k -= c0; prefix |= (1u << bit); }
    }
    if (tid == 0) qv[b * NSEL + q] = key2f(prefix);
}

// ---------------- quantile interpolation -> stats ----------------
__global__ void k_qwrite(const float* __restrict__ qv, float* __restrict__ stats) {
    int b = threadIdx.x;
    if (b >= B) return;
    const float* qq = qv + b * NSEL;
    double q25 = 0.25 * (double)qq[0] + 0.75 * (double)qq[1];
    double q50 = 0.5 * ((double)qq[2] + (double)qq[3]);
    double q75 = 0.75 * (double)qq[4] + 0.25 * (double)qq[5];
    stats[b * 17 + 6] = (float)q25;
    stats[b * 17 + 7] = (float)q50;
    stats[b * 17 + 8] = (float)q75;
}

// ---------------- gram = Xc^T Xc (fp32 tiled GEMM, 64x64 tiles) ----------------
__global__ __launch_bounds__(256) void k_gram(const float* __restrict__ x, const float* __restrict__ mu,
        float* __restrict__ gram) {
    __shared__ __align__(16) float As[32][64];
    __shared__ __align__(16) float Bs[32][64];
    int bid = blockIdx.x;
    int b = bid >> 4, tile = bid & 15;
    int R0 = (tile >> 2) * 64, C0 = (tile & 3) * 64;
    int tid = threadIdx.x;
    const float* xb = x + (size_t)b * T * D;
    int cg = tid & 15;
    float4 muAv = *(const float4*)(mu + b * D + R0 + cg * 4);
    float4 muBv = *(const float4*)(mu + b * D + C0 + cg * 4);
    float accv[4][4];
    #pragma unroll
    for (int i = 0; i < 4; ++i)
        #pragma unroll
        for (int j = 0; j < 4; ++j) accv[i][j] = 0.f;
    int tr = (tid & 15) * 4;
    int tc = (tid >> 4) * 4;
    for (int t0 = 0; t0 < T; t0 += 32) {
        __syncthreads();
        #pragma unroll
        for (int i = 0; i < 2; ++i) {
            int kk = i * 16 + (tid >> 4);
            float4 a = *(const float4*)(xb + (size_t)(t0 + kk) * D + R0 + cg * 4);
            a.x -= muAv.x; a.y -= muAv.y; a.z -= muAv.z; a.w -= muAv.w;
            *(float4*)&As[kk][cg * 4] = a;
            float4 c = *(const float4*)(xb + (size_t)(t0 + kk) * D + C0 + cg * 4);
            c.x -= muBv.x; c.y -= muBv.y; c.z -= muBv.z; c.w -= muBv.w;
            *(float4*)&Bs[kk][cg * 4] = c;
        }
        __syncthreads();
        #pragma unroll
        for (int kk = 0; kk < 32; ++kk) {
            float4 av = *(const float4*)&As[kk][tr];
            float4 bv = *(const float4*)&Bs[kk][tc];
            float aa[4] = {av.x, av.y, av.z, av.w};
            float bb[4] = {bv.x, bv.y, bv.z, bv.w};
            #pragma unroll
            for (int i = 0; i < 4; ++i)
                #pragma unroll
                for (int j = 0; j < 4; ++j) accv[i][j] += aa[i] * bb[j];
        }
    }
    float* gb = gram + (size_t)b * D * D;
    #pragma unroll
    for (int i = 0; i < 4; ++i) {
        float4 o4 = {accv[i][0], accv[i][1], accv[i][2], accv[i][3]};
        *(float4*)(gb + (size_t)(R0 + tr + i) * D + C0 + tc) = o4;
    }
}

// ---------------- power iteration for lambda_max -> var_exp ----------------
__global__ __launch_bounds__(1024) void k_power(const float* __restrict__ gram,
        const double* __restrict__ accum, float* __restrict__ stats) {
    int b = blockIdx.x;
    int tid = threadIdx.x;
    int row = tid & 255, sl = tid >> 8;   // 4 column-slices of 64
    __shared__ __align__(16) float v[2][D];
    __shared__ float part[1024];
    __shared__ double dpart[1024];
    const float* g = gram + (size_t)b * D * D + (size_t)row * D + sl * 64;
    float gr[64];
    #pragma unroll
    for (int j = 0; j < 64; j += 4) {
        float4 t4 = *(const float4*)(g + j);
        gr[j] = t4.x; gr[j + 1] = t4.y; gr[j + 2] = t4.z; gr[j + 3] = t4.w;
    }
    if (tid < D) {
        float h = sinf((float)tid * 12.9898f) * 43758.547f;
        v[0][tid] = h - floorf(h) - 0.4375f;
    }
    __syncthreads();
    int cur = 0;
    for (int it = 0; it < NAPPLY; ++it) {
        const float* vv = &v[cur][sl * 64];
        float acc = 0.f;
        #pragma unroll
        for (int j = 0; j < 64; j += 4) {
            float4 vb = *(const float4*)(vv + j);
            acc += gr[j] * vb.x + gr[j + 1] * vb.y + gr[j + 2] * vb.z + gr[j + 3] * vb.w;
        }
        part[tid] = acc; __syncthreads();
        if (tid < D) v[cur ^ 1][tid] = part[tid] + part[tid + 256] + part[tid + 512] + part[tid + 768];
        cur ^= 1;
        if ((it & 7) == 7 || it == NAPPLY - 1) {
            __syncthreads();
            double nl = 0;
            if (tid < D) { double yv = (double)v[cur][tid]; nl = yv * yv; }
            dpart[tid] = nl; __syncthreads();
            for (int o = 512; o > 0; o >>= 1) { if (tid < o) dpart[tid] += dpart[tid + o]; __syncthreads(); }
            float inv = (float)(1.0 / sqrt(dpart[0]));
            __syncthreads();
            if (tid < D) v[cur][tid] *= inv;
        }
        __syncthreads();
    }
    // Rayleigh quotient
    const float* vv = &v[cur][sl * 64];
    float acc = 0.f;
    #pragma unroll
    for (int j = 0; j < 64; j += 4) {
        float4 vb = *(const float4*)(vv + j);
        acc += gr[j] * vb.x + gr[j + 1] * vb.y + gr[j + 2] * vb.z + gr[j + 3] * vb.w;
    }
    part[tid] = acc; __syncthreads();
    double num = 0, den = 0;
    if (tid < D) {
        double w = (double)part[tid] + (double)part[tid + 256] + (double)part[tid + 512] + (double)part[tid + 768];
        double vd = (double)v[cur][tid];
        num = vd * w; den = vd * vd;
    }
    dpart[tid] = num; __syncthreads();
    for (int o = 512; o > 0; o >>= 1) { if (tid < o) dpart[tid] += dpart[tid + o]; __syncthreads(); }
    double lam = dpart[0];
    __syncthreads();
    dpart[tid] = den; __syncthreads();
    for (int o = 512; o > 0; o >>= 1) { if (tid < o) dpart[tid] += dpart[tid + o]; __syncthreads(); }
    if (tid == 0) {
        double trace = accum[b * A_N + A_TRACE];
        stats[b * 17 + 16] = (float)(lam / dpart[0] / trace);
    }
}

// ---------------- host launcher ----------------
extern "C" void kernel_launch(void* const* d_in, const int* in_sizes, int n_in,
                              void* d_out, int out_size, void* d_ws, size_t ws_size,
                              hipStream_t stream) {
    (void)in_sizes; (void)n_in; (void)ws_size;
    const float* x    = (const float*)d_in[0];
    const int*   mask = (const int*)d_in[1];
    const float* Wa1  = (const float*)d_in[2];
    const float* ba1  = (const float*)d_in[3];
    const float* Wa2  = (const float*)d_in[4];
    const float* ba2  = (const float*)d_in[5];
    const float* Wr1  = (const float*)d_in[6];
    const float* br1  = (const float*)d_in[7];
    const float* Wr2  = (const float*)d_in[8];
    const float* br2  = (const float*)d_in[9];
    const float* Wr3  = (const float*)d_in[10];
    const float* br3  = (const float*)d_in[11];
    const float* temp = (const float*)d_in[12];

    float* out = (float*)d_out;
    float* alpha = out;                 // 64*3
    float* hpool = out + 192;           // 64*256
    float* stats = out + 192 + 16384;   // 64*17

    char* w = (char*)d_ws;
    size_t off = 0;
    auto alloc = [&](size_t bytes) -> char* {
        char* p = w + off;
        off = (off + bytes + 255) & ~(size_t)255;
        return p;
    };
    // zeroed region first
    double* cs1 = (double*)alloc((size_t)B * D * 8);
    double* cs2 = (double*)alloc((size_t)B * D * 8);
    double* accum = (double*)alloc((size_t)B * A_N * 8);
    unsigned int* ccnt = (unsigned int*)alloc((size_t)B * NSEL * 4);
    unsigned int* hist = (unsigned int*)alloc((size_t)B * NBIN * 4);
    size_t zero_bytes = off;
    // non-zeroed
    double* xm = (double*)alloc((size_t)B * T * 8);
    float* rowm = (float*)alloc((size_t)B * T * 4);
    float* logit = (float*)alloc((size_t)B * T * 4);
    float* smz = (float*)alloc((size_t)B * 2 * 4);
    float* mu = (float*)alloc((size_t)B * D * 4);
    float* winv = (float*)alloc((size_t)B * D * 4);
    double* power = (double*)alloc((size_t)B * 1025 * 8);
    unsigned int* binsel = (unsigned int*)alloc((size_t)B * NSEL * 4);
    unsigned int* krem = (unsigned int*)alloc((size_t)B * NSEL * 4);
    float* qv = (float*)alloc((size_t)B * NSEL * 4);
    // cand (12.6MB) and gram (16.8MB) are temporally disjoint: cand dead after
    // k_select, gram written after -> alias them in one union region.
    size_t union_bytes = (size_t)B * D * D * 4;   // 16.8MB >= cand's 12.6MB
    char* ureg = alloc(union_bytes);
    unsigned int* cand = (unsigned int*)ureg;
    float* gram = (float*)ureg;

    hipMemsetAsync(d_ws, 0, zero_bytes, stream);
    hipMemsetAsync(d_out, 0, (size_t)out_size * 4, stream);

    k_pass1<<<B * 16, 256, 0, stream>>>(x, mask, xm, rowm, cs1, cs2, accum);
    k_chan<<<B, 256, 0, stream>>>(cs1, cs2, mu, winv, accum);
    k_attn<<<B * 8, 256, 0, stream>>>(x, Wa1, ba1, Wa2, ba2, logit);
    k_smax<<<B, 256, 0, stream>>>(logit, smz);
    k_pool<<<B * 8, 256, 0, stream>>>(x, logit, smz, mu, winv, hpool, accum);
    k_route<<<B, 64, 0, stream>>>(hpool, Wr1, br1, Wr2, br2, Wr3, br3, temp, alpha);
    k_xmstats<<<B, 256, 0, stream>>>(xm, rowm, accum, stats);
    k_dft<<<B * 5, 256, 0, stream>>>(xm, power);
    k_spec<<<B, 256, 0, stream>>>(power, stats);
    k_histA<<<B * 4, 256, 0, stream>>>(x, hist);
    k_histB<<<B, 256, 0, stream>>>(hist, binsel, krem);
    k_compact<<<B * 16, 256, 0, stream>>>(x, binsel, ccnt, cand);
    k_select<<<B * NSEL, 256, 0, stream>>>(cand, ccnt, binsel, krem, qv);
    k_qwrite<<<1, 64, 0, stream>>>(qv, stats);
    k_gram<<<B * 16, 256, 0, stream>>>(x, mu, gram);
    k_power<<<B, 1024, 0, stream>>>(gram, accum, stats);
}

// Round 3
// 1226.606 us; speedup vs baseline: 1.7642x; 1.1872x over previous
//
#include <hip/hip_runtime.h>
#include <math.h>
#include <stdint.h>

#define B 64
#define T 2048
#define D 256
#define HID 32
#define NSEL 6
#define NBIN 8192      // 13-bit bins: sign + 8 exp + 4 mantissa
#define CAP 8192
#define LCAP 2048      // per-block per-bin LDS candidate capacity
#define EPS 1e-8

// accum slots per batch (stride 16 doubles)
#define A_S1 0
#define A_S2 1
#define A_S3 2
#define A_S4 3
#define A_AC 4
#define A_Y2 5
#define A_DIAG 6
#define A_TRACE 7
#define A_N 16

// 128 iters: worst-case Rayleigh err ~1% of lambda1 -> var_exp err ~1e-4 << 0.13 thr
#define NAPPLY 128

// ---------------- sortable float keys ----------------
__device__ __forceinline__ unsigned int f2key(float f) {
    unsigned int u = __float_as_uint(f);
    return (u & 0x80000000u) ? ~u : (u | 0x80000000u);
}
__device__ __forceinline__ float key2f(unsigned int k) {
    unsigned int u = (k & 0x80000000u) ? (k ^ 0x80000000u) : ~k;
    return __uint_as_float(u);
}

// ---------------- pass1: fused moments / autocorr / row means / mask / channel sums ----------------
__global__ __launch_bounds__(256) void k_pass1(const float* __restrict__ x, const int* __restrict__ mask,
        double* __restrict__ xm, float* __restrict__ rowm,
        double* __restrict__ cs1, double* __restrict__ cs2, double* __restrict__ accum) {
    int b = blockIdx.x >> 4;
    int blk = blockIdx.x & 15;
    int wave = threadIdx.x >> 6;
    int lane = threadIdx.x & 63;
    int ts = blk * 128 + wave * 32;
    const float* xb = x + (size_t)b * T * D;
    const int* mb = mask + (size_t)b * T * D;
    double c1l[4] = {0, 0, 0, 0}, c2l[4] = {0, 0, 0, 0};
    double s1 = 0, s2 = 0, s3 = 0, s4 = 0, ac = 0;
    float pa[4] = {0, 0, 0, 0};
    for (int r = 0; r < 32; ++r) {
        int t = ts + r;
        float4 xv = *(const float4*)(xb + (size_t)t * D + lane * 4);
        int4 mv = *(const int4*)(mb + (size_t)t * D + lane * 4);
        double rs = (double)xv.x + (double)xv.y + (double)xv.z + (double)xv.w;
        int rm = mv.x + mv.y + mv.z + mv.w;
        for (int o = 32; o > 0; o >>= 1) { rs += __shfl_down(rs, o); rm += __shfl_down(rm, o); }
        if (lane == 0) {
            xm[(size_t)b * T + t] = rs * (1.0 / 256.0);
            rowm[(size_t)b * T + t] = (float)rm;
        }
        float xa[4] = {xv.x, xv.y, xv.z, xv.w};
        #pragma unroll
        for (int j = 0; j < 4; ++j) {
            double xd = (double)xa[j];
            double x2 = xd * xd;
            s1 += xd; s2 += x2; s3 += x2 * xd; s4 += x2 * x2;
            c1l[j] += xd; c2l[j] += x2;
        }
        if (r > 0) {
            #pragma unroll
            for (int j = 0; j < 4; ++j) ac += (double)pa[j] * (double)xa[j];
        }
        pa[0] = xa[0]; pa[1] = xa[1]; pa[2] = xa[2]; pa[3] = xa[3];
    }
    if (ts + 32 <= T - 1) {
        float4 xn = *(const float4*)(xb + (size_t)(ts + 32) * D + lane * 4);
        float na[4] = {xn.x, xn.y, xn.z, xn.w};
        #pragma unroll
        for (int j = 0; j < 4; ++j) ac += (double)pa[j] * (double)na[j];
    }
    for (int o = 32; o > 0; o >>= 1) {
        s1 += __shfl_down(s1, o); s2 += __shfl_down(s2, o);
        s3 += __shfl_down(s3, o); s4 += __shfl_down(s4, o);
        ac += __shfl_down(ac, o);
    }
    if (lane == 0) {
        atomicAdd(&accum[b * A_N + A_S1], s1);
        atomicAdd(&accum[b * A_N + A_S2], s2);
        atomicAdd(&accum[b * A_N + A_S3], s3);
        atomicAdd(&accum[b * A_N + A_S4], s4);
        atomicAdd(&accum[b * A_N + A_AC], ac);
    }
    #pragma unroll
    for (int j = 0; j < 4; ++j) {
        atomicAdd(&cs1[b * D + lane * 4 + j], c1l[j]);
        atomicAdd(&cs2[b * D + lane * 4 + j], c2l[j]);
    }
}

// ---------------- per-channel finalize: mu, 1/std, diag-corr sum, trace ----------------
__global__ __launch_bounds__(256) void k_chan(const double* __restrict__ cs1, const double* __restrict__ cs2,
        float* __restrict__ mu, float* __restrict__ winv, double* __restrict__ accum) {
    int b = blockIdx.x, d = threadIdx.x;
    double c1 = cs1[b * D + d], c2 = cs2[b * D + d];
    double m = c1 / (double)T;
    double c2c = c2 - c1 * c1 / (double)T;
    double var = c2c / (double)(T - 1);
    mu[b * D + d] = (float)m;
    winv[b * D + d] = (float)(1.0 / sqrt(var));
    double diag = (c2c / ((double)(T - 1) + EPS)) / (var + EPS);
    __shared__ double sd[256], st[256];
    sd[d] = diag; st[d] = c2c; __syncthreads();
    for (int o = 128; o > 0; o >>= 1) {
        if (d < o) { sd[d] += sd[d + o]; st[d] += st[d + o]; }
        __syncthreads();
    }
    if (d == 0) { accum[b * A_N + A_DIAG] = sd[0]; accum[b * A_N + A_TRACE] = st[0]; }
}

// ---------------- attention logits: tanh(x@Wa1+ba1)@Wa2+ba2 ----------------
__global__ __launch_bounds__(256) void k_attn(const float* __restrict__ x,
        const float* __restrict__ Wa1, const float* __restrict__ ba1,
        const float* __restrict__ Wa2, const float* __restrict__ ba2,
        float* __restrict__ logit) {
    __shared__ float tile[256][33];   // +1 pad: conflict-free column reads
    int bid = blockIdx.x;
    int b = bid >> 3, t0 = (bid & 7) * 256;
    int tid = threadIdx.x;
    const float* xb = x + (size_t)b * T * D + (size_t)t0 * D;
    float acc[HID];
    #pragma unroll
    for (int h = 0; h < HID; ++h) acc[h] = 0.f;
    for (int dc = 0; dc < 8; ++dc) {
        __syncthreads();
        #pragma unroll
        for (int i = 0; i < 32; ++i) {
            int idx = i * 256 + tid;
            int tl = idx >> 5, dd = idx & 31;
            tile[tl][dd] = xb[(size_t)tl * D + dc * 32 + dd];
        }
        __syncthreads();
        #pragma unroll
        for (int dd = 0; dd < 32; ++dd) {
            float xval = tile[tid][dd];
            const float* wrow = Wa1 + (dc * 32 + dd) * HID;   // wave-uniform -> s_load
            #pragma unroll
            for (int h = 0; h < HID; ++h) acc[h] += xval * wrow[h];
        }
    }
    float lg = ba2[0];
    #pragma unroll
    for (int h = 0; h < HID; ++h) lg += tanhf(acc[h] + ba1[h]) * Wa2[h];
    logit[(size_t)b * T + t0 + tid] = lg;
}

// ---------------- softmax max & denominator over T ----------------
__global__ __launch_bounds__(256) void k_smax(const float* __restrict__ logit, float* __restrict__ smz) {
    int b = blockIdx.x, tid = threadIdx.x;
    __shared__ float sm[256];
    __shared__ double sz[256];
    float mx = -1e30f;
    for (int i = tid; i < T; i += 256) mx = fmaxf(mx, logit[(size_t)b * T + i]);
    sm[tid] = mx; __syncthreads();
    for (int o = 128; o > 0; o >>= 1) { if (tid < o) sm[tid] = fmaxf(sm[tid], sm[tid + o]); __syncthreads(); }
    float m = sm[0];
    double z = 0;
    for (int i = tid; i < T; i += 256) z += (double)expf(logit[(size_t)b * T + i] - m);
    sz[tid] = z; __syncthreads();
    for (int o = 128; o > 0; o >>= 1) { if (tid < o) sz[tid] += sz[tid + o]; __syncthreads(); }
    if (tid == 0) { smz[b * 2] = m; smz[b * 2 + 1] = (float)sz[0]; }
}

// ---------------- fused: attention pooling + mean_corr y-pass ----------------
__global__ __launch_bounds__(256) void k_pool(const float* __restrict__ x,
        const float* __restrict__ logit, const float* __restrict__ smz,
        const float* __restrict__ mu, const float* __restrict__ winv,
        float* __restrict__ hpool, double* __restrict__ accum) {
    int bid = blockIdx.x;
    int b = bid >> 3, t0 = (bid & 7) * 256;
    int wave = threadIdx.x >> 6, lane = threadIdx.x & 63;
    const float* xb = x + (size_t)b * T * D;
    float m = smz[b * 2], Z = smz[b * 2 + 1];
    float4 mu4 = *(const float4*)(mu + b * D + lane * 4);
    float4 w4 = *(const float4*)(winv + b * D + lane * 4);
    double p0 = 0, p1 = 0, p2 = 0, p3 = 0, yacc = 0;
    for (int r = 0; r < 64; ++r) {
        int t = t0 + wave * 64 + r;
        float4 xv = *(const float4*)(xb + (size_t)t * D + lane * 4);
        float wt = expf(logit[(size_t)b * T + t] - m) / Z;
        p0 += (double)(wt * xv.x); p1 += (double)(wt * xv.y);
        p2 += (double)(wt * xv.z); p3 += (double)(wt * xv.w);
        double y = (double)((xv.x - mu4.x) * w4.x) + (double)((xv.y - mu4.y) * w4.y)
                 + (double)((xv.z - mu4.z) * w4.z) + (double)((xv.w - mu4.w) * w4.w);
        for (int o = 32; o > 0; o >>= 1) y += __shfl_down(y, o);
        if (lane == 0) yacc += y * y;
    }
    if (lane == 0) atomicAdd(&accum[b * A_N + A_Y2], yacc);
    atomicAdd(&hpool[b * D + lane * 4 + 0], (float)p0);
    atomicAdd(&hpool[b * D + lane * 4 + 1], (float)p1);
    atomicAdd(&hpool[b * D + lane * 4 + 2], (float)p2);
    atomicAdd(&hpool[b * D + lane * 4 + 3], (float)p3);
}

// ---------------- routing head MLP + softmax(logits/temp) ----------------
__global__ void k_route(const float* __restrict__ hpool,
        const float* __restrict__ Wr1, const float* __restrict__ br1,
        const float* __restrict__ Wr2, const float* __restrict__ br2,
        const float* __restrict__ Wr3, const float* __restrict__ br3,
        const float* __restrict__ temperature, float* __restrict__ alpha) {
    int b = blockIdx.x, tid = threadIdx.x;   // 64 threads
    __shared__ float z1[HID], z2[HID], hp[D];
    for (int i = tid; i < D; i += 64) hp[i] = hpool[b * D + i];
    __syncthreads();
    if (tid < HID) {
        float a = br1[tid];
        for (int d = 0; d < D; ++d) a += hp[d] * Wr1[d * HID + tid];
        z1[tid] = fmaxf(a, 0.f);
    }
    __syncthreads();
    if (tid < HID) {
        float a = br2[tid];
        for (int j = 0; j < HID; ++j) a += z1[j] * Wr2[j * HID + tid];
        z2[tid] = fmaxf(a, 0.f);
    }
    __syncthreads();
    if (tid == 0) {
        float tmp = temperature[0];
        tmp = fminf(fmaxf(tmp, 0.5f), 2.0f);
        float lg[3];
        for (int k = 0; k < 3; ++k) {
            float a = br3[k];
            for (int j = 0; j < HID; ++j) a += z2[j] * Wr3[j * 3 + k];
            lg[k] = a / tmp;
        }
        float mx = fmaxf(lg[0], fmaxf(lg[1], lg[2]));
        float e0 = expf(lg[0] - mx), e1 = expf(lg[1] - mx), e2 = expf(lg[2] - mx);
        float s = e0 + e1 + e2;
        alpha[b * 3 + 0] = e0 / s; alpha[b * 3 + 1] = e1 / s; alpha[b * 3 + 2] = e2 / s;
    }
}

// ---------------- xm-based stats + scalar finalize ----------------
__global__ __launch_bounds__(256) void k_xmstats(const double* __restrict__ xm,
        const float* __restrict__ rowm, const double* __restrict__ accum,
        float* __restrict__ stats) {
    int b = blockIdx.x, tid = threadIdx.x;
    __shared__ double xs[T];
    __shared__ double r0[256], r1[256], r2[256];
    __shared__ int i0[256], i1[256];
    const double* xmb = xm + (size_t)b * T;
    for (int i = tid; i < T; i += 256) xs[i] = xmb[i];
    __syncthreads();
    double ls = 0;
    for (int i = tid; i < T; i += 256) ls += xs[i];
    r0[tid] = ls; __syncthreads();
    for (int o = 128; o > 0; o >>= 1) { if (tid < o) r0[tid] += r0[tid + o]; __syncthreads(); }
    double xmean = r0[0] / (double)T;
    __syncthreads();
    double tn = 0, roc = 0; int pk = 0, zc = 0;
    for (int i = tid; i < T; i += 256) {
        tn += ((double)i - 1023.5) * (xs[i] - xmean);
        if (i <= T - 2) {
            double d1 = xs[i + 1] - xs[i];
            roc += fabs(d1);
            if (i >= 1) { double d0 = xs[i] - xs[i - 1]; if (d0 * d1 < 0.0) pk++; }
            if ((xs[i] - xmean) * (xs[i + 1] - xmean) < 0.0) zc++;
        }
    }
    r0[tid] = tn; r1[tid] = roc; i0[tid] = pk; i1[tid] = zc; __syncthreads();
    for (int o = 128; o > 0; o >>= 1) {
        if (tid < o) { r0[tid] += r0[tid + o]; r1[tid] += r1[tid + o]; i0[tid] += i0[tid + o]; i1[tid] += i1[tid + o]; }
        __syncthreads();
    }
    double trendnum = r0[0], rocsum = r1[0];
    int pks = i0[0], zcs = i1[0];
    __syncthreads();
    double ds = 0, ds2 = 0, obs = 0; int ft = T;
    for (int i = tid; i < T; i += 256) {
        double rm = (double)rowm[(size_t)b * T + i];
        obs += rm;
        double dn = rm / (256.0 + EPS);
        ds += dn; ds2 += dn * dn;
        if (rm > 0.0 && i < ft) ft = i;
    }
    r0[tid] = ds; r1[tid] = ds2; r2[tid] = obs; i0[tid] = ft; __syncthreads();
    for (int o = 128; o > 0; o >>= 1) {
        if (tid < o) { r0[tid] += r0[tid + o]; r1[tid] += r1[tid + o]; r2[tid] += r2[tid + o]; i0[tid] = min(i0[tid], i0[tid + o]); }
        __syncthreads();
    }
    if (tid == 0) {
        double dsum = r0[0], dsq = r1[0], obst = r2[0]; int ftt = i0[0];
        const double n = (double)T * (double)D;
        const double* ab = accum + b * A_N;
        double s1 = ab[A_S1], s2 = ab[A_S2], s3 = ab[A_S3], s4 = ab[A_S4];
        double acv = ab[A_AC], y2 = ab[A_Y2], dg = ab[A_DIAG];
        double mu_ = s1 / n;
        double m2 = s2 / n - mu_ * mu_;
        double m3 = s3 / n - 3.0 * mu_ * (s2 / n) + 2.0 * mu_ * mu_ * mu_;
        double m4 = s4 / n - 4.0 * mu_ * (s3 / n) + 6.0 * mu_ * mu_ * (s2 / n) - 3.0 * mu_ * mu_ * mu_ * mu_;
        float* st = stats + b * 17;
        st[0] = (float)(acv / ((double)(T - 1) * (double)D));
        st[1] = (float)(trendnum / (715827712.0 + EPS));
        st[4] = (float)(m3 / (sqrt(m2) * m2 + EPS));
        st[5] = (float)(m4 / (m2 * m2 + EPS));
        st[9] = (float)((double)pks / (double)(T - 2));
        st[10] = (float)((double)zcs / (double)(T - 1));
        st[11] = (float)(rocsum / (double)(T - 1));
        st[12] = (float)(1.0 - obst / ((double)T * (double)D + EPS));
        double dmean = dsum / (double)T;
        st[13] = (float)((dsq - dsum * dmean) / (double)(T - 1));
        st[14] = (ftt < T) ? (float)((double)ftt / (double)T) : 0.0f;
        st[15] = (float)((y2 / ((double)(T - 1) + EPS) - dg) / ((double)D * (D - 1) + EPS));
    }
}

// ---------------- DFT of xm: complex-rotation recurrence, no tables ----------------
// X[k] = sum_t x[t] e^{-2pi i k t / T}. 4-phase split: X = sum_m e^{i m th} * A_m,
// A_m = sum_p x[4p+m] e^{i 4 th p}, one rotation recurrence per thread (f64 drift ~6e-14).
__global__ __launch_bounds__(256) void k_dft(const double* __restrict__ xm, double* __restrict__ power) {
    __shared__ double xs[T];   // 16 KB only (tables eliminated)
    int b = blockIdx.x / 5, kc = blockIdx.x % 5;
    int tid = threadIdx.x;
    for (int i = tid; i < T; i += 256) xs[i] = xm[(size_t)b * T + i];
    __syncthreads();
    int k = kc * 256 + tid;
    if (k <= T / 2) {
        double theta = -6.283185307179586476925286766559 * (double)k / (double)T;
        double c4 = cos(4.0 * theta), s4 = sin(4.0 * theta);
        double cr = 1.0, ci = 0.0;
        double a0r = 0, a0i = 0, a1r = 0, a1i = 0, a2r = 0, a2i = 0, a3r = 0, a3i = 0;
        #pragma unroll 4
        for (int p = 0; p < T / 4; ++p) {
            double x0 = xs[4 * p + 0], x1 = xs[4 * p + 1];
            double x2 = xs[4 * p + 2], x3 = xs[4 * p + 3];
            a0r += x0 * cr; a0i += x0 * ci;
            a1r += x1 * cr; a1i += x1 * ci;
            a2r += x2 * cr; a2i += x2 * ci;
            a3r += x3 * cr; a3i += x3 * ci;
            double ncr = cr * c4 - ci * s4;
            double nci = cr * s4 + ci * c4;
            cr = ncr; ci = nci;
        }
        double c1 = cos(theta), s1 = sin(theta);
        double ar = a0r, ai = a0i;
        ar += c1 * a1r - s1 * a1i; ai += c1 * a1i + s1 * a1r;
        double c2 = c1 * c1 - s1 * s1, s2 = 2.0 * c1 * s1;
        ar += c2 * a2r - s2 * a2i; ai += c2 * a2i + s2 * a2r;
        double c3 = c2 * c1 - s2 * s1, s3 = c2 * s1 + s2 * c1;
        ar += c3 * a3r - s3 * a3i; ai += c3 * a3i + s3 * a3r;
        power[(size_t)b * 1025 + k] = ar * ar + ai * ai;
    }
}

// ---------------- spectral: argmax + entropy ----------------
__global__ __launch_bounds__(256) void k_spec(const double* __restrict__ power, float* __restrict__ stats) {
    int b = blockIdx.x, tid = threadIdx.x;
    __shared__ double rv[256];
    __shared__ int ri[256];
    const double* pb = power + (size_t)b * 1025;
    double bm = -1.0; int bi = 0; double lsum = 0;
    for (int i = tid; i < 1025; i += 256) {
        double p = pb[i];
        lsum += p;
        if (p > bm) { bm = p; bi = i; }
    }
    rv[tid] = bm; ri[tid] = bi; __syncthreads();
    for (int o = 128; o > 0; o >>= 1) {
        if (tid < o) {
            if (rv[tid + o] > rv[tid] || (rv[tid + o] == rv[tid] && ri[tid + o] < ri[tid])) {
                rv[tid] = rv[tid + o]; ri[tid] = ri[tid + o];
            }
        }
        __syncthreads();
    }
    int amax = ri[0];
    __syncthreads();
    rv[tid] = lsum; __syncthreads();
    for (int o = 128; o > 0; o >>= 1) { if (tid < o) rv[tid] += rv[tid + o]; __syncthreads(); }
    double S = rv[0] + EPS;
    __syncthreads();
    double le = 0;
    for (int i = tid; i < 1025; i += 256) {
        double pn = pb[i] / S;
        le -= pn * log(pn + EPS);
    }
    rv[tid] = le; __syncthreads();
    for (int o = 128; o > 0; o >>= 1) { if (tid < o) rv[tid] += rv[tid + o]; __syncthreads(); }
    if (tid == 0) {
        stats[b * 17 + 2] = (float)((double)amax / (double)(T / 2));
        stats[b * 17 + 3] = (float)rv[0];
    }
}

// ---------------- quantiles: 13-bit histogram ----------------
__global__ __launch_bounds__(256) void k_histA(const float* __restrict__ x, unsigned int* __restrict__ hist) {
    __shared__ unsigned int lh[NBIN];   // 32 KB
    int b = blockIdx.x >> 2, chunk = blockIdx.x & 3;
    int tid = threadIdx.x;
    for (int i = tid; i < NBIN; i += 256) lh[i] = 0;
    __syncthreads();
    const float4* xb = (const float4*)(x + (size_t)b * T * D + (size_t)chunk * (T * D / 4));
    for (int i = tid; i < T * D / 16; i += 256) {
        float4 v = xb[i];
        atomicAdd(&lh[f2key(v.x) >> 19], 1u);
        atomicAdd(&lh[f2key(v.y) >> 19], 1u);
        atomicAdd(&lh[f2key(v.z) >> 19], 1u);
        atomicAdd(&lh[f2key(v.w) >> 19], 1u);
    }
    __syncthreads();
    for (int i = tid; i < NBIN; i += 256)
        if (lh[i]) atomicAdd(&hist[(size_t)b * NBIN + i], lh[i]);
}

// ---------------- quantiles: locate bin + within-bin rank for each target ----------------
__global__ __launch_bounds__(256) void k_histB(const unsigned int* __restrict__ hist,
        unsigned int* __restrict__ binsel, unsigned int* __restrict__ krem) {
    int b = blockIdx.x, tid = threadIdx.x;
    __shared__ unsigned int seg[256], base[256];
    const unsigned int* hb = hist + (size_t)b * NBIN;
    unsigned int s = 0;
    for (int i = 0; i < 32; ++i) s += hb[tid * 32 + i];
    seg[tid] = s; __syncthreads();
    if (tid == 0) {
        unsigned int run = 0;
        for (int i = 0; i < 256; ++i) { base[i] = run; run += seg[i]; }
    }
    __syncthreads();
    const unsigned int targets[NSEL] = {131071u, 131072u, 262143u, 262144u, 393215u, 393216u};
    for (int q = 0; q < NSEL; ++q) {
        unsigned int k = targets[q];
        if (k >= base[tid] && k < base[tid] + seg[tid]) {
            unsigned int run = base[tid];
            for (int i = 0; i < 32; ++i) {
                unsigned int c = hb[tid * 32 + i];
                if (k < run + c) { binsel[b * NSEL + q] = tid * 32 + i; krem[b * NSEL + q] = k - run; break; }
                run += c;
            }
        }
    }
}

// ---------------- quantiles: compact candidates (LDS-aggregated, 1 global atomic per block per bin) ----------------
__global__ __launch_bounds__(256) void k_compact(const float* __restrict__ x,
        const unsigned int* __restrict__ binsel, unsigned int* __restrict__ ccnt,
        unsigned int* __restrict__ cand) {
    __shared__ unsigned int lbuf[NSEL][LCAP];   // 48 KB
    __shared__ unsigned int lcnt[NSEL];
    __shared__ unsigned int gbase[NSEL];
    int b = blockIdx.x >> 4, chunk = blockIdx.x & 15;
    int tid = threadIdx.x;
    if (tid < NSEL) lcnt[tid] = 0;
    unsigned int bs[NSEL];
    #pragma unroll
    for (int q = 0; q < NSEL; ++q) bs[q] = binsel[b * NSEL + q];
    __syncthreads();
    const float4* xb = (const float4*)(x + (size_t)b * T * D + (size_t)chunk * (T * D / 16));
    // 32 uniform iterations: T*D/64 = 8192 float4 per chunk = 32 * 256
    for (int it = 0; it < 32; ++it) {
        float4 v = xb[it * 256 + tid];
        float va[4] = {v.x, v.y, v.z, v.w};
        #pragma unroll
        for (int j = 0; j < 4; ++j) {
            unsigned int u = f2key(va[j]);
            unsigned int bin = u >> 19;
            #pragma unroll
            for (int q = 0; q < NSEL; ++q) {
                if (bin == bs[q]) {
                    unsigned int p = atomicAdd(&lcnt[q], 1u);
                    if (p < LCAP) lbuf[q][p] = u;
                }
            }
        }
        // uniform overflow check: max growth per iteration is 256*4 = 1024 per bin
        __syncthreads();
        bool need = false;
        #pragma unroll
        for (int q = 0; q < NSEL; ++q) need = need || (lcnt[q] > (unsigned)(LCAP - 1024));
        if (need) {
            if (tid < NSEL) {
                unsigned int n = min(lcnt[tid], (unsigned)LCAP);
                gbase[tid] = atomicAdd(&ccnt[b * NSEL + tid], n);
            }
            __syncthreads();
            #pragma unroll
            for (int q = 0; q < NSEL; ++q) {
                unsigned int n = min(lcnt[q], (unsigned)LCAP);
                unsigned int g0 = gbase[q];
                for (unsigned int i = tid; i < n; i += 256) {
                    unsigned int p = g0 + i;
                    if (p < CAP) cand[((size_t)b * NSEL + q) * CAP + p] = lbuf[q][i];
                }
            }
            __syncthreads();
            if (tid < NSEL) lcnt[tid] = 0;
            __syncthreads();
        }
    }
    // final flush
    __syncthreads();
    if (tid < NSEL) {
        unsigned int n = min(lcnt[tid], (unsigned)LCAP);
        gbase[tid] = atomicAdd(&ccnt[b * NSEL + tid], n);
    }
    __syncthreads();
    #pragma unroll
    for (int q = 0; q < NSEL; ++q) {
        unsigned int n = min(lcnt[q], (unsigned)LCAP);
        unsigned int g0 = gbase[q];
        for (unsigned int i = tid; i < n; i += 256) {
            unsigned int p = g0 + i;
            if (p < CAP) cand[((size_t)b * NSEL + q) * CAP + p] = lbuf[q][i];
        }
    }
}

// ---------------- quantiles: bitwise exact select of k-th smallest within bin ----------------
__global__ __launch_bounds__(256) void k_select(const unsigned int* __restrict__ cand,
        const unsigned int* __restrict__ ccnt, const unsigned int* __restrict__ binsel,
        const unsigned int* __restrict__ krem, float* __restrict__ qv) {
    int b = blockIdx.x / NSEL, q = blockIdx.x % NSEL;
    int tid = threadIdx.x;
    __shared__ unsigned int lc[CAP];   // 32 KB
    __shared__ unsigned int rc[256];
    unsigned int n = ccnt[b * NSEL + q];
    if (n > CAP) n = CAP;
    for (unsigned int i = tid; i < n; i += 256) lc[i] = cand[((size_t)b * NSEL + q) * CAP + i];
    __syncthreads();
    unsigned int prefix = binsel[b * NSEL + q] << 19;
    unsigned int k = krem[b * NSEL + q];
    for (int bit = 18; bit >= 0; --bit) {
        unsigned int hi = prefix >> (bit + 1);
        unsigned int c = 0;
        for (unsigned int i = tid; i < n; i += 256) {
            unsigned int u = lc[i];
            if ((u >> (bit + 1)) == hi && !((u >> bit) & 1u)) c++;
        }
        rc[tid] = c; __syncthreads();
        for (int o = 128; o > 0; o >>= 1) { if (tid < o) rc[tid] += rc[tid + o]; __syncthreads(); }
        unsigned int c0 = rc[0];
        __syncthreads();
        if (k >= c0) { k -= c0; prefix |= (1u << bit); }
    }
    if (tid == 0) qv[b * NSEL + q] = key2f(prefix);
}

// ---------------- quantile interpolation -> stats ----------------
__global__ void k_qwrite(const float* __restrict__ qv, float* __restrict__ stats) {
    int b = threadIdx.x;
    if (b >= B) return;
    const float* qq = qv + b * NSEL;
    double q25 = 0.25 * (double)qq[0] + 0.75 * (double)qq[1];
    double q50 = 0.5 * ((double)qq[2] + (double)qq[3]);
    double q75 = 0.75 * (double)qq[4] + 0.25 * (double)qq[5];
    stats[b * 17 + 6] = (float)q25;
    stats[b * 17 + 7] = (float)q50;
    stats[b * 17 + 8] = (float)q75;
}

// ---------------- gram = Xc^T Xc (fp32 tiled GEMM, 64x64 tiles) ----------------
__global__ __launch_bounds__(256) void k_gram(const float* __restrict__ x, const float* __restrict__ mu,
        float* __restrict__ gram) {
    __shared__ __align__(16) float As[32][64];
    __shared__ __align__(16) float Bs[32][64];
    int bid = blockIdx.x;
    int b = bid >> 4, tile = bid & 15;
    int R0 = (tile >> 2) * 64, C0 = (tile & 3) * 64;
    int tid = threadIdx.x;
    const float* xb = x + (size_t)b * T * D;
    int cg = tid & 15;
    float4 muAv = *(const float4*)(mu + b * D + R0 + cg * 4);
    float4 muBv = *(const float4*)(mu + b * D + C0 + cg * 4);
    float accv[4][4];
    #pragma unroll
    for (int i = 0; i < 4; ++i)
        #pragma unroll
        for (int j = 0; j < 4; ++j) accv[i][j] = 0.f;
    int tr = (tid & 15) * 4;
    int tc = (tid >> 4) * 4;
    for (int t0 = 0; t0 < T; t0 += 32) {
        __syncthreads();
        #pragma unroll
        for (int i = 0; i < 2; ++i) {
            int kk = i * 16 + (tid >> 4);
            float4 a = *(const float4*)(xb + (size_t)(t0 + kk) * D + R0 + cg * 4);
            a.x -= muAv.x; a.y -= muAv.y; a.z -= muAv.z; a.w -= muAv.w;
            *(float4*)&As[kk][cg * 4] = a;
            float4 c = *(const float4*)(xb + (size_t)(t0 + kk) * D + C0 + cg * 4);
            c.x -= muBv.x; c.y -= muBv.y; c.z -= muBv.z; c.w -= muBv.w;
            *(float4*)&Bs[kk][cg * 4] = c;
        }
        __syncthreads();
        #pragma unroll
        for (int kk = 0; kk < 32; ++kk) {
            float4 av = *(const float4*)&As[kk][tr];
            float4 bv = *(const float4*)&Bs[kk][tc];
            float aa[4] = {av.x, av.y, av.z, av.w};
            float bb[4] = {bv.x, bv.y, bv.z, bv.w};
            #pragma unroll
            for (int i = 0; i < 4; ++i)
                #pragma unroll
                for (int j = 0; j < 4; ++j) accv[i][j] += aa[i] * bb[j];
        }
    }
    float* gb = gram + (size_t)b * D * D;
    #pragma unroll
    for (int i = 0; i < 4; ++i) {
        float4 o4 = {accv[i][0], accv[i][1], accv[i][2], accv[i][3]};
        *(float4*)(gb + (size_t)(R0 + tr + i) * D + C0 + tc) = o4;
    }
}

// ---------------- power iteration for lambda_max -> var_exp ----------------
// 8x8 G-tile per thread: 2 ds_read_b128/iter (vs 16 for row-slices), cross-lane
// sum via shfl_xor butterfly over the 32 lanes of a half-wave (half-wave = one
// rowblock: lanes 0-31 -> rowblock 2w, lanes 32-63 -> rowblock 2w+1).
__global__ __launch_bounds__(1024) void k_power(const float* __restrict__ gram,
        const double* __restrict__ accum, float* __restrict__ stats) {
    int b = blockIdx.x;
    int tid = threadIdx.x;
    int rowblock = tid >> 5;        // 0..31
    int colblock = tid & 31;        // 0..31
    int r0 = rowblock * 8, c0 = colblock * 8;
    __shared__ __align__(16) float v[2][D];
    __shared__ double dpart[1024];
    const float* g = gram + (size_t)b * D * D;
    float gr[8][8];
    #pragma unroll
    for (int i = 0; i < 8; ++i) {
        float4 ta = *(const float4*)(g + (size_t)(r0 + i) * D + c0);
        float4 tb = *(const float4*)(g + (size_t)(r0 + i) * D + c0 + 4);
        gr[i][0] = ta.x; gr[i][1] = ta.y; gr[i][2] = ta.z; gr[i][3] = ta.w;
        gr[i][4] = tb.x; gr[i][5] = tb.y; gr[i][6] = tb.z; gr[i][7] = tb.w;
    }
    if (tid < D) {
        float h = sinf((float)tid * 12.9898f) * 43758.547f;
        v[0][tid] = h - floorf(h) - 0.4375f;
    }
    __syncthreads();
    int cur = 0;
    for (int it = 0; it < NAPPLY; ++it) {
        float4 va = *(const float4*)&v[cur][c0];
        float4 vb = *(const float4*)&v[cur][c0 + 4];
        float y[8];
        #pragma unroll
        for (int i = 0; i < 8; ++i) {
            y[i] = gr[i][0] * va.x + gr[i][1] * va.y + gr[i][2] * va.z + gr[i][3] * va.w
                 + gr[i][4] * vb.x + gr[i][5] * vb.y + gr[i][6] * vb.z + gr[i][7] * vb.w;
        }
        #pragma unroll
        for (int m = 1; m < 32; m <<= 1) {
            #pragma unroll
            for (int i = 0; i < 8; ++i) y[i] += __shfl_xor(y[i], m);
        }
        if (colblock == 0) {
            float4 o0 = {y[0], y[1], y[2], y[3]};
            float4 o1 = {y[4], y[5], y[6], y[7]};
            *(float4*)&v[cur ^ 1][r0] = o0;
            *(float4*)&v[cur ^ 1][r0 + 4] = o1;
        }
        cur ^= 1;
        __syncthreads();
        if ((it & 7) == 7) {
            double nl = 0;
            if (tid < D) { double yv = (double)v[cur][tid]; nl = yv * yv; }
            dpart[tid] = nl; __syncthreads();
            for (int o = 512; o > 0; o >>= 1) { if (tid < o) dpart[tid] += dpart[tid + o]; __syncthreads(); }
            float inv = (float)(1.0 / sqrt(dpart[0]));
            __syncthreads();
            if (tid < D) v[cur][tid] *= inv;
            __syncthreads();
        }
    }
    // final apply y = G v into v[cur^1], then Rayleigh quotient in f64
    {
        float4 va = *(const float4*)&v[cur][c0];
        float4 vb = *(const float4*)&v[cur][c0 + 4];
        float y[8];
        #pragma unroll
        for (int i = 0; i < 8; ++i) {
            y[i] = gr[i][0] * va.x + gr[i][1] * va.y + gr[i][2] * va.z + gr[i][3] * va.w
                 + gr[i][4] * vb.x + gr[i][5] * vb.y + gr[i][6] * vb.z + gr[i][7] * vb.w;
        }
        #pragma unroll
        for (int m = 1; m < 32; m <<= 1) {
            #pragma unroll
            for (int i = 0; i < 8; ++i) y[i] += __shfl_xor(y[i], m);
        }
        if (colblock == 0) {
            float4 o0 = {y[0], y[1], y[2], y[3]};
            float4 o1 = {y[4], y[5], y[6], y[7]};
            *(float4*)&v[cur ^ 1][r0] = o0;
            *(float4*)&v[cur ^ 1][r0 + 4] = o1;
        }
        __syncthreads();
    }
    double num = 0, den = 0;
    if (tid < D) {
        double vd = (double)v[cur][tid];
        double yd = (double)v[cur ^ 1][tid];
        num = vd * yd; den = vd * vd;
    }
    dpart[tid] = num; __syncthreads();
    for (int o = 512; o > 0; o >>= 1) { if (tid < o) dpart[tid] += dpart[tid + o]; __syncthreads(); }
    double lam = dpart[0];
    __syncthreads();
    dpart[tid] = den; __syncthreads();
    for (int o = 512; o > 0; o >>= 1) { if (tid < o) dpart[tid] += dpart[tid + o]; __syncthreads(); }
    if (tid == 0) {
        double trace = accum[b * A_N + A_TRACE];
        stats[b * 17 + 16] = (float)(lam / dpart[0] / trace);
    }
}

// ---------------- host launcher ----------------
extern "C" void kernel_launch(void* const* d_in, const int* in_sizes, int n_in,
                              void* d_out, int out_size, void* d_ws, size_t ws_size,
                              hipStream_t stream) {
    (void)in_sizes; (void)n_in; (void)ws_size;
    const float* x    = (const float*)d_in[0];
    const int*   mask = (const int*)d_in[1];
    const float* Wa1  = (const float*)d_in[2];
    const float* ba1  = (const float*)d_in[3];
    const float* Wa2  = (const float*)d_in[4];
    const float* ba2  = (const float*)d_in[5];
    const float* Wr1  = (const float*)d_in[6];
    const float* br1  = (const float*)d_in[7];
    const float* Wr2  = (const float*)d_in[8];
    const float* br2  = (const float*)d_in[9];
    const float* Wr3  = (const float*)d_in[10];
    const float* br3  = (const float*)d_in[11];
    const float* temp = (const float*)d_in[12];

    float* out = (float*)d_out;
    float* alpha = out;                 // 64*3
    float* hpool = out + 192;           // 64*256
    float* stats = out + 192 + 16384;   // 64*17

    char* w = (char*)d_ws;
    size_t off = 0;
    auto alloc = [&](size_t bytes) -> char* {
        char* p = w + off;
        off = (off + bytes + 255) & ~(size_t)255;
        return p;
    };
    // zeroed region first
    double* cs1 = (double*)alloc((size_t)B * D * 8);
    double* cs2 = (double*)alloc((size_t)B * D * 8);
    double* accum = (double*)alloc((size_t)B * A_N * 8);
    unsigned int* ccnt = (unsigned int*)alloc((size_t)B * NSEL * 4);
    unsigned int* hist = (unsigned int*)alloc((size_t)B * NBIN * 4);
    size_t zero_bytes = off;
    // non-zeroed
    double* xm = (double*)alloc((size_t)B * T * 8);
    float* rowm = (float*)alloc((size_t)B * T * 4);
    float* logit = (float*)alloc((size_t)B * T * 4);
    float* smz = (float*)alloc((size_t)B * 2 * 4);
    float* mu = (float*)alloc((size_t)B * D * 4);
    float* winv = (float*)alloc((size_t)B * D * 4);
    double* power = (double*)alloc((size_t)B * 1025 * 8);
    unsigned int* binsel = (unsigned int*)alloc((size_t)B * NSEL * 4);
    unsigned int* krem = (unsigned int*)alloc((size_t)B * NSEL * 4);
    float* qv = (float*)alloc((size_t)B * NSEL * 4);
    // cand (12.6MB) and gram (16.8MB) are temporally disjoint: cand dead after
    // k_select, gram written after -> alias them in one union region.
    size_t union_bytes = (size_t)B * D * D * 4;   // 16.8MB >= cand's 12.6MB
    char* ureg = alloc(union_bytes);
    unsigned int* cand = (unsigned int*)ureg;
    float* gram = (float*)ureg;

    hipMemsetAsync(d_ws, 0, zero_bytes, stream);
    hipMemsetAsync(d_out, 0, (size_t)out_size * 4, stream);

    k_pass1<<<B * 16, 256, 0, stream>>>(x, mask, xm, rowm, cs1, cs2, accum);
    k_chan<<<B, 256, 0, stream>>>(cs1, cs2, mu, winv, accum);
    k_attn<<<B * 8, 256, 0, stream>>>(x, Wa1, ba1, Wa2, ba2, logit);
    k_smax<<<B, 256, 0, stream>>>(logit, smz);
    k_pool<<<B * 8, 256, 0, stream>>>(x, logit, smz, mu, winv, hpool, accum);
    k_route<<<B, 64, 0, stream>>>(hpool, Wr1, br1, Wr2, br2, Wr3, br3, temp, alpha);
    k_xmstats<<<B, 256, 0, stream>>>(xm, rowm, accum, stats);
    k_dft<<<B * 5, 256, 0, stream>>>(xm, power);
    k_spec<<<B, 256, 0, stream>>>(power, stats);
    k_histA<<<B * 4, 256, 0, stream>>>(x, hist);
    k_histB<<<B, 256, 0, stream>>>(hist, binsel, krem);
    k_compact<<<B * 16, 256, 0, stream>>>(x, binsel, ccnt, cand);
    k_select<<<B * NSEL, 256, 0, stream>>>(cand, ccnt, binsel, krem, qv);
    k_qwrite<<<1, 64, 0, stream>>>(qv, stats);
    k_gram<<<B * 16, 256, 0, stream>>>(x, mu, gram);
    k_power<<<B, 1024, 0, stream>>>(gram, accum, stats);
}

// Round 4
// 865.156 us; speedup vs baseline: 2.5012x; 1.4178x over previous
//
#include <hip/hip_runtime.h>
#include <math.h>
#include <stdint.h>

#define B 64
#define T 2048
#define D 256
#define HID 32
#define NSEL 6
#define NBIN 8192      // 13-bit bins: sign + 8 exp + 4 mantissa
#define CAP 8192
#define LCAP 2048      // per-block per-bin LDS candidate capacity
#define EPS 1e-8

// accum slots per batch (stride 16 doubles)
#define A_S1 0
#define A_S2 1
#define A_S3 2
#define A_S4 3
#define A_AC 4
#define A_Y2 5
#define A_DIAG 6
#define A_TRACE 7
#define A_N 16

// 32 iters: worst-case Rayleigh err ~1% of lambda1 -> var_exp abs err ~1e-4 << 0.13 thr
#define NAPPLY 32

typedef __attribute__((ext_vector_type(4))) short short4v;
typedef __attribute__((ext_vector_type(8))) short short8v;
typedef __attribute__((ext_vector_type(4))) float f32x4;

// ---------------- sortable float keys ----------------
__device__ __forceinline__ unsigned int f2key(float f) {
    unsigned int u = __float_as_uint(f);
    return (u & 0x80000000u) ? ~u : (u | 0x80000000u);
}
__device__ __forceinline__ float key2f(unsigned int k) {
    unsigned int u = (k & 0x80000000u) ? (k ^ 0x80000000u) : ~k;
    return __uint_as_float(u);
}
// f32 -> bf16 (round-nearest-even)
__device__ __forceinline__ short f2bf(float f) {
    unsigned int u = __float_as_uint(f);
    unsigned int r = u + 0x7FFFu + ((u >> 16) & 1u);
    return (short)(r >> 16);
}

// ---------------- pass1: fused moments / autocorr / row means / mask / channel sums ----------------
__global__ __launch_bounds__(256) void k_pass1(const float* __restrict__ x, const int* __restrict__ mask,
        double* __restrict__ xm, float* __restrict__ rowm,
        double* __restrict__ cs1, double* __restrict__ cs2, double* __restrict__ accum) {
    int b = blockIdx.x >> 4;
    int blk = blockIdx.x & 15;
    int wave = threadIdx.x >> 6;
    int lane = threadIdx.x & 63;
    int ts = blk * 128 + wave * 32;
    const float* xb = x + (size_t)b * T * D;
    const int* mb = mask + (size_t)b * T * D;
    double c1l[4] = {0, 0, 0, 0}, c2l[4] = {0, 0, 0, 0};
    double s1 = 0, s2 = 0, s3 = 0, s4 = 0, ac = 0;
    float pa[4] = {0, 0, 0, 0};
    for (int r = 0; r < 32; ++r) {
        int t = ts + r;
        float4 xv = *(const float4*)(xb + (size_t)t * D + lane * 4);
        int4 mv = *(const int4*)(mb + (size_t)t * D + lane * 4);
        double rs = (double)xv.x + (double)xv.y + (double)xv.z + (double)xv.w;
        int rm = mv.x + mv.y + mv.z + mv.w;
        for (int o = 32; o > 0; o >>= 1) { rs += __shfl_down(rs, o); rm += __shfl_down(rm, o); }
        if (lane == 0) {
            xm[(size_t)b * T + t] = rs * (1.0 / 256.0);
            rowm[(size_t)b * T + t] = (float)rm;
        }
        float xa[4] = {xv.x, xv.y, xv.z, xv.w};
        #pragma unroll
        for (int j = 0; j < 4; ++j) {
            double xd = (double)xa[j];
            double x2 = xd * xd;
            s1 += xd; s2 += x2; s3 += x2 * xd; s4 += x2 * x2;
            c1l[j] += xd; c2l[j] += x2;
        }
        if (r > 0) {
            #pragma unroll
            for (int j = 0; j < 4; ++j) ac += (double)pa[j] * (double)xa[j];
        }
        pa[0] = xa[0]; pa[1] = xa[1]; pa[2] = xa[2]; pa[3] = xa[3];
    }
    if (ts + 32 <= T - 1) {
        float4 xn = *(const float4*)(xb + (size_t)(ts + 32) * D + lane * 4);
        float na[4] = {xn.x, xn.y, xn.z, xn.w};
        #pragma unroll
        for (int j = 0; j < 4; ++j) ac += (double)pa[j] * (double)na[j];
    }
    for (int o = 32; o > 0; o >>= 1) {
        s1 += __shfl_down(s1, o); s2 += __shfl_down(s2, o);
        s3 += __shfl_down(s3, o); s4 += __shfl_down(s4, o);
        ac += __shfl_down(ac, o);
    }
    if (lane == 0) {
        atomicAdd(&accum[b * A_N + A_S1], s1);
        atomicAdd(&accum[b * A_N + A_S2], s2);
        atomicAdd(&accum[b * A_N + A_S3], s3);
        atomicAdd(&accum[b * A_N + A_S4], s4);
        atomicAdd(&accum[b * A_N + A_AC], ac);
    }
    #pragma unroll
    for (int j = 0; j < 4; ++j) {
        atomicAdd(&cs1[b * D + lane * 4 + j], c1l[j]);
        atomicAdd(&cs2[b * D + lane * 4 + j], c2l[j]);
    }
}

// ---------------- per-channel finalize: mu, 1/std, diag-corr sum, trace ----------------
__global__ __launch_bounds__(256) void k_chan(const double* __restrict__ cs1, const double* __restrict__ cs2,
        float* __restrict__ mu, float* __restrict__ winv, double* __restrict__ accum) {
    int b = blockIdx.x, d = threadIdx.x;
    double c1 = cs1[b * D + d], c2 = cs2[b * D + d];
    double m = c1 / (double)T;
    double c2c = c2 - c1 * c1 / (double)T;
    double var = c2c / (double)(T - 1);
    mu[b * D + d] = (float)m;
    winv[b * D + d] = (float)(1.0 / sqrt(var));
    double diag = (c2c / ((double)(T - 1) + EPS)) / (var + EPS);
    __shared__ double sd[256], st[256];
    sd[d] = diag; st[d] = c2c; __syncthreads();
    for (int o = 128; o > 0; o >>= 1) {
        if (d < o) { sd[d] += sd[d + o]; st[d] += st[d + o]; }
        __syncthreads();
    }
    if (d == 0) { accum[b * A_N + A_DIAG] = sd[0]; accum[b * A_N + A_TRACE] = st[0]; }
}

// ---------------- attention logits: tanh(x@Wa1+ba1)@Wa2+ba2 ----------------
__global__ __launch_bounds__(256) void k_attn(const float* __restrict__ x,
        const float* __restrict__ Wa1, const float* __restrict__ ba1,
        const float* __restrict__ Wa2, const float* __restrict__ ba2,
        float* __restrict__ logit) {
    __shared__ float tile[256][33];   // +1 pad: conflict-free column reads
    int bid = blockIdx.x;
    int b = bid >> 3, t0 = (bid & 7) * 256;
    int tid = threadIdx.x;
    const float* xb = x + (size_t)b * T * D + (size_t)t0 * D;
    float acc[HID];
    #pragma unroll
    for (int h = 0; h < HID; ++h) acc[h] = 0.f;
    for (int dc = 0; dc < 8; ++dc) {
        __syncthreads();
        #pragma unroll
        for (int i = 0; i < 32; ++i) {
            int idx = i * 256 + tid;
            int tl = idx >> 5, dd = idx & 31;
            tile[tl][dd] = xb[(size_t)tl * D + dc * 32 + dd];
        }
        __syncthreads();
        #pragma unroll
        for (int dd = 0; dd < 32; ++dd) {
            float xval = tile[tid][dd];
            const float* wrow = Wa1 + (dc * 32 + dd) * HID;   // wave-uniform -> s_load
            #pragma unroll
            for (int h = 0; h < HID; ++h) acc[h] += xval * wrow[h];
        }
    }
    float lg = ba2[0];
    #pragma unroll
    for (int h = 0; h < HID; ++h) lg += tanhf(acc[h] + ba1[h]) * Wa2[h];
    logit[(size_t)b * T + t0 + tid] = lg;
}

// ---------------- softmax max & denominator over T ----------------
__global__ __launch_bounds__(256) void k_smax(const float* __restrict__ logit, float* __restrict__ smz) {
    int b = blockIdx.x, tid = threadIdx.x;
    __shared__ float sm[256];
    __shared__ double sz[256];
    float mx = -1e30f;
    for (int i = tid; i < T; i += 256) mx = fmaxf(mx, logit[(size_t)b * T + i]);
    sm[tid] = mx; __syncthreads();
    for (int o = 128; o > 0; o >>= 1) { if (tid < o) sm[tid] = fmaxf(sm[tid], sm[tid + o]); __syncthreads(); }
    float m = sm[0];
    double z = 0;
    for (int i = tid; i < T; i += 256) z += (double)expf(logit[(size_t)b * T + i] - m);
    sz[tid] = z; __syncthreads();
    for (int o = 128; o > 0; o >>= 1) { if (tid < o) sz[tid] += sz[tid + o]; __syncthreads(); }
    if (tid == 0) { smz[b * 2] = m; smz[b * 2 + 1] = (float)sz[0]; }
}

// ---------------- fused: attention pooling + mean_corr y-pass ----------------
__global__ __launch_bounds__(256) void k_pool(const float* __restrict__ x,
        const float* __restrict__ logit, const float* __restrict__ smz,
        const float* __restrict__ mu, const float* __restrict__ winv,
        float* __restrict__ hpool, double* __restrict__ accum) {
    int bid = blockIdx.x;
    int b = bid >> 3, t0 = (bid & 7) * 256;
    int wave = threadIdx.x >> 6, lane = threadIdx.x & 63;
    const float* xb = x + (size_t)b * T * D;
    float m = smz[b * 2], Z = smz[b * 2 + 1];
    float4 mu4 = *(const float4*)(mu + b * D + lane * 4);
    float4 w4 = *(const float4*)(winv + b * D + lane * 4);
    double p0 = 0, p1 = 0, p2 = 0, p3 = 0, yacc = 0;
    for (int r = 0; r < 64; ++r) {
        int t = t0 + wave * 64 + r;
        float4 xv = *(const float4*)(xb + (size_t)t * D + lane * 4);
        float wt = expf(logit[(size_t)b * T + t] - m) / Z;
        p0 += (double)(wt * xv.x); p1 += (double)(wt * xv.y);
        p2 += (double)(wt * xv.z); p3 += (double)(wt * xv.w);
        double y = (double)((xv.x - mu4.x) * w4.x) + (double)((xv.y - mu4.y) * w4.y)
                 + (double)((xv.z - mu4.z) * w4.z) + (double)((xv.w - mu4.w) * w4.w);
        for (int o = 32; o > 0; o >>= 1) y += __shfl_down(y, o);
        if (lane == 0) yacc += y * y;
    }
    if (lane == 0) atomicAdd(&accum[b * A_N + A_Y2], yacc);
    atomicAdd(&hpool[b * D + lane * 4 + 0], (float)p0);
    atomicAdd(&hpool[b * D + lane * 4 + 1], (float)p1);
    atomicAdd(&hpool[b * D + lane * 4 + 2], (float)p2);
    atomicAdd(&hpool[b * D + lane * 4 + 3], (float)p3);
}

// ---------------- routing head MLP + softmax(logits/temp) ----------------
__global__ void k_route(const float* __restrict__ hpool,
        const float* __restrict__ Wr1, const float* __restrict__ br1,
        const float* __restrict__ Wr2, const float* __restrict__ br2,
        const float* __restrict__ Wr3, const float* __restrict__ br3,
        const float* __restrict__ temperature, float* __restrict__ alpha) {
    int b = blockIdx.x, tid = threadIdx.x;   // 64 threads
    __shared__ float z1[HID], z2[HID], hp[D];
    for (int i = tid; i < D; i += 64) hp[i] = hpool[b * D + i];
    __syncthreads();
    if (tid < HID) {
        float a = br1[tid];
        for (int d = 0; d < D; ++d) a += hp[d] * Wr1[d * HID + tid];
        z1[tid] = fmaxf(a, 0.f);
    }
    __syncthreads();
    if (tid < HID) {
        float a = br2[tid];
        for (int j = 0; j < HID; ++j) a += z1[j] * Wr2[j * HID + tid];
        z2[tid] = fmaxf(a, 0.f);
    }
    __syncthreads();
    if (tid == 0) {
        float tmp = temperature[0];
        tmp = fminf(fmaxf(tmp, 0.5f), 2.0f);
        float lg[3];
        for (int k = 0; k < 3; ++k) {
            float a = br3[k];
            for (int j = 0; j < HID; ++j) a += z2[j] * Wr3[j * 3 + k];
            lg[k] = a / tmp;
        }
        float mx = fmaxf(lg[0], fmaxf(lg[1], lg[2]));
        float e0 = expf(lg[0] - mx), e1 = expf(lg[1] - mx), e2 = expf(lg[2] - mx);
        float s = e0 + e1 + e2;
        alpha[b * 3 + 0] = e0 / s; alpha[b * 3 + 1] = e1 / s; alpha[b * 3 + 2] = e2 / s;
    }
}

// ---------------- xm-based stats + scalar finalize ----------------
__global__ __launch_bounds__(256) void k_xmstats(const double* __restrict__ xm,
        const float* __restrict__ rowm, const double* __restrict__ accum,
        float* __restrict__ stats) {
    int b = blockIdx.x, tid = threadIdx.x;
    __shared__ double xs[T];
    __shared__ double r0[256], r1[256], r2[256];
    __shared__ int i0[256], i1[256];
    const double* xmb = xm + (size_t)b * T;
    for (int i = tid; i < T; i += 256) xs[i] = xmb[i];
    __syncthreads();
    double ls = 0;
    for (int i = tid; i < T; i += 256) ls += xs[i];
    r0[tid] = ls; __syncthreads();
    for (int o = 128; o > 0; o >>= 1) { if (tid < o) r0[tid] += r0[tid + o]; __syncthreads(); }
    double xmean = r0[0] / (double)T;
    __syncthreads();
    double tn = 0, roc = 0; int pk = 0, zc = 0;
    for (int i = tid; i < T; i += 256) {
        tn += ((double)i - 1023.5) * (xs[i] - xmean);
        if (i <= T - 2) {
            double d1 = xs[i + 1] - xs[i];
            roc += fabs(d1);
            if (i >= 1) { double d0 = xs[i] - xs[i - 1]; if (d0 * d1 < 0.0) pk++; }
            if ((xs[i] - xmean) * (xs[i + 1] - xmean) < 0.0) zc++;
        }
    }
    r0[tid] = tn; r1[tid] = roc; i0[tid] = pk; i1[tid] = zc; __syncthreads();
    for (int o = 128; o > 0; o >>= 1) {
        if (tid < o) { r0[tid] += r0[tid + o]; r1[tid] += r1[tid + o]; i0[tid] += i0[tid + o]; i1[tid] += i1[tid + o]; }
        __syncthreads();
    }
    double trendnum = r0[0], rocsum = r1[0];
    int pks = i0[0], zcs = i1[0];
    __syncthreads();
    double ds = 0, ds2 = 0, obs = 0; int ft = T;
    for (int i = tid; i < T; i += 256) {
        double rm = (double)rowm[(size_t)b * T + i];
        obs += rm;
        double dn = rm / (256.0 + EPS);
        ds += dn; ds2 += dn * dn;
        if (rm > 0.0 && i < ft) ft = i;
    }
    r0[tid] = ds; r1[tid] = ds2; r2[tid] = obs; i0[tid] = ft; __syncthreads();
    for (int o = 128; o > 0; o >>= 1) {
        if (tid < o) { r0[tid] += r0[tid + o]; r1[tid] += r1[tid + o]; r2[tid] += r2[tid + o]; i0[tid] = min(i0[tid], i0[tid + o]); }
        __syncthreads();
    }
    if (tid == 0) {
        double dsum = r0[0], dsq = r1[0], obst = r2[0]; int ftt = i0[0];
        const double n = (double)T * (double)D;
        const double* ab = accum + b * A_N;
        double s1 = ab[A_S1], s2 = ab[A_S2], s3 = ab[A_S3], s4 = ab[A_S4];
        double acv = ab[A_AC], y2 = ab[A_Y2], dg = ab[A_DIAG];
        double mu_ = s1 / n;
        double m2 = s2 / n - mu_ * mu_;
        double m3 = s3 / n - 3.0 * mu_ * (s2 / n) + 2.0 * mu_ * mu_ * mu_;
        double m4 = s4 / n - 4.0 * mu_ * (s3 / n) + 6.0 * mu_ * mu_ * (s2 / n) - 3.0 * mu_ * mu_ * mu_ * mu_;
        float* st = stats + b * 17;
        st[0] = (float)(acv / ((double)(T - 1) * (double)D));
        st[1] = (float)(trendnum / (715827712.0 + EPS));
        st[4] = (float)(m3 / (sqrt(m2) * m2 + EPS));
        st[5] = (float)(m4 / (m2 * m2 + EPS));
        st[9] = (float)((double)pks / (double)(T - 2));
        st[10] = (float)((double)zcs / (double)(T - 1));
        st[11] = (float)(rocsum / (double)(T - 1));
        st[12] = (float)(1.0 - obst / ((double)T * (double)D + EPS));
        double dmean = dsum / (double)T;
        st[13] = (float)((dsq - dsum * dmean) / (double)(T - 1));
        st[14] = (ftt < T) ? (float)((double)ftt / (double)T) : 0.0f;
        st[15] = (float)((y2 / ((double)(T - 1) + EPS) - dg) / ((double)D * (D - 1) + EPS));
    }
}

// ---------------- DFT of xm: complex-rotation recurrence, no tables ----------------
__global__ __launch_bounds__(256) void k_dft(const double* __restrict__ xm, double* __restrict__ power) {
    __shared__ double xs[T];   // 16 KB only (tables eliminated)
    int b = blockIdx.x / 5, kc = blockIdx.x % 5;
    int tid = threadIdx.x;
    for (int i = tid; i < T; i += 256) xs[i] = xm[(size_t)b * T + i];
    __syncthreads();
    int k = kc * 256 + tid;
    if (k <= T / 2) {
        double theta = -6.283185307179586476925286766559 * (double)k / (double)T;
        double c4 = cos(4.0 * theta), s4 = sin(4.0 * theta);
        double cr = 1.0, ci = 0.0;
        double a0r = 0, a0i = 0, a1r = 0, a1i = 0, a2r = 0, a2i = 0, a3r = 0, a3i = 0;
        #pragma unroll 4
        for (int p = 0; p < T / 4; ++p) {
            double x0 = xs[4 * p + 0], x1 = xs[4 * p + 1];
            double x2 = xs[4 * p + 2], x3 = xs[4 * p + 3];
            a0r += x0 * cr; a0i += x0 * ci;
            a1r += x1 * cr; a1i += x1 * ci;
            a2r += x2 * cr; a2i += x2 * ci;
            a3r += x3 * cr; a3i += x3 * ci;
            double ncr = cr * c4 - ci * s4;
            double nci = cr * s4 + ci * c4;
            cr = ncr; ci = nci;
        }
        double c1 = cos(theta), s1 = sin(theta);
        double ar = a0r, ai = a0i;
        ar += c1 * a1r - s1 * a1i; ai += c1 * a1i + s1 * a1r;
        double c2 = c1 * c1 - s1 * s1, s2 = 2.0 * c1 * s1;
        ar += c2 * a2r - s2 * a2i; ai += c2 * a2i + s2 * a2r;
        double c3 = c2 * c1 - s2 * s1, s3 = c2 * s1 + s2 * c1;
        ar += c3 * a3r - s3 * a3i; ai += c3 * a3i + s3 * a3r;
        power[(size_t)b * 1025 + k] = ar * ar + ai * ai;
    }
}

// ---------------- spectral: argmax + entropy ----------------
__global__ __launch_bounds__(256) void k_spec(const double* __restrict__ power, float* __restrict__ stats) {
    int b = blockIdx.x, tid = threadIdx.x;
    __shared__ double rv[256];
    __shared__ int ri[256];
    const double* pb = power + (size_t)b * 1025;
    double bm = -1.0; int bi = 0; double lsum = 0;
    for (int i = tid; i < 1025; i += 256) {
        double p = pb[i];
        lsum += p;
        if (p > bm) { bm = p; bi = i; }
    }
    rv[tid] = bm; ri[tid] = bi; __syncthreads();
    for (int o = 128; o > 0; o >>= 1) {
        if (tid < o) {
            if (rv[tid + o] > rv[tid] || (rv[tid + o] == rv[tid] && ri[tid + o] < ri[tid])) {
                rv[tid] = rv[tid + o]; ri[tid] = ri[tid + o];
            }
        }
        __syncthreads();
    }
    int amax = ri[0];
    __syncthreads();
    rv[tid] = lsum; __syncthreads();
    for (int o = 128; o > 0; o >>= 1) { if (tid < o) rv[tid] += rv[tid + o]; __syncthreads(); }
    double S = rv[0] + EPS;
    __syncthreads();
    double le = 0;
    for (int i = tid; i < 1025; i += 256) {
        double pn = pb[i] / S;
        le -= pn * log(pn + EPS);
    }
    rv[tid] = le; __syncthreads();
    for (int o = 128; o > 0; o >>= 1) { if (tid < o) rv[tid] += rv[tid + o]; __syncthreads(); }
    if (tid == 0) {
        stats[b * 17 + 2] = (float)((double)amax / (double)(T / 2));
        stats[b * 17 + 3] = (float)rv[0];
    }
}

// ---------------- quantiles: 13-bit histogram ----------------
__global__ __launch_bounds__(256) void k_histA(const float* __restrict__ x, unsigned int* __restrict__ hist) {
    __shared__ unsigned int lh[NBIN];   // 32 KB
    int b = blockIdx.x >> 2, chunk = blockIdx.x & 3;
    int tid = threadIdx.x;
    for (int i = tid; i < NBIN; i += 256) lh[i] = 0;
    __syncthreads();
    const float4* xb = (const float4*)(x + (size_t)b * T * D + (size_t)chunk * (T * D / 4));
    for (int i = tid; i < T * D / 16; i += 256) {
        float4 v = xb[i];
        atomicAdd(&lh[f2key(v.x) >> 19], 1u);
        atomicAdd(&lh[f2key(v.y) >> 19], 1u);
        atomicAdd(&lh[f2key(v.z) >> 19], 1u);
        atomicAdd(&lh[f2key(v.w) >> 19], 1u);
    }
    __syncthreads();
    for (int i = tid; i < NBIN; i += 256)
        if (lh[i]) atomicAdd(&hist[(size_t)b * NBIN + i], lh[i]);
}

// ---------------- quantiles: locate bin + within-bin rank for each target ----------------
__global__ __launch_bounds__(256) void k_histB(const unsigned int* __restrict__ hist,
        unsigned int* __restrict__ binsel, unsigned int* __restrict__ krem) {
    int b = blockIdx.x, tid = threadIdx.x;
    __shared__ unsigned int seg[256], base[256];
    const unsigned int* hb = hist + (size_t)b * NBIN;
    unsigned int s = 0;
    for (int i = 0; i < 32; ++i) s += hb[tid * 32 + i];
    seg[tid] = s; __syncthreads();
    if (tid == 0) {
        unsigned int run = 0;
        for (int i = 0; i < 256; ++i) { base[i] = run; run += seg[i]; }
    }
    __syncthreads();
    const unsigned int targets[NSEL] = {131071u, 131072u, 262143u, 262144u, 393215u, 393216u};
    for (int q = 0; q < NSEL; ++q) {
        unsigned int k = targets[q];
        if (k >= base[tid] && k < base[tid] + seg[tid]) {
            unsigned int run = base[tid];
            for (int i = 0; i < 32; ++i) {
                unsigned int c = hb[tid * 32 + i];
                if (k < run + c) { binsel[b * NSEL + q] = tid * 32 + i; krem[b * NSEL + q] = k - run; break; }
                run += c;
            }
        }
    }
}

// ---------------- quantiles: compact candidates (LDS-aggregated) ----------------
__global__ __launch_bounds__(256) void k_compact(const float* __restrict__ x,
        const unsigned int* __restrict__ binsel, unsigned int* __restrict__ ccnt,
        unsigned int* __restrict__ cand) {
    __shared__ unsigned int lbuf[NSEL][LCAP];   // 48 KB
    __shared__ unsigned int lcnt[NSEL];
    __shared__ unsigned int gbase[NSEL];
    int b = blockIdx.x >> 4, chunk = blockIdx.x & 15;
    int tid = threadIdx.x;
    if (tid < NSEL) lcnt[tid] = 0;
    unsigned int bs[NSEL];
    #pragma unroll
    for (int q = 0; q < NSEL; ++q) bs[q] = binsel[b * NSEL + q];
    __syncthreads();
    const float4* xb = (const float4*)(x + (size_t)b * T * D + (size_t)chunk * (T * D / 16));
    for (int it = 0; it < 32; ++it) {
        float4 v = xb[it * 256 + tid];
        float va[4] = {v.x, v.y, v.z, v.w};
        #pragma unroll
        for (int j = 0; j < 4; ++j) {
            unsigned int u = f2key(va[j]);
            unsigned int bin = u >> 19;
            #pragma unroll
            for (int q = 0; q < NSEL; ++q) {
                if (bin == bs[q]) {
                    unsigned int p = atomicAdd(&lcnt[q], 1u);
                    if (p < LCAP) lbuf[q][p] = u;
                }
            }
        }
        __syncthreads();
        bool need = false;
        #pragma unroll
        for (int q = 0; q < NSEL; ++q) need = need || (lcnt[q] > (unsigned)(LCAP - 1024));
        if (need) {
            if (tid < NSEL) {
                unsigned int n = min(lcnt[tid], (unsigned)LCAP);
                gbase[tid] = atomicAdd(&ccnt[b * NSEL + tid], n);
            }
            __syncthreads();
            #pragma unroll
            for (int q = 0; q < NSEL; ++q) {
                unsigned int n = min(lcnt[q], (unsigned)LCAP);
                unsigned int g0 = gbase[q];
                for (unsigned int i = tid; i < n; i += 256) {
                    unsigned int p = g0 + i;
                    if (p < CAP) cand[((size_t)b * NSEL + q) * CAP + p] = lbuf[q][i];
                }
            }
            __syncthreads();
            if (tid < NSEL) lcnt[tid] = 0;
            __syncthreads();
        }
    }
    __syncthreads();
    if (tid < NSEL) {
        unsigned int n = min(lcnt[tid], (unsigned)LCAP);
        gbase[tid] = atomicAdd(&ccnt[b * NSEL + tid], n);
    }
    __syncthreads();
    #pragma unroll
    for (int q = 0; q < NSEL; ++q) {
        unsigned int n = min(lcnt[q], (unsigned)LCAP);
        unsigned int g0 = gbase[q];
        for (unsigned int i = tid; i < n; i += 256) {
            unsigned int p = g0 + i;
            if (p < CAP) cand[((size_t)b * NSEL + q) * CAP + p] = lbuf[q][i];
        }
    }
}

// ---------------- quantiles: bitwise exact select ----------------
__global__ __launch_bounds__(256) void k_select(const unsigned int* __restrict__ cand,
        const unsigned int* __restrict__ ccnt, const unsigned int* __restrict__ binsel,
        const unsigned int* __restrict__ krem, float* __restrict__ qv) {
    int b = blockIdx.x / NSEL, q = blockIdx.x % NSEL;
    int tid = threadIdx.x;
    __shared__ unsigned int lc[CAP];   // 32 KB
    __shared__ unsigned int rc[256];
    unsigned int n = ccnt[b * NSEL + q];
    if (n > CAP) n = CAP;
    for (unsigned int i = tid; i < n; i += 256) lc[i] = cand[((size_t)b * NSEL + q) * CAP + i];
    __syncthreads();
    unsigned int prefix = binsel[b * NSEL + q] << 19;
    unsigned int k = krem[b * NSEL + q];
    for (int bit = 18; bit >= 0; --bit) {
        unsigned int hi = prefix >> (bit + 1);
        unsigned int c = 0;
        for (unsigned int i = tid; i < n; i += 256) {
            unsigned int u = lc[i];
            if ((u >> (bit + 1)) == hi && !((u >> bit) & 1u)) c++;
        }
        rc[tid] = c; __syncthreads();
        for (int o = 128; o > 0; o >>= 1) { if (tid < o) rc[tid] += rc[tid + o]; __syncthreads(); }
        unsigned int c0 = rc[0];
        __syncthreads();
        if (k >= c0) { k -= c0; prefix |= (1u << bit); }
    }
    if (tid == 0) qv[b * NSEL + q] = key2f(prefix);
}

// ---------------- quantile interpolation -> stats ----------------
__global__ void k_qwrite(const float* __restrict__ qv, float* __restrict__ stats) {
    int b = threadIdx.x;
    if (b >= B) return;
    const float* qq = qv + b * NSEL;
    double q25 = 0.25 * (double)qq[0] + 0.75 * (double)qq[1];
    double q50 = 0.5 * ((double)qq[2] + (double)qq[3]);
    double q75 = 0.75 * (double)qq[4] + 0.25 * (double)qq[5];
    stats[b * 17 + 6] = (float)q25;
    stats[b * 17 + 7] = (float)q50;
    stats[b * 17 + 8] = (float)q75;
}

// ---------------- gram = Xc^T Xc via bf16 MFMA (128x128 tile per block) ----------------
// LDS layout (per slab): xT[c][t] k-contiguous bf16, row = 128 shorts data + 8 pad (144 B),
// with t-block rotation rot = ((t>>3) + (c>>2)) & 7 to break staging-write bank collisions.
// A-frag (16x16x32 bf16): lane holds A[m=lane&15][k=quad*8+j]; B-frag: B[k=quad*8+j][n=lane&15];
// D: row=quad*4+reg, col=lane&15  [guide §3, m89/m120-verified].
#define GROWS 72   // shorts per LDS row (64 data + 8 pad)
__global__ __launch_bounds__(256) void k_gram(const float* __restrict__ x, const float* __restrict__ mu,
        float* __restrict__ gram) {
    __shared__ __align__(16) short lds_a[128 * GROWS];
    __shared__ __align__(16) short lds_b[128 * GROWS];
    int b = blockIdx.x >> 2;
    int ti = (blockIdx.x >> 1) & 1, tj = blockIdx.x & 1;
    int i0 = ti * 128, j0 = tj * 128;
    int tid = threadIdx.x;
    int w = tid >> 6, lane = tid & 63;
    int qd = lane >> 4, l15 = lane & 15;
    const float* xb = x + (size_t)b * T * D;
    const float* mub = mu + (size_t)b * D;
    // staging constants (mc/channel fixed per thread across K-steps)
    int mc = tid & 31;
    float4 mua = *(const float4*)(mub + i0 + 4 * mc);
    float4 mub4 = *(const float4*)(mub + j0 + 4 * mc);
    f32x4 acc[2][8];
    #pragma unroll
    for (int rt = 0; rt < 2; ++rt)
        #pragma unroll
        for (int ct = 0; ct < 8; ++ct) acc[rt][ct] = (f32x4){0.f, 0.f, 0.f, 0.f};
    for (int t0 = 0; t0 < T; t0 += 64) {
        __syncthreads();
        // stage both slabs: 2 micro-tiles (4c x 4t) per thread per slab
        #pragma unroll
        for (int half = 0; half < 2; ++half) {
            int mtt = (tid >> 5) + half * 8;      // t-group 0..15
            int t = t0 + 4 * mtt;
            int tblk = mtt >> 1;
            int sub = (mtt & 1) * 4;
            int rot = (tblk + mc) & 7;
            // slab A (i-channels)
            {
                const float* src = xb + (size_t)t * D + i0 + 4 * mc;
                float4 r0 = *(const float4*)(src);
                float4 r1 = *(const float4*)(src + D);
                float4 r2 = *(const float4*)(src + 2 * D);
                float4 r3 = *(const float4*)(src + 3 * D);
                float a0[4] = {r0.x - mua.x, r0.y - mua.y, r0.z - mua.z, r0.w - mua.w};
                float a1[4] = {r1.x - mua.x, r1.y - mua.y, r1.z - mua.z, r1.w - mua.w};
                float a2[4] = {r2.x - mua.x, r2.y - mua.y, r2.z - mua.z, r2.w - mua.w};
                float a3[4] = {r3.x - mua.x, r3.y - mua.y, r3.z - mua.z, r3.w - mua.w};
                #pragma unroll
                for (int j = 0; j < 4; ++j) {
                    int c = 4 * mc + j;
                    short4v v4 = {f2bf(a0[j]), f2bf(a1[j]), f2bf(a2[j]), f2bf(a3[j])};
                    *(short4v*)(lds_a + c * GROWS + rot * 8 + sub) = v4;
                }
            }
            // slab B (j-channels)
            {
                const float* src = xb + (size_t)t * D + j0 + 4 * mc;
                float4 r0 = *(const float4*)(src);
                float4 r1 = *(const float4*)(src + D);
                float4 r2 = *(const float4*)(src + 2 * D);
                float4 r3 = *(const float4*)(src + 3 * D);
                float a0[4] = {r0.x - mub4.x, r0.y - mub4.y, r0.z - mub4.z, r0.w - mub4.w};
                float a1[4] = {r1.x - mub4.x, r1.y - mub4.y, r1.z - mub4.z, r1.w - mub4.w};
                float a2[4] = {r2.x - mub4.x, r2.y - mub4.y, r2.z - mub4.z, r2.w - mub4.w};
                float a3[4] = {r3.x - mub4.x, r3.y - mub4.y, r3.z - mub4.z, r3.w - mub4.w};
                #pragma unroll
                for (int j = 0; j < 4; ++j) {
                    int c = 4 * mc + j;
                    short4v v4 = {f2bf(a0[j]), f2bf(a1[j]), f2bf(a2[j]), f2bf(a3[j])};
                    *(short4v*)(lds_b + c * GROWS + rot * 8 + sub) = v4;
                }
            }
        }
        __syncthreads();
        // MFMA: wave w computes rows [w*32, w*32+32) of the 128x128 tile
        #pragma unroll
        for (int kc = 0; kc < 2; ++kc) {
            int tblk = kc * 4 + qd;
            short8v af[2];
            #pragma unroll
            for (int rt = 0; rt < 2; ++rt) {
                int c = w * 32 + rt * 16 + l15;
                int rot = (tblk + (c >> 2)) & 7;
                af[rt] = *(const short8v*)(lds_a + c * GROWS + rot * 8);
            }
            short8v bfr[8];
            #pragma unroll
            for (int ct = 0; ct < 8; ++ct) {
                int c = ct * 16 + l15;
                int rot = (tblk + (c >> 2)) & 7;
                bfr[ct] = *(const short8v*)(lds_b + c * GROWS + rot * 8);
            }
            #pragma unroll
            for (int rt = 0; rt < 2; ++rt)
                #pragma unroll
                for (int ct = 0; ct < 8; ++ct)
                    acc[rt][ct] = __builtin_amdgcn_mfma_f32_16x16x32_bf16(af[rt], bfr[ct], acc[rt][ct], 0, 0, 0);
        }
    }
    // epilogue: D row = quad*4 + reg, col = lane&15
    float* gb = gram + (size_t)b * D * D;
    #pragma unroll
    for (int rt = 0; rt < 2; ++rt) {
        int rbase = i0 + w * 32 + rt * 16 + qd * 4;
        #pragma unroll
        for (int ct = 0; ct < 8; ++ct) {
            int cc = j0 + ct * 16 + l15;
            #pragma unroll
            for (int reg = 0; reg < 4; ++reg)
                gb[(size_t)(rbase + reg) * D + cc] = acc[rt][ct][reg];
        }
    }
}

// ---------------- power iteration for lambda_max -> var_exp ----------------
// round-2 structure (1.13 us/iter measured): row-slice G in regs, broadcast v-reads,
// 4-way LDS reduction. NAPPLY=32 suffices (Rayleigh err ~1% of lambda1 worst case).
__global__ __launch_bounds__(1024) void k_power(const float* __restrict__ gram,
        const double* __restrict__ accum, float* __restrict__ stats) {
    int b = blockIdx.x;
    int tid = threadIdx.x;
    int row = tid & 255, sl = tid >> 8;   // 4 column-slices of 64
    __shared__ __align__(16) float v[2][D];
    __shared__ float part[1024];
    __shared__ double dpart[1024];
    const float* g = gram + (size_t)b * D * D + (size_t)row * D + sl * 64;
    float gr[64];
    #pragma unroll
    for (int j = 0; j < 64; j += 4) {
        float4 t4 = *(const float4*)(g + j);
        gr[j] = t4.x; gr[j + 1] = t4.y; gr[j + 2] = t4.z; gr[j + 3] = t4.w;
    }
    if (tid < D) {
        float h = sinf((float)tid * 12.9898f) * 43758.547f;
        v[0][tid] = h - floorf(h) - 0.4375f;
    }
    __syncthreads();
    int cur = 0;
    for (int it = 0; it < NAPPLY; ++it) {
        const float* vv = &v[cur][sl * 64];
        float acc = 0.f;
        #pragma unroll
        for (int j = 0; j < 64; j += 4) {
            float4 vb = *(const float4*)(vv + j);
            acc += gr[j] * vb.x + gr[j + 1] * vb.y + gr[j + 2] * vb.z + gr[j + 3] * vb.w;
        }
        part[tid] = acc; __syncthreads();
        if (tid < D) v[cur ^ 1][tid] = part[tid] + part[tid + 256] + part[tid + 512] + part[tid + 768];
        cur ^= 1;
        if ((it & 7) == 7 || it == NAPPLY - 1) {
            __syncthreads();
            double nl = 0;
            if (tid < D) { double yv = (double)v[cur][tid]; nl = yv * yv; }
            dpart[tid] = nl; __syncthreads();
            for (int o = 512; o > 0; o >>= 1) { if (tid < o) dpart[tid] += dpart[tid + o]; __syncthreads(); }
            float inv = (float)(1.0 / sqrt(dpart[0]));
            __syncthreads();
            if (tid < D) v[cur][tid] *= inv;
        }
        __syncthreads();
    }
    // Rayleigh quotient
    const float* vv = &v[cur][sl * 64];
    float acc = 0.f;
    #pragma unroll
    for (int j = 0; j < 64; j += 4) {
        float4 vb = *(const float4*)(vv + j);
        acc += gr[j] * vb.x + gr[j + 1] * vb.y + gr[j + 2] * vb.z + gr[j + 3] * vb.w;
    }
    part[tid] = acc; __syncthreads();
    double num = 0, den = 0;
    if (tid < D) {
        double wv = (double)part[tid] + (double)part[tid + 256] + (double)part[tid + 512] + (double)part[tid + 768];
        double vd = (double)v[cur][tid];
        num = vd * wv; den = vd * vd;
    }
    dpart[tid] = num; __syncthreads();
    for (int o = 512; o > 0; o >>= 1) { if (tid < o) dpart[tid] += dpart[tid + o]; __syncthreads(); }
    double lam = dpart[0];
    __syncthreads();
    dpart[tid] = den; __syncthreads();
    for (int o = 512; o > 0; o >>= 1) { if (tid < o) dpart[tid] += dpart[tid + o]; __syncthreads(); }
    if (tid == 0) {
        double trace = accum[b * A_N + A_TRACE];
        stats[b * 17 + 16] = (float)(lam / dpart[0] / trace);
    }
}

// ---------------- host launcher ----------------
extern "C" void kernel_launch(void* const* d_in, const int* in_sizes, int n_in,
                              void* d_out, int out_size, void* d_ws, size_t ws_size,
                              hipStream_t stream) {
    (void)in_sizes; (void)n_in; (void)ws_size;
    const float* x    = (const float*)d_in[0];
    const int*   mask = (const int*)d_in[1];
    const float* Wa1  = (const float*)d_in[2];
    const float* ba1  = (const float*)d_in[3];
    const float* Wa2  = (const float*)d_in[4];
    const float* ba2  = (const float*)d_in[5];
    const float* Wr1  = (const float*)d_in[6];
    const float* br1  = (const float*)d_in[7];
    const float* Wr2  = (const float*)d_in[8];
    const float* br2  = (const float*)d_in[9];
    const float* Wr3  = (const float*)d_in[10];
    const float* br3  = (const float*)d_in[11];
    const float* temp = (const float*)d_in[12];

    float* out = (float*)d_out;
    float* alpha = out;                 // 64*3
    float* hpool = out + 192;           // 64*256
    float* stats = out + 192 + 16384;   // 64*17

    char* w = (char*)d_ws;
    size_t off = 0;
    auto alloc = [&](size_t bytes) -> char* {
        char* p = w + off;
        off = (off + bytes + 255) & ~(size_t)255;
        return p;
    };
    // zeroed region first
    double* cs1 = (double*)alloc((size_t)B * D * 8);
    double* cs2 = (double*)alloc((size_t)B * D * 8);
    double* accum = (double*)alloc((size_t)B * A_N * 8);
    unsigned int* ccnt = (unsigned int*)alloc((size_t)B * NSEL * 4);
    unsigned int* hist = (unsigned int*)alloc((size_t)B * NBIN * 4);
    size_t zero_bytes = off;
    // non-zeroed
    double* xm = (double*)alloc((size_t)B * T * 8);
    float* rowm = (float*)alloc((size_t)B * T * 4);
    float* logit = (float*)alloc((size_t)B * T * 4);
    float* smz = (float*)alloc((size_t)B * 2 * 4);
    float* mu = (float*)alloc((size_t)B * D * 4);
    float* winv = (float*)alloc((size_t)B * D * 4);
    double* power = (double*)alloc((size_t)B * 1025 * 8);
    unsigned int* binsel = (unsigned int*)alloc((size_t)B * NSEL * 4);
    unsigned int* krem = (unsigned int*)alloc((size_t)B * NSEL * 4);
    float* qv = (float*)alloc((size_t)B * NSEL * 4);
    // cand (12.6MB) and gram (16.8MB) temporally disjoint -> union region
    size_t union_bytes = (size_t)B * D * D * 4;
    char* ureg = alloc(union_bytes);
    unsigned int* cand = (unsigned int*)ureg;
    float* gram = (float*)ureg;

    hipMemsetAsync(d_ws, 0, zero_bytes, stream);
    hipMemsetAsync(d_out, 0, (size_t)out_size * 4, stream);

    k_pass1<<<B * 16, 256, 0, stream>>>(x, mask, xm, rowm, cs1, cs2, accum);
    k_chan<<<B, 256, 0, stream>>>(cs1, cs2, mu, winv, accum);
    k_attn<<<B * 8, 256, 0, stream>>>(x, Wa1, ba1, Wa2, ba2, logit);
    k_smax<<<B, 256, 0, stream>>>(logit, smz);
    k_pool<<<B * 8, 256, 0, stream>>>(x, logit, smz, mu, winv, hpool, accum);
    k_route<<<B, 64, 0, stream>>>(hpool, Wr1, br1, Wr2, br2, Wr3, br3, temp, alpha);
    k_xmstats<<<B, 256, 0, stream>>>(xm, rowm, accum, stats);
    k_dft<<<B * 5, 256, 0, stream>>>(xm, power);
    k_spec<<<B, 256, 0, stream>>>(power, stats);
    k_histA<<<B * 4, 256, 0, stream>>>(x, hist);
    k_histB<<<B, 256, 0, stream>>>(hist, binsel, krem);
    k_compact<<<B * 16, 256, 0, stream>>>(x, binsel, ccnt, cand);
    k_select<<<B * NSEL, 256, 0, stream>>>(cand, ccnt, binsel, krem, qv);
    k_qwrite<<<1, 64, 0, stream>>>(qv, stats);
    k_gram<<<B * 4, 256, 0, stream>>>(x, mu, gram);
    k_power<<<B, 1024, 0, stream>>>(gram, accum, stats);
}

// Round 5
// 816.204 us; speedup vs baseline: 2.6512x; 1.0600x over previous
//
#include <hip/hip_runtime.h>
#include <math.h>
#include <stdint.h>

#define B 64
#define T 2048
#define D 256
#define HID 32
#define NSEL 6
#define NBIN 8192      // 13-bit bins: sign + 8 exp + 4 mantissa
#define CAP 8192
#define LCAP 2048      // per-block per-bin LDS candidate capacity
#define EPS 1e-8

// accum slots per batch (stride 16 doubles)
#define A_S1 0
#define A_S2 1
#define A_S3 2
#define A_S4 3
#define A_AC 4
#define A_Y2 5
#define A_DIAG 6
#define A_TRACE 7
#define A_N 16

// 32 iters: worst-case Rayleigh err ~1% of lambda1 -> var_exp abs err ~1e-4 << 0.13 thr
#define NAPPLY 32

typedef __attribute__((ext_vector_type(4))) short short4v;
typedef __attribute__((ext_vector_type(8))) short short8v;
typedef __attribute__((ext_vector_type(4))) float f32x4;

// ---------------- sortable float keys ----------------
__device__ __forceinline__ unsigned int f2key(float f) {
    unsigned int u = __float_as_uint(f);
    return (u & 0x80000000u) ? ~u : (u | 0x80000000u);
}
__device__ __forceinline__ float key2f(unsigned int k) {
    unsigned int u = (k & 0x80000000u) ? (k ^ 0x80000000u) : ~k;
    return __uint_as_float(u);
}
// f32 -> bf16 (round-nearest-even)
__device__ __forceinline__ short f2bf(float f) {
    unsigned int u = __float_as_uint(f);
    unsigned int r = u + 0x7FFFu + ((u >> 16) & 1u);
    return (short)(r >> 16);
}

// ---------------- pass1: fused moments / autocorr / row means / mask / channel sums ----------------
// No global atomics for channel sums (per-block partials); row sums via LDS transpose
// (column-major buf, (4k+q)%32 bank-free) instead of 6-deep f64 shfl chains.
#define RST 132
__global__ __launch_bounds__(256) void k_pass1(const float* __restrict__ x, const int* __restrict__ mask,
        double* __restrict__ xm, float* __restrict__ rowm,
        double* __restrict__ cs1p, double* __restrict__ cs2p, double* __restrict__ accum) {
    __shared__ float rsb[16 * RST];
    __shared__ float rmb[16 * RST];
    __shared__ double cbuf[4][64][8];
    __shared__ double sacc[4][5];
    int b = blockIdx.x >> 4;
    int blk = blockIdx.x & 15;
    int wave = threadIdx.x >> 6;
    int lane = threadIdx.x & 63;
    int tid = threadIdx.x;
    int ts = blk * 128 + wave * 32;
    const float* xb = x + (size_t)b * T * D;
    const int* mb = mask + (size_t)b * T * D;
    double c1l[4] = {0, 0, 0, 0}, c2l[4] = {0, 0, 0, 0};
    double s1 = 0, s2 = 0, s3 = 0, s4 = 0, ac = 0;
    float pa[4] = {0, 0, 0, 0};
    for (int r = 0; r < 32; ++r) {
        int t = ts + r;
        float4 xv = *(const float4*)(xb + (size_t)t * D + lane * 4);
        int4 mv = *(const int4*)(mb + (size_t)t * D + lane * 4);
        float rsf = xv.x + xv.y + xv.z + xv.w;
        float rmf = (float)(mv.x + mv.y + mv.z + mv.w);
        rsf += __shfl_xor(rsf, 1); rsf += __shfl_xor(rsf, 2);
        rmf += __shfl_xor(rmf, 1); rmf += __shfl_xor(rmf, 2);
        int q = wave * 32 + r;
        if ((lane & 3) == 0) {
            rsb[(lane >> 2) * RST + q] = rsf;
            rmb[(lane >> 2) * RST + q] = rmf;
        }
        float xa[4] = {xv.x, xv.y, xv.z, xv.w};
        #pragma unroll
        for (int j = 0; j < 4; ++j) {
            double xd = (double)xa[j];
            double x2 = xd * xd;
            s1 += xd; s2 += x2; s3 += x2 * xd; s4 += x2 * x2;
            c1l[j] += xd; c2l[j] += x2;
        }
        if (r > 0) {
            #pragma unroll
            for (int j = 0; j < 4; ++j) ac += (double)pa[j] * (double)xa[j];
        }
        pa[0] = xa[0]; pa[1] = xa[1]; pa[2] = xa[2]; pa[3] = xa[3];
    }
    if (ts + 32 <= T - 1) {
        float4 xn = *(const float4*)(xb + (size_t)(ts + 32) * D + lane * 4);
        float na[4] = {xn.x, xn.y, xn.z, xn.w};
        #pragma unroll
        for (int j = 0; j < 4; ++j) ac += (double)pa[j] * (double)na[j];
    }
    // per-wave scalar butterfly (once per kernel, not per row)
    for (int o = 32; o > 0; o >>= 1) {
        s1 += __shfl_down(s1, o); s2 += __shfl_down(s2, o);
        s3 += __shfl_down(s3, o); s4 += __shfl_down(s4, o);
        ac += __shfl_down(ac, o);
    }
    if (lane == 0) {
        sacc[wave][0] = s1; sacc[wave][1] = s2; sacc[wave][2] = s3;
        sacc[wave][3] = s4; sacc[wave][4] = ac;
    }
    #pragma unroll
    for (int j = 0; j < 4; ++j) {
        cbuf[wave][lane][j] = c1l[j];
        cbuf[wave][lane][4 + j] = c2l[j];
    }
    __syncthreads();
    // phase 2: row sums (128 rows), conflict-free column reads
    if (tid < 128) {
        float rs = 0.f, rm = 0.f;
        #pragma unroll
        for (int k = 0; k < 16; ++k) { rs += rsb[k * RST + tid]; rm += rmb[k * RST + tid]; }
        xm[(size_t)b * T + blk * 128 + tid] = (double)rs * (1.0 / 256.0);
        rowm[(size_t)b * T + blk * 128 + tid] = rm;
    }
    // channel partials (plain coalesced writes, no atomics)
    if (tid < 64) {
        #pragma unroll
        for (int j = 0; j < 4; ++j) {
            double c1 = cbuf[0][tid][j] + cbuf[1][tid][j] + cbuf[2][tid][j] + cbuf[3][tid][j];
            double c2 = cbuf[0][tid][4 + j] + cbuf[1][tid][4 + j] + cbuf[2][tid][4 + j] + cbuf[3][tid][4 + j];
            cs1p[((size_t)b * 16 + blk) * 256 + tid * 4 + j] = c1;
            cs2p[((size_t)b * 16 + blk) * 256 + tid * 4 + j] = c2;
        }
    }
    if (tid < 5) {
        double s = sacc[0][tid] + sacc[1][tid] + sacc[2][tid] + sacc[3][tid];
        atomicAdd(&accum[b * A_N + tid], s);   // A_S1..A_AC == 0..4
    }
}

// ---------------- per-channel finalize: mu, 1/std, diag-corr sum, trace ----------------
__global__ __launch_bounds__(256) void k_chan(const double* __restrict__ cs1p, const double* __restrict__ cs2p,
        float* __restrict__ mu, float* __restrict__ winv, double* __restrict__ accum) {
    int b = blockIdx.x, d = threadIdx.x;
    double c1 = 0, c2 = 0;
    #pragma unroll
    for (int k = 0; k < 16; ++k) {
        c1 += cs1p[((size_t)b * 16 + k) * 256 + d];
        c2 += cs2p[((size_t)b * 16 + k) * 256 + d];
    }
    double m = c1 / (double)T;
    double c2c = c2 - c1 * c1 / (double)T;
    double var = c2c / (double)(T - 1);
    mu[b * D + d] = (float)m;
    winv[b * D + d] = (float)(1.0 / sqrt(var));
    double diag = (c2c / ((double)(T - 1) + EPS)) / (var + EPS);
    __shared__ double sd[256], st[256];
    sd[d] = diag; st[d] = c2c; __syncthreads();
    for (int o = 128; o > 0; o >>= 1) {
        if (d < o) { sd[d] += sd[d + o]; st[d] += st[d + o]; }
        __syncthreads();
    }
    if (d == 0) { accum[b * A_N + A_DIAG] = sd[0]; accum[b * A_N + A_TRACE] = st[0]; }
}

// ---------------- attention logits: tanh(x@Wa1+ba1)@Wa2+ba2 ----------------
__global__ __launch_bounds__(256) void k_attn(const float* __restrict__ x,
        const float* __restrict__ Wa1, const float* __restrict__ ba1,
        const float* __restrict__ Wa2, const float* __restrict__ ba2,
        float* __restrict__ logit) {
    __shared__ float tile[256][33];   // +1 pad: conflict-free column reads
    int bid = blockIdx.x;
    int b = bid >> 3, t0 = (bid & 7) * 256;
    int tid = threadIdx.x;
    const float* xb = x + (size_t)b * T * D + (size_t)t0 * D;
    float acc[HID];
    #pragma unroll
    for (int h = 0; h < HID; ++h) acc[h] = 0.f;
    for (int dc = 0; dc < 8; ++dc) {
        __syncthreads();
        #pragma unroll
        for (int i = 0; i < 32; ++i) {
            int idx = i * 256 + tid;
            int tl = idx >> 5, dd = idx & 31;
            tile[tl][dd] = xb[(size_t)tl * D + dc * 32 + dd];
        }
        __syncthreads();
        #pragma unroll
        for (int dd = 0; dd < 32; ++dd) {
            float xval = tile[tid][dd];
            const float* wrow = Wa1 + (dc * 32 + dd) * HID;   // wave-uniform -> s_load
            #pragma unroll
            for (int h = 0; h < HID; ++h) acc[h] += xval * wrow[h];
        }
    }
    float lg = ba2[0];
    #pragma unroll
    for (int h = 0; h < HID; ++h) lg += tanhf(acc[h] + ba1[h]) * Wa2[h];
    logit[(size_t)b * T + t0 + tid] = lg;
}

// ---------------- softmax max & denominator over T ----------------
__global__ __launch_bounds__(256) void k_smax(const float* __restrict__ logit, float* __restrict__ smz) {
    int b = blockIdx.x, tid = threadIdx.x;
    __shared__ float sm[256];
    __shared__ double sz[256];
    float mx = -1e30f;
    for (int i = tid; i < T; i += 256) mx = fmaxf(mx, logit[(size_t)b * T + i]);
    sm[tid] = mx; __syncthreads();
    for (int o = 128; o > 0; o >>= 1) { if (tid < o) sm[tid] = fmaxf(sm[tid], sm[tid + o]); __syncthreads(); }
    float m = sm[0];
    double z = 0;
    for (int i = tid; i < T; i += 256) z += (double)expf(logit[(size_t)b * T + i] - m);
    sz[tid] = z; __syncthreads();
    for (int o = 128; o > 0; o >>= 1) { if (tid < o) sz[tid] += sz[tid + o]; __syncthreads(); }
    if (tid == 0) { smz[b * 2] = m; smz[b * 2 + 1] = (float)sz[0]; }
}

// ---------------- fused: attention pooling + mean_corr y-pass ----------------
// hpool via per-block partials (no global atomics); y row-sum via LDS transpose.
#define YST 260
__global__ __launch_bounds__(256) void k_pool(const float* __restrict__ x,
        const float* __restrict__ logit, const float* __restrict__ smz,
        const float* __restrict__ mu, const float* __restrict__ winv,
        float* __restrict__ hpoolp, double* __restrict__ accum) {
    __shared__ float ybuf[16 * YST];
    __shared__ float pbuf[4][64][4];
    __shared__ double dred[256];
    int bid = blockIdx.x;
    int b = bid >> 3, blk = bid & 7, t0 = blk * 256;
    int wave = threadIdx.x >> 6, lane = threadIdx.x & 63;
    int tid = threadIdx.x;
    const float* xb = x + (size_t)b * T * D;
    float m = smz[b * 2], Z = smz[b * 2 + 1];
    float4 mu4 = *(const float4*)(mu + b * D + lane * 4);
    float4 w4 = *(const float4*)(winv + b * D + lane * 4);
    float p0 = 0.f, p1 = 0.f, p2 = 0.f, p3 = 0.f;
    for (int r = 0; r < 64; ++r) {
        int t = t0 + wave * 64 + r;
        float4 xv = *(const float4*)(xb + (size_t)t * D + lane * 4);
        float wt = expf(logit[(size_t)b * T + t] - m) / Z;
        p0 += wt * xv.x; p1 += wt * xv.y; p2 += wt * xv.z; p3 += wt * xv.w;
        float yl = (xv.x - mu4.x) * w4.x + (xv.y - mu4.y) * w4.y
                 + (xv.z - mu4.z) * w4.z + (xv.w - mu4.w) * w4.w;
        yl += __shfl_xor(yl, 1); yl += __shfl_xor(yl, 2);
        int q = wave * 64 + r;
        if ((lane & 3) == 0) ybuf[(lane >> 2) * YST + q] = yl;
    }
    pbuf[wave][lane][0] = p0; pbuf[wave][lane][1] = p1;
    pbuf[wave][lane][2] = p2; pbuf[wave][lane][3] = p3;
    __syncthreads();
    // y^2 block-sum
    {
        float y = 0.f;
        #pragma unroll
        for (int k = 0; k < 16; ++k) y += ybuf[k * YST + tid];
        dred[tid] = (double)y * (double)y;
    }
    __syncthreads();
    for (int o = 128; o > 0; o >>= 1) { if (tid < o) dred[tid] += dred[tid + o]; __syncthreads(); }
    if (tid == 0) atomicAdd(&accum[b * A_N + A_Y2], dred[0]);
    // hpool partial write
    if (tid < 64) {
        #pragma unroll
        for (int j = 0; j < 4; ++j) {
            float s = pbuf[0][tid][j] + pbuf[1][tid][j] + pbuf[2][tid][j] + pbuf[3][tid][j];
            hpoolp[((size_t)b * 8 + blk) * 256 + tid * 4 + j] = s;
        }
    }
}

// ---------------- routing head: sum hpool partials + MLP + softmax(logits/temp) ----------------
__global__ __launch_bounds__(256) void k_route(const float* __restrict__ hpoolp,
        const float* __restrict__ Wr1, const float* __restrict__ br1,
        const float* __restrict__ Wr2, const float* __restrict__ br2,
        const float* __restrict__ Wr3, const float* __restrict__ br3,
        const float* __restrict__ temperature, float* __restrict__ hpool,
        float* __restrict__ alpha) {
    int b = blockIdx.x, tid = threadIdx.x;   // 256 threads
    __shared__ float z1[HID], z2[HID], hp[D];
    {
        float s = 0.f;
        #pragma unroll
        for (int k = 0; k < 8; ++k) s += hpoolp[((size_t)b * 8 + k) * 256 + tid];
        hp[tid] = s;
        hpool[b * D + tid] = s;
    }
    __syncthreads();
    if (tid < HID) {
        float a = br1[tid];
        for (int d = 0; d < D; ++d) a += hp[d] * Wr1[d * HID + tid];
        z1[tid] = fmaxf(a, 0.f);
    }
    __syncthreads();
    if (tid < HID) {
        float a = br2[tid];
        for (int j = 0; j < HID; ++j) a += z1[j] * Wr2[j * HID + tid];
        z2[tid] = fmaxf(a, 0.f);
    }
    __syncthreads();
    if (tid == 0) {
        float tmp = temperature[0];
        tmp = fminf(fmaxf(tmp, 0.5f), 2.0f);
        float lg[3];
        for (int k = 0; k < 3; ++k) {
            float a = br3[k];
            for (int j = 0; j < HID; ++j) a += z2[j] * Wr3[j * 3 + k];
            lg[k] = a / tmp;
        }
        float mx = fmaxf(lg[0], fmaxf(lg[1], lg[2]));
        float e0 = expf(lg[0] - mx), e1 = expf(lg[1] - mx), e2 = expf(lg[2] - mx);
        float s = e0 + e1 + e2;
        alpha[b * 3 + 0] = e0 / s; alpha[b * 3 + 1] = e1 / s; alpha[b * 3 + 2] = e2 / s;
    }
}

// ---------------- xm-based stats + scalar finalize ----------------
__global__ __launch_bounds__(256) void k_xmstats(const double* __restrict__ xm,
        const float* __restrict__ rowm, const double* __restrict__ accum,
        float* __restrict__ stats) {
    int b = blockIdx.x, tid = threadIdx.x;
    __shared__ double xs[T];
    __shared__ double r0[256], r1[256], r2[256];
    __shared__ int i0[256], i1[256];
    const double* xmb = xm + (size_t)b * T;
    for (int i = tid; i < T; i += 256) xs[i] = xmb[i];
    __syncthreads();
    double ls = 0;
    for (int i = tid; i < T; i += 256) ls += xs[i];
    r0[tid] = ls; __syncthreads();
    for (int o = 128; o > 0; o >>= 1) { if (tid < o) r0[tid] += r0[tid + o]; __syncthreads(); }
    double xmean = r0[0] / (double)T;
    __syncthreads();
    double tn = 0, roc = 0; int pk = 0, zc = 0;
    for (int i = tid; i < T; i += 256) {
        tn += ((double)i - 1023.5) * (xs[i] - xmean);
        if (i <= T - 2) {
            double d1 = xs[i + 1] - xs[i];
            roc += fabs(d1);
            if (i >= 1) { double d0 = xs[i] - xs[i - 1]; if (d0 * d1 < 0.0) pk++; }
            if ((xs[i] - xmean) * (xs[i + 1] - xmean) < 0.0) zc++;
        }
    }
    r0[tid] = tn; r1[tid] = roc; i0[tid] = pk; i1[tid] = zc; __syncthreads();
    for (int o = 128; o > 0; o >>= 1) {
        if (tid < o) { r0[tid] += r0[tid + o]; r1[tid] += r1[tid + o]; i0[tid] += i0[tid + o]; i1[tid] += i1[tid + o]; }
        __syncthreads();
    }
    double trendnum = r0[0], rocsum = r1[0];
    int pks = i0[0], zcs = i1[0];
    __syncthreads();
    double ds = 0, ds2 = 0, obs = 0; int ft = T;
    for (int i = tid; i < T; i += 256) {
        double rm = (double)rowm[(size_t)b * T + i];
        obs += rm;
        double dn = rm / (256.0 + EPS);
        ds += dn; ds2 += dn * dn;
        if (rm > 0.0 && i < ft) ft = i;
    }
    r0[tid] = ds; r1[tid] = ds2; r2[tid] = obs; i0[tid] = ft; __syncthreads();
    for (int o = 128; o > 0; o >>= 1) {
        if (tid < o) { r0[tid] += r0[tid + o]; r1[tid] += r1[tid + o]; r2[tid] += r2[tid + o]; i0[tid] = min(i0[tid], i0[tid + o]); }
        __syncthreads();
    }
    if (tid == 0) {
        double dsum = r0[0], dsq = r1[0], obst = r2[0]; int ftt = i0[0];
        const double n = (double)T * (double)D;
        const double* ab = accum + b * A_N;
        double s1 = ab[A_S1], s2 = ab[A_S2], s3 = ab[A_S3], s4 = ab[A_S4];
        double acv = ab[A_AC], y2 = ab[A_Y2], dg = ab[A_DIAG];
        double mu_ = s1 / n;
        double m2 = s2 / n - mu_ * mu_;
        double m3 = s3 / n - 3.0 * mu_ * (s2 / n) + 2.0 * mu_ * mu_ * mu_;
        double m4 = s4 / n - 4.0 * mu_ * (s3 / n) + 6.0 * mu_ * mu_ * (s2 / n) - 3.0 * mu_ * mu_ * mu_ * mu_;
        float* st = stats + b * 17;
        st[0] = (float)(acv / ((double)(T - 1) * (double)D));
        st[1] = (float)(trendnum / (715827712.0 + EPS));
        st[4] = (float)(m3 / (sqrt(m2) * m2 + EPS));
        st[5] = (float)(m4 / (m2 * m2 + EPS));
        st[9] = (float)((double)pks / (double)(T - 2));
        st[10] = (float)((double)zcs / (double)(T - 1));
        st[11] = (float)(rocsum / (double)(T - 1));
        st[12] = (float)(1.0 - obst / ((double)T * (double)D + EPS));
        double dmean = dsum / (double)T;
        st[13] = (float)((dsq - dsum * dmean) / (double)(T - 1));
        st[14] = (ftt < T) ? (float)((double)ftt / (double)T) : 0.0f;
        st[15] = (float)((y2 / ((double)(T - 1) + EPS) - dg) / ((double)D * (D - 1) + EPS));
    }
}

// ---------------- DFT of xm: complex-rotation recurrence, no tables ----------------
__global__ __launch_bounds__(256) void k_dft(const double* __restrict__ xm, double* __restrict__ power) {
    __shared__ double xs[T];   // 16 KB only (tables eliminated)
    int b = blockIdx.x / 5, kc = blockIdx.x % 5;
    int tid = threadIdx.x;
    for (int i = tid; i < T; i += 256) xs[i] = xm[(size_t)b * T + i];
    __syncthreads();
    int k = kc * 256 + tid;
    if (k <= T / 2) {
        double theta = -6.283185307179586476925286766559 * (double)k / (double)T;
        double c4 = cos(4.0 * theta), s4 = sin(4.0 * theta);
        double cr = 1.0, ci = 0.0;
        double a0r = 0, a0i = 0, a1r = 0, a1i = 0, a2r = 0, a2i = 0, a3r = 0, a3i = 0;
        #pragma unroll 4
        for (int p = 0; p < T / 4; ++p) {
            double x0 = xs[4 * p + 0], x1 = xs[4 * p + 1];
            double x2 = xs[4 * p + 2], x3 = xs[4 * p + 3];
            a0r += x0 * cr; a0i += x0 * ci;
            a1r += x1 * cr; a1i += x1 * ci;
            a2r += x2 * cr; a2i += x2 * ci;
            a3r += x3 * cr; a3i += x3 * ci;
            double ncr = cr * c4 - ci * s4;
            double nci = cr * s4 + ci * c4;
            cr = ncr; ci = nci;
        }
        double c1 = cos(theta), s1 = sin(theta);
        double ar = a0r, ai = a0i;
        ar += c1 * a1r - s1 * a1i; ai += c1 * a1i + s1 * a1r;
        double c2 = c1 * c1 - s1 * s1, s2 = 2.0 * c1 * s1;
        ar += c2 * a2r - s2 * a2i; ai += c2 * a2i + s2 * a2r;
        double c3 = c2 * c1 - s2 * s1, s3 = c2 * s1 + s2 * c1;
        ar += c3 * a3r - s3 * a3i; ai += c3 * a3i + s3 * a3r;
        power[(size_t)b * 1025 + k] = ar * ar + ai * ai;
    }
}

// ---------------- spectral: argmax + entropy ----------------
__global__ __launch_bounds__(256) void k_spec(const double* __restrict__ power, float* __restrict__ stats) {
    int b = blockIdx.x, tid = threadIdx.x;
    __shared__ double rv[256];
    __shared__ int ri[256];
    const double* pb = power + (size_t)b * 1025;
    double bm = -1.0; int bi = 0; double lsum = 0;
    for (int i = tid; i < 1025; i += 256) {
        double p = pb[i];
        lsum += p;
        if (p > bm) { bm = p; bi = i; }
    }
    rv[tid] = bm; ri[tid] = bi; __syncthreads();
    for (int o = 128; o > 0; o >>= 1) {
        if (tid < o) {
            if (rv[tid + o] > rv[tid] || (rv[tid + o] == rv[tid] && ri[tid + o] < ri[tid])) {
                rv[tid] = rv[tid + o]; ri[tid] = ri[tid + o];
            }
        }
        __syncthreads();
    }
    int amax = ri[0];
    __syncthreads();
    rv[tid] = lsum; __syncthreads();
    for (int o = 128; o > 0; o >>= 1) { if (tid < o) rv[tid] += rv[tid + o]; __syncthreads(); }
    double S = rv[0] + EPS;
    __syncthreads();
    double le = 0;
    for (int i = tid; i < 1025; i += 256) {
        double pn = pb[i] / S;
        le -= pn * log(pn + EPS);
    }
    rv[tid] = le; __syncthreads();
    for (int o = 128; o > 0; o >>= 1) { if (tid < o) rv[tid] += rv[tid + o]; __syncthreads(); }
    if (tid == 0) {
        stats[b * 17 + 2] = (float)((double)amax / (double)(T / 2));
        stats[b * 17 + 3] = (float)rv[0];
    }
}

// ---------------- quantiles: 13-bit histogram ----------------
__global__ __launch_bounds__(256) void k_histA(const float* __restrict__ x, unsigned int* __restrict__ hist) {
    __shared__ unsigned int lh[NBIN];   // 32 KB
    int b = blockIdx.x >> 2, chunk = blockIdx.x & 3;
    int tid = threadIdx.x;
    for (int i = tid; i < NBIN; i += 256) lh[i] = 0;
    __syncthreads();
    const float4* xb = (const float4*)(x + (size_t)b * T * D + (size_t)chunk * (T * D / 4));
    for (int i = tid; i < T * D / 16; i += 256) {
        float4 v = xb[i];
        atomicAdd(&lh[f2key(v.x) >> 19], 1u);
        atomicAdd(&lh[f2key(v.y) >> 19], 1u);
        atomicAdd(&lh[f2key(v.z) >> 19], 1u);
        atomicAdd(&lh[f2key(v.w) >> 19], 1u);
    }
    __syncthreads();
    for (int i = tid; i < NBIN; i += 256)
        if (lh[i]) atomicAdd(&hist[(size_t)b * NBIN + i], lh[i]);
}

// ---------------- quantiles: locate bin + within-bin rank for each target ----------------
__global__ __launch_bounds__(256) void k_histB(const unsigned int* __restrict__ hist,
        unsigned int* __restrict__ binsel, unsigned int* __restrict__ krem) {
    int b = blockIdx.x, tid = threadIdx.x;
    __shared__ unsigned int seg[256], base[256];
    const unsigned int* hb = hist + (size_t)b * NBIN;
    unsigned int s = 0;
    for (int i = 0; i < 32; ++i) s += hb[tid * 32 + i];
    seg[tid] = s; __syncthreads();
    if (tid == 0) {
        unsigned int run = 0;
        for (int i = 0; i < 256; ++i) { base[i] = run; run += seg[i]; }
    }
    __syncthreads();
    const unsigned int targets[NSEL] = {131071u, 131072u, 262143u, 262144u, 393215u, 393216u};
    for (int q = 0; q < NSEL; ++q) {
        unsigned int k = targets[q];
        if (k >= base[tid] && k < base[tid] + seg[tid]) {
            unsigned int run = base[tid];
            for (int i = 0; i < 32; ++i) {
                unsigned int c = hb[tid * 32 + i];
                if (k < run + c) { binsel[b * NSEL + q] = tid * 32 + i; krem[b * NSEL + q] = k - run; break; }
                run += c;
            }
        }
    }
}

// ---------------- quantiles: compact candidates (LDS-aggregated) ----------------
__global__ __launch_bounds__(256) void k_compact(const float* __restrict__ x,
        const unsigned int* __restrict__ binsel, unsigned int* __restrict__ ccnt,
        unsigned int* __restrict__ cand) {
    __shared__ unsigned int lbuf[NSEL][LCAP];   // 48 KB
    __shared__ unsigned int lcnt[NSEL];
    __shared__ unsigned int gbase[NSEL];
    int b = blockIdx.x >> 4, chunk = blockIdx.x & 15;
    int tid = threadIdx.x;
    if (tid < NSEL) lcnt[tid] = 0;
    unsigned int bs[NSEL];
    #pragma unroll
    for (int q = 0; q < NSEL; ++q) bs[q] = binsel[b * NSEL + q];
    __syncthreads();
    const float4* xb = (const float4*)(x + (size_t)b * T * D + (size_t)chunk * (T * D / 16));
    for (int it = 0; it < 32; ++it) {
        float4 v = xb[it * 256 + tid];
        float va[4] = {v.x, v.y, v.z, v.w};
        #pragma unroll
        for (int j = 0; j < 4; ++j) {
            unsigned int u = f2key(va[j]);
            unsigned int bin = u >> 19;
            #pragma unroll
            for (int q = 0; q < NSEL; ++q) {
                if (bin == bs[q]) {
                    unsigned int p = atomicAdd(&lcnt[q], 1u);
                    if (p < LCAP) lbuf[q][p] = u;
                }
            }
        }
        __syncthreads();
        bool need = false;
        #pragma unroll
        for (int q = 0; q < NSEL; ++q) need = need || (lcnt[q] > (unsigned)(LCAP - 1024));
        if (need) {
            if (tid < NSEL) {
                unsigned int n = min(lcnt[tid], (unsigned)LCAP);
                gbase[tid] = atomicAdd(&ccnt[b * NSEL + tid], n);
            }
            __syncthreads();
            #pragma unroll
            for (int q = 0; q < NSEL; ++q) {
                unsigned int n = min(lcnt[q], (unsigned)LCAP);
                unsigned int g0 = gbase[q];
                for (unsigned int i = tid; i < n; i += 256) {
                    unsigned int p = g0 + i;
                    if (p < CAP) cand[((size_t)b * NSEL + q) * CAP + p] = lbuf[q][i];
                }
            }
            __syncthreads();
            if (tid < NSEL) lcnt[tid] = 0;
            __syncthreads();
        }
    }
    __syncthreads();
    if (tid < NSEL) {
        unsigned int n = min(lcnt[tid], (unsigned)LCAP);
        gbase[tid] = atomicAdd(&ccnt[b * NSEL + tid], n);
    }
    __syncthreads();
    #pragma unroll
    for (int q = 0; q < NSEL; ++q) {
        unsigned int n = min(lcnt[q], (unsigned)LCAP);
        unsigned int g0 = gbase[q];
        for (unsigned int i = tid; i < n; i += 256) {
            unsigned int p = g0 + i;
            if (p < CAP) cand[((size_t)b * NSEL + q) * CAP + p] = lbuf[q][i];
        }
    }
}

// ---------------- quantiles: bitwise exact select ----------------
__global__ __launch_bounds__(256) void k_select(const unsigned int* __restrict__ cand,
        const unsigned int* __restrict__ ccnt, const unsigned int* __restrict__ binsel,
        const unsigned int* __restrict__ krem, float* __restrict__ qv) {
    int b = blockIdx.x / NSEL, q = blockIdx.x % NSEL;
    int tid = threadIdx.x;
    __shared__ unsigned int lc[CAP];   // 32 KB
    __shared__ unsigned int rc[256];
    unsigned int n = ccnt[b * NSEL + q];
    if (n > CAP) n = CAP;
    for (unsigned int i = tid; i < n; i += 256) lc[i] = cand[((size_t)b * NSEL + q) * CAP + i];
    __syncthreads();
    unsigned int prefix = binsel[b * NSEL + q] << 19;
    unsigned int k = krem[b * NSEL + q];
    for (int bit = 18; bit >= 0; --bit) {
        unsigned int hi = prefix >> (bit + 1);
        unsigned int c = 0;
        for (unsigned int i = tid; i < n; i += 256) {
            unsigned int u = lc[i];
            if ((u >> (bit + 1)) == hi && !((u >> bit) & 1u)) c++;
        }
        rc[tid] = c; __syncthreads();
        for (int o = 128; o > 0; o >>= 1) { if (tid < o) rc[tid] += rc[tid + o]; __syncthreads(); }
        unsigned int c0 = rc[0];
        __syncthreads();
        if (k >= c0) { k -= c0; prefix |= (1u << bit); }
    }
    if (tid == 0) qv[b * NSEL + q] = key2f(prefix);
}

// ---------------- quantile interpolation -> stats ----------------
__global__ void k_qwrite(const float* __restrict__ qv, float* __restrict__ stats) {
    int b = threadIdx.x;
    if (b >= B) return;
    const float* qq = qv + b * NSEL;
    double q25 = 0.25 * (double)qq[0] + 0.75 * (double)qq[1];
    double q50 = 0.5 * ((double)qq[2] + (double)qq[3]);
    double q75 = 0.75 * (double)qq[4] + 0.25 * (double)qq[5];
    stats[b * 17 + 6] = (float)q25;
    stats[b * 17 + 7] = (float)q50;
    stats[b * 17 + 8] = (float)q75;
}

// ---------------- gram = Xc^T Xc via bf16 MFMA (128x128 tile per block) ----------------
#define GROWS 72   // shorts per LDS row (64 data + 8 pad)
__global__ __launch_bounds__(256) void k_gram(const float* __restrict__ x, const float* __restrict__ mu,
        float* __restrict__ gram) {
    __shared__ __align__(16) short lds_a[128 * GROWS];
    __shared__ __align__(16) short lds_b[128 * GROWS];
    int b = blockIdx.x >> 2;
    int ti = (blockIdx.x >> 1) & 1, tj = blockIdx.x & 1;
    int i0 = ti * 128, j0 = tj * 128;
    int tid = threadIdx.x;
    int w = tid >> 6, lane = tid & 63;
    int qd = lane >> 4, l15 = lane & 15;
    const float* xb = x + (size_t)b * T * D;
    const float* mub = mu + (size_t)b * D;
    int mc = tid & 31;
    float4 mua = *(const float4*)(mub + i0 + 4 * mc);
    float4 mub4 = *(const float4*)(mub + j0 + 4 * mc);
    f32x4 acc[2][8];
    #pragma unroll
    for (int rt = 0; rt < 2; ++rt)
        #pragma unroll
        for (int ct = 0; ct < 8; ++ct) acc[rt][ct] = (f32x4){0.f, 0.f, 0.f, 0.f};
    for (int t0 = 0; t0 < T; t0 += 64) {
        __syncthreads();
        #pragma unroll
        for (int half = 0; half < 2; ++half) {
            int mtt = (tid >> 5) + half * 8;      // t-group 0..15
            int t = t0 + 4 * mtt;
            int tblk = mtt >> 1;
            int sub = (mtt & 1) * 4;
            int rot = (tblk + mc) & 7;
            {
                const float* src = xb + (size_t)t * D + i0 + 4 * mc;
                float4 r0 = *(const float4*)(src);
                float4 r1 = *(const float4*)(src + D);
                float4 r2 = *(const float4*)(src + 2 * D);
                float4 r3 = *(const float4*)(src + 3 * D);
                float a0[4] = {r0.x - mua.x, r0.y - mua.y, r0.z - mua.z, r0.w - mua.w};
                float a1[4] = {r1.x - mua.x, r1.y - mua.y, r1.z - mua.z, r1.w - mua.w};
                float a2[4] = {r2.x - mua.x, r2.y - mua.y, r2.z - mua.z, r2.w - mua.w};
                float a3[4] = {r3.x - mua.x, r3.y - mua.y, r3.z - mua.z, r3.w - mua.w};
                #pragma unroll
                for (int j = 0; j < 4; ++j) {
                    int c = 4 * mc + j;
                    short4v v4 = {f2bf(a0[j]), f2bf(a1[j]), f2bf(a2[j]), f2bf(a3[j])};
                    *(short4v*)(lds_a + c * GROWS + rot * 8 + sub) = v4;
                }
            }
            {
                const float* src = xb + (size_t)t * D + j0 + 4 * mc;
                float4 r0 = *(const float4*)(src);
                float4 r1 = *(const float4*)(src + D);
                float4 r2 = *(const float4*)(src + 2 * D);
                float4 r3 = *(const float4*)(src + 3 * D);
                float a0[4] = {r0.x - mub4.x, r0.y - mub4.y, r0.z - mub4.z, r0.w - mub4.w};
                float a1[4] = {r1.x - mub4.x, r1.y - mub4.y, r1.z - mub4.z, r1.w - mub4.w};
                float a2[4] = {r2.x - mub4.x, r2.y - mub4.y, r2.z - mub4.z, r2.w - mub4.w};
                float a3[4] = {r3.x - mub4.x, r3.y - mub4.y, r3.z - mub4.z, r3.w - mub4.w};
                #pragma unroll
                for (int j = 0; j < 4; ++j) {
                    int c = 4 * mc + j;
                    short4v v4 = {f2bf(a0[j]), f2bf(a1[j]), f2bf(a2[j]), f2bf(a3[j])};
                    *(short4v*)(lds_b + c * GROWS + rot * 8 + sub) = v4;
                }
            }
        }
        __syncthreads();
        #pragma unroll
        for (int kc = 0; kc < 2; ++kc) {
            int tblk = kc * 4 + qd;
            short8v af[2];
            #pragma unroll
            for (int rt = 0; rt < 2; ++rt) {
                int c = w * 32 + rt * 16 + l15;
                int rot = (tblk + (c >> 2)) & 7;
                af[rt] = *(const short8v*)(lds_a + c * GROWS + rot * 8);
            }
            short8v bfr[8];
            #pragma unroll
            for (int ct = 0; ct < 8; ++ct) {
                int c = ct * 16 + l15;
                int rot = (tblk + (c >> 2)) & 7;
                bfr[ct] = *(const short8v*)(lds_b + c * GROWS + rot * 8);
            }
            #pragma unroll
            for (int rt = 0; rt < 2; ++rt)
                #pragma unroll
                for (int ct = 0; ct < 8; ++ct)
                    acc[rt][ct] = __builtin_amdgcn_mfma_f32_16x16x32_bf16(af[rt], bfr[ct], acc[rt][ct], 0, 0, 0);
        }
    }
    float* gb = gram + (size_t)b * D * D;
    #pragma unroll
    for (int rt = 0; rt < 2; ++rt) {
        int rbase = i0 + w * 32 + rt * 16 + qd * 4;
        #pragma unroll
        for (int ct = 0; ct < 8; ++ct) {
            int cc = j0 + ct * 16 + l15;
            #pragma unroll
            for (int reg = 0; reg < 4; ++reg)
                gb[(size_t)(rbase + reg) * D + cc] = acc[rt][ct][reg];
        }
    }
}

// ---------------- power iteration for lambda_max -> var_exp ----------------
__global__ __launch_bounds__(1024) void k_power(const float* __restrict__ gram,
        const double* __restrict__ accum, float* __restrict__ stats) {
    int b = blockIdx.x;
    int tid = threadIdx.x;
    int row = tid & 255, sl = tid >> 8;   // 4 column-slices of 64
    __shared__ __align__(16) float v[2][D];
    __shared__ float part[1024];
    __shared__ double dpart[1024];
    const float* g = gram + (size_t)b * D * D + (size_t)row * D + sl * 64;
    float gr[64];
    #pragma unroll
    for (int j = 0; j < 64; j += 4) {
        float4 t4 = *(const float4*)(g + j);
        gr[j] = t4.x; gr[j + 1] = t4.y; gr[j + 2] = t4.z; gr[j + 3] = t4.w;
    }
    if (tid < D) {
        float h = sinf((float)tid * 12.9898f) * 43758.547f;
        v[0][tid] = h - floorf(h) - 0.4375f;
    }
    __syncthreads();
    int cur = 0;
    for (int it = 0; it < NAPPLY; ++it) {
        const float* vv = &v[cur][sl * 64];
        float acc = 0.f;
        #pragma unroll
        for (int j = 0; j < 64; j += 4) {
            float4 vb = *(const float4*)(vv + j);
            acc += gr[j] * vb.x + gr[j + 1] * vb.y + gr[j + 2] * vb.z + gr[j + 3] * vb.w;
        }
        part[tid] = acc; __syncthreads();
        if (tid < D) v[cur ^ 1][tid] = part[tid] + part[tid + 256] + part[tid + 512] + part[tid + 768];
        cur ^= 1;
        if ((it & 7) == 7 || it == NAPPLY - 1) {
            __syncthreads();
            double nl = 0;
            if (tid < D) { double yv = (double)v[cur][tid]; nl = yv * yv; }
            dpart[tid] = nl; __syncthreads();
            for (int o = 512; o > 0; o >>= 1) { if (tid < o) dpart[tid] += dpart[tid + o]; __syncthreads(); }
            float inv = (float)(1.0 / sqrt(dpart[0]));
            __syncthreads();
            if (tid < D) v[cur][tid] *= inv;
        }
        __syncthreads();
    }
    const float* vv = &v[cur][sl * 64];
    float acc = 0.f;
    #pragma unroll
    for (int j = 0; j < 64; j += 4) {
        float4 vb = *(const float4*)(vv + j);
        acc += gr[j] * vb.x + gr[j + 1] * vb.y + gr[j + 2] * vb.z + gr[j + 3] * vb.w;
    }
    part[tid] = acc; __syncthreads();
    double num = 0, den = 0;
    if (tid < D) {
        double wv = (double)part[tid] + (double)part[tid + 256] + (double)part[tid + 512] + (double)part[tid + 768];
        double vd = (double)v[cur][tid];
        num = vd * wv; den = vd * vd;
    }
    dpart[tid] = num; __syncthreads();
    for (int o = 512; o > 0; o >>= 1) { if (tid < o) dpart[tid] += dpart[tid + o]; __syncthreads(); }
    double lam = dpart[0];
    __syncthreads();
    dpart[tid] = den; __syncthreads();
    for (int o = 512; o > 0; o >>= 1) { if (tid < o) dpart[tid] += dpart[tid + o]; __syncthreads(); }
    if (tid == 0) {
        double trace = accum[b * A_N + A_TRACE];
        stats[b * 17 + 16] = (float)(lam / dpart[0] / trace);
    }
}

// ---------------- host launcher ----------------
extern "C" void kernel_launch(void* const* d_in, const int* in_sizes, int n_in,
                              void* d_out, int out_size, void* d_ws, size_t ws_size,
                              hipStream_t stream) {
    (void)in_sizes; (void)n_in; (void)ws_size;
    const float* x    = (const float*)d_in[0];
    const int*   mask = (const int*)d_in[1];
    const float* Wa1  = (const float*)d_in[2];
    const float* ba1  = (const float*)d_in[3];
    const float* Wa2  = (const float*)d_in[4];
    const float* ba2  = (const float*)d_in[5];
    const float* Wr1  = (const float*)d_in[6];
    const float* br1  = (const float*)d_in[7];
    const float* Wr2  = (const float*)d_in[8];
    const float* br2  = (const float*)d_in[9];
    const float* Wr3  = (const float*)d_in[10];
    const float* br3  = (const float*)d_in[11];
    const float* temp = (const float*)d_in[12];

    float* out = (float*)d_out;
    float* alpha = out;                 // 64*3
    float* hpool = out + 192;           // 64*256
    float* stats = out + 192 + 16384;   // 64*17

    char* w = (char*)d_ws;
    size_t off = 0;
    auto alloc = [&](size_t bytes) -> char* {
        char* p = w + off;
        off = (off + bytes + 255) & ~(size_t)255;
        return p;
    };
    // zeroed region first
    double* accum = (double*)alloc((size_t)B * A_N * 8);
    unsigned int* ccnt = (unsigned int*)alloc((size_t)B * NSEL * 4);
    unsigned int* hist = (unsigned int*)alloc((size_t)B * NBIN * 4);
    size_t zero_bytes = off;
    // non-zeroed
    double* xm = (double*)alloc((size_t)B * T * 8);
    float* rowm = (float*)alloc((size_t)B * T * 4);
    float* logit = (float*)alloc((size_t)B * T * 4);
    float* smz = (float*)alloc((size_t)B * 2 * 4);
    float* mu = (float*)alloc((size_t)B * D * 4);
    float* winv = (float*)alloc((size_t)B * D * 4);
    double* power = (double*)alloc((size_t)B * 1025 * 8);
    unsigned int* binsel = (unsigned int*)alloc((size_t)B * NSEL * 4);
    unsigned int* krem = (unsigned int*)alloc((size_t)B * NSEL * 4);
    float* qv = (float*)alloc((size_t)B * NSEL * 4);
    // union region (16.8 MB): holds, non-overlapping in time:
    //   cs1p/cs2p (4 MB, dead after k_chan) + hpoolp (0.5 MB, dead after k_route)
    //   then cand (12.6 MB, k_compact..k_select), then gram (16.8 MB, k_gram..k_power)
    size_t union_bytes = (size_t)B * D * D * 4;
    char* ureg = alloc(union_bytes);
    double* cs1p = (double*)ureg;                                      // 64*16*256*8 = 2 MB
    double* cs2p = (double*)(ureg + (size_t)B * 16 * 256 * 8);         // 2 MB
    float* hpoolp = (float*)(ureg + 2 * (size_t)B * 16 * 256 * 8);     // 64*8*256*4 = 0.5 MB
    unsigned int* cand = (unsigned int*)ureg;
    float* gram = (float*)ureg;

    hipMemsetAsync(d_ws, 0, zero_bytes, stream);
    hipMemsetAsync(d_out, 0, (size_t)out_size * 4, stream);

    k_pass1<<<B * 16, 256, 0, stream>>>(x, mask, xm, rowm, cs1p, cs2p, accum);
    k_chan<<<B, 256, 0, stream>>>(cs1p, cs2p, mu, winv, accum);
    k_attn<<<B * 8, 256, 0, stream>>>(x, Wa1, ba1, Wa2, ba2, logit);
    k_smax<<<B, 256, 0, stream>>>(logit, smz);
    k_pool<<<B * 8, 256, 0, stream>>>(x, logit, smz, mu, winv, hpoolp, accum);
    k_route<<<B, 256, 0, stream>>>(hpoolp, Wr1, br1, Wr2, br2, Wr3, br3, temp, hpool, alpha);
    k_xmstats<<<B, 256, 0, stream>>>(xm, rowm, accum, stats);
    k_dft<<<B * 5, 256, 0, stream>>>(xm, power);
    k_spec<<<B, 256, 0, stream>>>(power, stats);
    k_histA<<<B * 4, 256, 0, stream>>>(x, hist);
    k_histB<<<B, 256, 0, stream>>>(hist, binsel, krem);
    k_compact<<<B * 16, 256, 0, stream>>>(x, binsel, ccnt, cand);
    k_select<<<B * NSEL, 256, 0, stream>>>(cand, ccnt, binsel, krem, qv);
    k_qwrite<<<1, 64, 0, stream>>>(qv, stats);
    k_gram<<<B * 4, 256, 0, stream>>>(x, mu, gram);
    k_power<<<B, 1024, 0, stream>>>(gram, accum, stats);
}